// Round 1
// baseline (7075.780 us; speedup 1.0000x reference)
//
#include <hip/hip_runtime.h>

// Problem constants
#define NB 16
#define NTOK 197
#define NPATCH 196
#define D 768
#define NH 12
#define HD 64
#define HOP 3072
#define TSTEPS 6
#define BETA_F 0.125f
#define PLD 208  // padded leading dim for P matrices (197 -> 208)

// ---------------- patchify gather ----------------
__global__ __launch_bounds__(256) void patchify_kernel(const float* __restrict__ x, float* __restrict__ tok) {
    int idx = blockIdx.x * 256 + threadIdx.x;
    const int total = NB * NPATCH * D;
    if (idx >= total) return;
    int d = idx % D;
    int p = (idx / D) % NPATCH;
    int b = idx / (D * NPATCH);
    int c = d >> 8;          // /256
    int pi = (d >> 4) & 15;
    int pj = d & 15;
    int hp = p / 14, wp = p % 14;
    int row = hp * 16 + pi, col = wp * 16 + pj;
    tok[idx] = x[(((long)b * 3 + c) * 224 + row) * 224 + col];
}

// ---------------- cls + pos add ----------------
__global__ __launch_bounds__(256) void cls_pos_kernel(float* __restrict__ h, const float* __restrict__ cls,
                                                      const float* __restrict__ pos) {
    int idx = blockIdx.x * 256 + threadIdx.x;
    const int total = NB * NTOK * D;
    if (idx >= total) return;
    int d = idx % D;
    int n = (idx / D) % NTOK;
    float v = pos[n * D + d];
    if (n == 0) h[idx] = cls[d] + v;
    else        h[idx] = h[idx] + v;
}

// ---------------- wq [H,D,K] -> Wm [D, H*K] ----------------
__global__ __launch_bounds__(256) void wcat_kernel(const float* __restrict__ w, float* __restrict__ Wm) {
    int idx = blockIdx.x * 256 + threadIdx.x;
    const int total = NH * D * HD;
    if (idx >= total) return;
    int k = idx & 63;
    int d = (idx >> 6) % D;
    int hh = idx / (D * HD);
    Wm[d * D + hh * HD + k] = w[idx];
}

// ---------------- tiled transpose: src[R,C] -> dst[C,R], batched ----------------
__global__ __launch_bounds__(256) void transpose_kernel(const float* __restrict__ src, float* __restrict__ dst,
                                                        int R, int C, long sStride, long dStride) {
    __shared__ float tile[32][33];
    const float* s = src + (long)blockIdx.z * sStride;
    float* d = dst + (long)blockIdx.z * dStride;
    int c0 = blockIdx.x * 32, r0 = blockIdx.y * 32;
    int tx = threadIdx.x % 32, ty = threadIdx.x / 32;  // ty 0..7
    for (int i = ty; i < 32; i += 8) {
        int r = r0 + i, c = c0 + tx;
        tile[i][tx] = (r < R && c < C) ? s[(long)r * C + c] : 0.f;
    }
    __syncthreads();
    for (int i = ty; i < 32; i += 8) {
        int c = c0 + i, r = r0 + tx;
        if (c < C && r < R) d[(long)c * R + r] = tile[tx][i];
    }
}

// ---------------- layernorm ----------------
__global__ __launch_bounds__(256) void ln_kernel(const float* __restrict__ X, float* __restrict__ Y,
                                                 const float* __restrict__ gamma, const float* __restrict__ beta,
                                                 int compact) {
    int r = blockIdx.x;
    long xrow = compact ? ((long)(r / NPATCH) * NTOK + 1 + (r % NPATCH)) : (long)r;
    const float* x = X + xrow * D;
    float* y = Y + (long)r * D;
    int t = threadIdx.x;
    float v[3];
    float s = 0.f, ss = 0.f;
#pragma unroll
    for (int i = 0; i < 3; i++) {
        v[i] = x[t + 256 * i];
        s += v[i];
        ss += v[i] * v[i];
    }
    __shared__ float red[8];
    for (int off = 32; off; off >>= 1) {
        s += __shfl_down(s, off, 64);
        ss += __shfl_down(ss, off, 64);
    }
    int wid = t >> 6, lane = t & 63;
    if (lane == 0) { red[wid] = s; red[4 + wid] = ss; }
    __syncthreads();
    s = red[0] + red[1] + red[2] + red[3];
    ss = red[4] + red[5] + red[6] + red[7];
    float mu = s * (1.f / 768.f);
    float var = ss * (1.f / 768.f) - mu * mu;
    float inv = rsqrtf(var + 1e-5f);
#pragma unroll
    for (int i = 0; i < 3; i++) {
        int c = t + 256 * i;
        y[c] = gamma[c] * (v[i] - mu) * inv + beta[c];
    }
}

// ---------------- attention scores + softmax over keys ----------------
// One block per (b,h). Stages K,Q in LDS, loops over queries m.
// Writes Pt[m][n] (=p[n,m]) and Pn[n][m] (=p[n,m]) with leading dim PLD.
__global__ __launch_bounds__(256) void attn_softmax_kernel(const float* __restrict__ Q, const float* __restrict__ K,
                                                           float* __restrict__ Pt, float* __restrict__ Pn) {
    extern __shared__ float smem[];
    float (*Ks)[65] = (float(*)[65])smem;
    float (*Qs)[65] = (float(*)[65])(smem + NTOK * 65);
    __shared__ float red4[8];
    int bh = blockIdx.x;
    int b = bh / NH, hh = bh % NH;
    int t = threadIdx.x;
    const float* Kb = K + (long)b * NTOK * D + hh * HD;
    const float* Qb = Q + (long)b * NTOK * D + hh * HD;
    for (int idx = t; idx < NTOK * HD; idx += 256) {
        int n = idx >> 6, k = idx & 63;
        Ks[n][k] = Kb[(long)n * D + k];
        Qs[n][k] = Qb[(long)n * D + k];
    }
    __syncthreads();
    float* PtB = Pt + (long)bh * NTOK * PLD;
    float* PnB = Pn + (long)bh * NTOK * PLD;
    int wid = t >> 6, lane = t & 63;
    for (int m = 0; m < NTOK; m++) {
        float sv = 0.f;
        float s = -INFINITY;
        if (t < NTOK) {
            const float* kr = Ks[t];
            const float* qr = Qs[m];
            float a0 = 0.f, a1 = 0.f, a2 = 0.f, a3 = 0.f;
#pragma unroll
            for (int k = 0; k < 64; k += 4) {
                a0 += kr[k] * qr[k];
                a1 += kr[k + 1] * qr[k + 1];
                a2 += kr[k + 2] * qr[k + 2];
                a3 += kr[k + 3] * qr[k + 3];
            }
            sv = ((a0 + a1) + (a2 + a3)) * BETA_F;
            s = sv;
        }
        float mx = s;
        for (int off = 32; off; off >>= 1) mx = fmaxf(mx, __shfl_down(mx, off, 64));
        if (lane == 0) red4[wid] = mx;
        __syncthreads();
        mx = fmaxf(fmaxf(red4[0], red4[1]), fmaxf(red4[2], red4[3]));
        float e = (t < NTOK) ? __expf(sv - mx) : 0.f;
        float sm = e;
        for (int off = 32; off; off >>= 1) sm += __shfl_down(sm, off, 64);
        if (lane == 0) red4[4 + wid] = sm;
        __syncthreads();
        sm = red4[4] + red4[5] + red4[6] + red4[7];
        float p = e * (1.f / sm);
        if (t < NTOK) {
            PtB[(long)m * PLD + t] = p;
            PnB[(long)t * PLD + m] = p;
        }
        __syncthreads();
    }
}

// ---------------- generic tiled f32 GEMM ----------------
// C[M,N] = A[M,K(lda)] * B[K,N(ldb)] (+bias) (flags: 1=accumulate into C, 2=relu)
// batch z: off = (z/zdiv)*s?1 + (z%zdiv)*s?2
__global__ __launch_bounds__(256) void gemm_f32(
    const float* __restrict__ A, const float* __restrict__ B, float* __restrict__ C,
    const float* __restrict__ bias,
    int M, int N, int K, int lda, int ldb, int ldc,
    int zdiv, long sA1, long sA2, long sB1, long sB2, long sC1, long sC2,
    int flags) {
    int z = blockIdx.z;
    int z1 = z / zdiv, z2 = z - z1 * zdiv;
    A += (long)z1 * sA1 + (long)z2 * sA2;
    B += (long)z1 * sB1 + (long)z2 * sB2;
    C += (long)z1 * sC1 + (long)z2 * sC2;

    __shared__ float As[16][68];
    __shared__ float Bs[16][68];

    int t = threadIdx.x;
    int tx = t & 15, ty = t >> 4;
    int row0 = blockIdx.y * 64, col0 = blockIdx.x * 64;

    float acc[4][4] = {};

    for (int kt = 0; kt < K; kt += 16) {
        // A tile: 64 rows x 16 k
        {
            int r = t >> 2;
            int c4 = (t & 3) << 2;
            int gr = row0 + r;
            int gk = kt + c4;
            float4 v = make_float4(0.f, 0.f, 0.f, 0.f);
            if (gr < M) {
                if (gk + 3 < K) {
                    v = *(const float4*)(A + (long)gr * lda + gk);
                } else {
                    float x0 = (gk < K) ? A[(long)gr * lda + gk] : 0.f;
                    float x1 = (gk + 1 < K) ? A[(long)gr * lda + gk + 1] : 0.f;
                    float x2 = (gk + 2 < K) ? A[(long)gr * lda + gk + 2] : 0.f;
                    float x3 = (gk + 3 < K) ? A[(long)gr * lda + gk + 3] : 0.f;
                    v = make_float4(x0, x1, x2, x3);
                }
            }
            As[c4 + 0][r] = v.x; As[c4 + 1][r] = v.y; As[c4 + 2][r] = v.z; As[c4 + 3][r] = v.w;
        }
        // B tile: 16 k x 64 cols
        {
            int r = t >> 4;
            int c4 = (t & 15) << 2;
            int gk = kt + r;
            int gc = col0 + c4;
            float4 v = make_float4(0.f, 0.f, 0.f, 0.f);
            if (gk < K && gc + 3 < N) {
                v = *(const float4*)(B + (long)gk * ldb + gc);
            }
            Bs[r][c4 + 0] = v.x; Bs[r][c4 + 1] = v.y; Bs[r][c4 + 2] = v.z; Bs[r][c4 + 3] = v.w;
        }
        __syncthreads();
#pragma unroll
        for (int kk = 0; kk < 16; kk++) {
            float av[4], bv[4];
#pragma unroll
            for (int i = 0; i < 4; i++) av[i] = As[kk][ty * 4 + i];
#pragma unroll
            for (int j = 0; j < 4; j++) bv[j] = Bs[kk][tx * 4 + j];
#pragma unroll
            for (int i = 0; i < 4; i++)
#pragma unroll
                for (int j = 0; j < 4; j++) acc[i][j] += av[i] * bv[j];
        }
        __syncthreads();
    }
#pragma unroll
    for (int i = 0; i < 4; i++) {
        int gr = row0 + ty * 4 + i;
        if (gr >= M) continue;
#pragma unroll
        for (int j = 0; j < 4; j++) {
            int gc = col0 + tx * 4 + j;
            if (gc >= N) continue;
            float v = acc[i][j];
            if (bias) v += bias[gc];
            if (flags & 2) v = fmaxf(v, 0.f);
            long idx = (long)gr * ldc + gc;
            if (flags & 1) C[idx] += v;
            else C[idx] = v;
        }
    }
}

extern "C" void kernel_launch(void* const* d_in, const int* in_sizes, int n_in,
                              void* d_out, int out_size, void* d_ws, size_t ws_size,
                              hipStream_t stream) {
    const float* x        = (const float*)d_in[0];
    const float* patch_w  = (const float*)d_in[1];
    const float* patch_b  = (const float*)d_in[2];
    const float* cls_tok  = (const float*)d_in[3];
    const float* pos_emb  = (const float*)d_in[4];
    const float* ln_gamma = (const float*)d_in[5];
    const float* ln_beta  = (const float*)d_in[6];
    const float* wq       = (const float*)d_in[7];
    const float* wk       = (const float*)d_in[8];
    const float* xi       = (const float*)d_in[9];
    const float* out_gamma= (const float*)d_in[10];
    const float* out_beta = (const float*)d_in[11];
    const float* out_w    = (const float*)d_in[12];
    const float* out_b    = (const float*)d_in[13];
    float* out = (float*)d_out;

    float* ws = (float*)d_ws;
    const long SZ = (long)NB * NTOK * D;           // 2,420,736
    float* h   = ws;
    float* g   = ws + SZ;
    float* Qb  = ws + 2 * SZ;
    float* Kb  = ws + 3 * SZ;
    float* G1  = ws + 4 * SZ;
    float* G2  = ws + 5 * SZ;
    float* Wq  = ws + 6 * SZ;                      // 589,824 each
    float* Wk  = Wq + (long)D * D;
    float* WqT = Wk + (long)D * D;
    float* WkT = WqT + (long)D * D;
    float* xiT = WkT + (long)D * D;                // 2,359,296
    float* R1  = xiT + (long)D * HOP;
    float* Pt  = R1;                               // 192*197*208
    float* Pn  = R1 + (long)NB * NH * NTOK * PLD;
    float* HH  = R1;                               // reused after P consumed
    float* tok = R1;                               // reused (setup only)

    auto gemm = [&](const float* A, const float* B, float* C, const float* bias,
                    int M, int N, int K, int lda, int ldb, int ldc,
                    int gz, int zdiv, long sA1, long sA2, long sB1, long sB2,
                    long sC1, long sC2, int flags) {
        dim3 grid((N + 63) / 64, (M + 63) / 64, gz);
        gemm_f32<<<grid, 256, 0, stream>>>(A, B, C, bias, M, N, K, lda, ldb, ldc,
                                           zdiv, sA1, sA2, sB1, sB2, sC1, sC2, flags);
    };

    // ---- setup ----
    patchify_kernel<<<(NB * NPATCH * D + 255) / 256, 256, 0, stream>>>(x, tok);
    wcat_kernel<<<(NH * D * HD + 255) / 256, 256, 0, stream>>>(wq, Wq);
    wcat_kernel<<<(NH * D * HD + 255) / 256, 256, 0, stream>>>(wk, Wk);
    transpose_kernel<<<dim3(2, 24, 12), 256, 0, stream>>>(wq, WqT, D, HD, (long)D * HD, (long)HD * D);
    transpose_kernel<<<dim3(2, 24, 12), 256, 0, stream>>>(wk, WkT, D, HD, (long)D * HD, (long)HD * D);
    transpose_kernel<<<dim3(96, 24, 1), 256, 0, stream>>>(xi, xiT, D, HOP, 0, 0);
    // tok @ patch_w + patch_b -> h rows 1..196 per batch
    gemm(tok, patch_w, h + D, patch_b, NPATCH, D, D, D, D, D,
         NB, 1, (long)NPATCH * D, 0, 0, 0, (long)NTOK * D, 0, 0);
    cls_pos_kernel<<<(NB * NTOK * D + 255) / 256, 256, 0, stream>>>(h, cls_tok, pos_emb);

    const long PBH = (long)NTOK * PLD;             // 40,976
    const size_t attn_lds = (size_t)(2 * NTOK * 65) * sizeof(float);

    for (int step = 0; step < TSTEPS; step++) {
        ln_kernel<<<NB * NTOK, 256, 0, stream>>>(h, g, ln_gamma, ln_beta, 0);
        gemm(g, Wq, Qb, nullptr, NB * NTOK, D, D, D, D, D, 1, 1, 0, 0, 0, 0, 0, 0, 0);
        gemm(g, Wk, Kb, nullptr, NB * NTOK, D, D, D, D, D, 1, 1, 0, 0, 0, 0, 0, 0, 0);
        attn_softmax_kernel<<<NB * NH, 256, attn_lds, stream>>>(Qb, Kb, Pt, Pn);
        // G1[m,k] = sum_n Pt[m,n] * K[n,k]   (per b,h)
        gemm(Pt, Kb, G1, nullptr, NTOK, HD, NTOK, PLD, D, D,
             NB * NH, NH, (long)NH * PBH, PBH, (long)NTOK * D, HD, (long)NTOK * D, HD, 0);
        // G2[n,k] = sum_m Pn[n,m] * Q[m,k]   (per b,h)
        gemm(Pn, Qb, G2, nullptr, NTOK, HD, NTOK, PLD, D, D,
             NB * NH, NH, (long)NH * PBH, PBH, (long)NTOK * D, HD, (long)NTOK * D, HD, 0);
        // h += G1cat @ WqT ; h += G2cat @ WkT
        gemm(G1, WqT, h, nullptr, NB * NTOK, D, D, D, D, D, 1, 1, 0, 0, 0, 0, 0, 0, 1);
        gemm(G2, WkT, h, nullptr, NB * NTOK, D, D, D, D, D, 1, 1, 0, 0, 0, 0, 0, 0, 1);
        // Hopfield: HH = relu(g @ xi); h += HH @ xiT
        gemm(g, xi, HH, nullptr, NB * NTOK, HOP, D, D, HOP, HOP, 1, 1, 0, 0, 0, 0, 0, 0, 2);
        gemm(HH, xiT, h, nullptr, NB * NTOK, D, HOP, HOP, D, D, 1, 1, 0, 0, 0, 0, 0, 0, 1);
    }

    // ---- final LN (compact, skip cls) + output projection ----
    ln_kernel<<<NB * NPATCH, 256, 0, stream>>>(h, g, out_gamma, out_beta, 1);
    gemm(g, out_w, out, out_b, NB * NPATCH, D, D, D, D, D, 1, 1, 0, 0, 0, 0, 0, 0, 0);
}

// Round 6
// 5529.129 us; speedup vs baseline: 1.2797x; 1.2797x over previous
//
#include <hip/hip_runtime.h>

#define NB 16
#define NTOK 197
#define NPATCH 196
#define D 768
#define NH 12
#define HD 64
#define HOP 3072
#define TSTEPS 6
#define BETA_F 0.125f
#define PLD 208                 // P leading dim (f32, R0 layout)
#define PBH (NTOK * PLD)        // 40976
#define NROWS (NB * NTOK)       // 3152
#define NPROWS (NB * NPATCH)    // 3136
#define AROWS 3200              // padded rows for MFMA A-side staging

typedef unsigned short u16;
typedef __attribute__((ext_vector_type(8))) short bf16x8;
typedef __attribute__((ext_vector_type(4))) float f32x4;

#define FLAG_ACC 1
#define FLAG_RELU 2
#define FLAG_SPLIT 4

__device__ __forceinline__ u16 f2b(float f) {
    unsigned u = __float_as_uint(f);
    u = (u + 0x7fffu + ((u >> 16) & 1u)) >> 16;
    return (u16)u;
}
__device__ __forceinline__ float b2f(u16 u) { return __uint_as_float(((unsigned)u) << 16); }

__device__ __forceinline__ void gld16(const void* g, void* l) {
    __builtin_amdgcn_global_load_lds((const __attribute__((address_space(1))) void*)g,
                                     (__attribute__((address_space(3))) void*)l, 16, 0, 0);
}

// ---------------- split-bf16 MFMA GEMM (suspect under test; R4-verbatim) ----------------
__global__ __launch_bounds__(256) void gemm_split(
    const u16* __restrict__ Ah, const u16* __restrict__ Al,
    const u16* __restrict__ Bh, const u16* __restrict__ Bl,
    void* __restrict__ Cv, u16* __restrict__ Cl, const float* __restrict__ bias,
    int M, int N, int K, int lda, int ldbt, int ldc, int flags) {
    __shared__ __align__(16) u16 AsH[128 * 32];
    __shared__ __align__(16) u16 AsL[128 * 32];
    __shared__ __align__(16) u16 BsH[128 * 32];
    __shared__ __align__(16) u16 BsL[128 * 32];
    int t = threadIdx.x;
    int w = t >> 6, lane = t & 63;
    int lr = lane & 15, lg = lane >> 4, ko = lg * 8;
    int wr = w >> 1, wc = w & 1;
    long row0 = (long)blockIdx.y * 128, col0 = (long)blockIdx.x * 128;

    f32x4 acc[4][4];
#pragma unroll
    for (int i = 0; i < 4; i++)
#pragma unroll
        for (int j = 0; j < 4; j++) acc[i][j] = (f32x4){0.f, 0.f, 0.f, 0.f};

    int c0 = w * 64 + lane;
    int r0s = c0 >> 2, k0s = (c0 & 3) << 3;
    int c1 = 256 + w * 64 + lane;
    int r1s = c1 >> 2, k1s = (c1 & 3) << 3;

    for (int kt = 0; kt < K; kt += 32) {
        const u16* AhB = Ah + row0 * lda + kt;
        const u16* AlB = Al + row0 * lda + kt;
        const u16* BhB = Bh + col0 * ldbt + kt;
        const u16* BlB = Bl + col0 * ldbt + kt;
        gld16(AhB + (long)r0s * lda + k0s, (char*)AsH + (w * 64) * 16);
        gld16(AhB + (long)r1s * lda + k1s, (char*)AsH + (256 + w * 64) * 16);
        gld16(AlB + (long)r0s * lda + k0s, (char*)AsL + (w * 64) * 16);
        gld16(AlB + (long)r1s * lda + k1s, (char*)AsL + (256 + w * 64) * 16);
        gld16(BhB + (long)r0s * ldbt + k0s, (char*)BsH + (w * 64) * 16);
        gld16(BhB + (long)r1s * ldbt + k1s, (char*)BsH + (256 + w * 64) * 16);
        gld16(BlB + (long)r0s * ldbt + k0s, (char*)BsL + (w * 64) * 16);
        gld16(BlB + (long)r1s * ldbt + k1s, (char*)BsL + (256 + w * 64) * 16);
        __syncthreads();
        bf16x8 afh[4], afl[4], bfh[4], bfl[4];
#pragma unroll
        for (int mi = 0; mi < 4; mi++) {
            int o = (wr * 64 + mi * 16 + lr) * 32 + ko;
            afh[mi] = *(const bf16x8*)&AsH[o];
            afl[mi] = *(const bf16x8*)&AsL[o];
        }
#pragma unroll
        for (int ni = 0; ni < 4; ni++) {
            int o = (wc * 64 + ni * 16 + lr) * 32 + ko;
            bfh[ni] = *(const bf16x8*)&BsH[o];
            bfl[ni] = *(const bf16x8*)&BsL[o];
        }
#pragma unroll
        for (int mi = 0; mi < 4; mi++)
#pragma unroll
            for (int ni = 0; ni < 4; ni++) {
                acc[mi][ni] = __builtin_amdgcn_mfma_f32_16x16x32_bf16(afl[mi], bfh[ni], acc[mi][ni], 0, 0, 0);
                acc[mi][ni] = __builtin_amdgcn_mfma_f32_16x16x32_bf16(afh[mi], bfl[ni], acc[mi][ni], 0, 0, 0);
                acc[mi][ni] = __builtin_amdgcn_mfma_f32_16x16x32_bf16(afh[mi], bfh[ni], acc[mi][ni], 0, 0, 0);
            }
        __syncthreads();
    }

    long mbase = row0 + wr * 64;
    long nbase = col0 + wc * 64;
#pragma unroll
    for (int mi = 0; mi < 4; mi++) {
#pragma unroll
        for (int r = 0; r < 4; r++) {
            long grow = mbase + mi * 16 + lg * 4 + r;
            if (grow >= M) continue;
#pragma unroll
            for (int ni = 0; ni < 4; ni++) {
                long gcol = nbase + ni * 16 + lr;
                float v = acc[mi][ni][r];
                if (bias) v += bias[gcol];
                if (flags & FLAG_RELU) v = fmaxf(v, 0.f);
                long idx = grow * ldc + gcol;
                if (flags & FLAG_ACC) ((float*)Cv)[idx] += v;
                else if (flags & FLAG_SPLIT) {
                    u16 hv = f2b(v);
                    ((u16*)Cv)[idx] = hv;
                    Cl[idx] = f2b(v - b2f(hv));
                } else ((float*)Cv)[idx] = v;
            }
        }
    }
}

// ================= R0-VERBATIM f32 PIPELINE =================

__global__ __launch_bounds__(256) void patchify_kernel(const float* __restrict__ x, float* __restrict__ tok) {
    int idx = blockIdx.x * 256 + threadIdx.x;
    const int total = NB * NPATCH * D;
    if (idx >= total) return;
    int d = idx % D;
    int p = (idx / D) % NPATCH;
    int b = idx / (D * NPATCH);
    int c = d >> 8;
    int pi = (d >> 4) & 15;
    int pj = d & 15;
    int hp = p / 14, wp = p % 14;
    int row = hp * 16 + pi, col = wp * 16 + pj;
    tok[idx] = x[(((long)b * 3 + c) * 224 + row) * 224 + col];
}

__global__ __launch_bounds__(256) void cls_pos_kernel(float* __restrict__ h, const float* __restrict__ cls,
                                                      const float* __restrict__ pos) {
    int idx = blockIdx.x * 256 + threadIdx.x;
    const int total = NB * NTOK * D;
    if (idx >= total) return;
    int d = idx % D;
    int n = (idx / D) % NTOK;
    float v = pos[n * D + d];
    if (n == 0) h[idx] = cls[d] + v;
    else        h[idx] = h[idx] + v;
}

__global__ __launch_bounds__(256) void wcat_kernel(const float* __restrict__ w, float* __restrict__ Wm) {
    int idx = blockIdx.x * 256 + threadIdx.x;
    const int total = NH * D * HD;
    if (idx >= total) return;
    int k = idx & 63;
    int d = (idx >> 6) % D;
    int hh = idx / (D * HD);
    Wm[d * D + hh * HD + k] = w[idx];
}

__global__ __launch_bounds__(256) void transpose_kernel(const float* __restrict__ src, float* __restrict__ dst,
                                                        int R, int C, long sStride, long dStride) {
    __shared__ float tile[32][33];
    const float* s = src + (long)blockIdx.z * sStride;
    float* d = dst + (long)blockIdx.z * dStride;
    int c0 = blockIdx.x * 32, r0 = blockIdx.y * 32;
    int tx = threadIdx.x % 32, ty = threadIdx.x / 32;
    for (int i = ty; i < 32; i += 8) {
        int r = r0 + i, c = c0 + tx;
        tile[i][tx] = (r < R && c < C) ? s[(long)r * C + c] : 0.f;
    }
    __syncthreads();
    for (int i = ty; i < 32; i += 8) {
        int c = c0 + i, r = r0 + tx;
        if (c < C && r < R) d[(long)c * R + r] = tile[tx][i];
    }
}

// ln: f32 out (R0) + OPTIONAL split bf16 out (for the Hopfield gemm_split)
__global__ __launch_bounds__(256) void ln_kernel(const float* __restrict__ X, float* __restrict__ Y,
                                                 u16* __restrict__ Yh, u16* __restrict__ Yl,
                                                 const float* __restrict__ gamma, const float* __restrict__ beta,
                                                 int compact) {
    int r = blockIdx.x;
    long xrow = compact ? ((long)(r / NPATCH) * NTOK + 1 + (r % NPATCH)) : (long)r;
    const float* x = X + xrow * D;
    float* y = Y + (long)r * D;
    int t = threadIdx.x;
    float v[3];
    float s = 0.f, ss = 0.f;
#pragma unroll
    for (int i = 0; i < 3; i++) {
        v[i] = x[t + 256 * i];
        s += v[i];
        ss += v[i] * v[i];
    }
    __shared__ float red[8];
    for (int off = 32; off; off >>= 1) {
        s += __shfl_down(s, off, 64);
        ss += __shfl_down(ss, off, 64);
    }
    int wid = t >> 6, lane = t & 63;
    if (lane == 0) { red[wid] = s; red[4 + wid] = ss; }
    __syncthreads();
    s = red[0] + red[1] + red[2] + red[3];
    ss = red[4] + red[5] + red[6] + red[7];
    float mu = s * (1.f / 768.f);
    float var = ss * (1.f / 768.f) - mu * mu;
    float inv = rsqrtf(var + 1e-5f);
#pragma unroll
    for (int i = 0; i < 3; i++) {
        int c = t + 256 * i;
        float yv = gamma[c] * (v[i] - mu) * inv + beta[c];
        y[c] = yv;
        if (Yh) {
            u16 hv = f2b(yv);
            Yh[(long)r * D + c] = hv;
            Yl[(long)r * D + c] = f2b(yv - b2f(hv));
        }
    }
}

__global__ __launch_bounds__(256) void attn_softmax_kernel(const float* __restrict__ Q, const float* __restrict__ K,
                                                           float* __restrict__ Pt, float* __restrict__ Pn) {
    extern __shared__ float smem[];
    float (*Ks)[65] = (float(*)[65])smem;
    float (*Qs)[65] = (float(*)[65])(smem + NTOK * 65);
    __shared__ float red4[8];
    int bh = blockIdx.x;
    int b = bh / NH, hh = bh % NH;
    int t = threadIdx.x;
    const float* Kb = K + (long)b * NTOK * D + hh * HD;
    const float* Qb = Q + (long)b * NTOK * D + hh * HD;
    for (int idx = t; idx < NTOK * HD; idx += 256) {
        int n = idx >> 6, k = idx & 63;
        Ks[n][k] = Kb[(long)n * D + k];
        Qs[n][k] = Qb[(long)n * D + k];
    }
    __syncthreads();
    float* PtB = Pt + (long)bh * NTOK * PLD;
    float* PnB = Pn + (long)bh * NTOK * PLD;
    int wid = t >> 6, lane = t & 63;
    for (int m = 0; m < NTOK; m++) {
        float sv = 0.f;
        float s = -INFINITY;
        if (t < NTOK) {
            const float* kr = Ks[t];
            const float* qr = Qs[m];
            float a0 = 0.f, a1 = 0.f, a2 = 0.f, a3 = 0.f;
#pragma unroll
            for (int k = 0; k < 64; k += 4) {
                a0 += kr[k] * qr[k];
                a1 += kr[k + 1] * qr[k + 1];
                a2 += kr[k + 2] * qr[k + 2];
                a3 += kr[k + 3] * qr[k + 3];
            }
            sv = ((a0 + a1) + (a2 + a3)) * BETA_F;
            s = sv;
        }
        float mx = s;
        for (int off = 32; off; off >>= 1) mx = fmaxf(mx, __shfl_down(mx, off, 64));
        if (lane == 0) red4[wid] = mx;
        __syncthreads();
        mx = fmaxf(fmaxf(red4[0], red4[1]), fmaxf(red4[2], red4[3]));
        float e = (t < NTOK) ? __expf(sv - mx) : 0.f;
        float sm = e;
        for (int off = 32; off; off >>= 1) sm += __shfl_down(sm, off, 64);
        if (lane == 0) red4[4 + wid] = sm;
        __syncthreads();
        sm = red4[4] + red4[5] + red4[6] + red4[7];
        float p = e * (1.f / sm);
        if (t < NTOK) {
            PtB[(long)m * PLD + t] = p;
            PnB[(long)t * PLD + m] = p;
        }
        __syncthreads();
    }
}

__global__ __launch_bounds__(256) void gemm_f32(
    const float* __restrict__ A, const float* __restrict__ B, float* __restrict__ C,
    const float* __restrict__ bias,
    int M, int N, int K, int lda, int ldb, int ldc,
    int zdiv, long sA1, long sA2, long sB1, long sB2, long sC1, long sC2,
    int flags) {
    int z = blockIdx.z;
    int z1 = z / zdiv, z2 = z - z1 * zdiv;
    A += (long)z1 * sA1 + (long)z2 * sA2;
    B += (long)z1 * sB1 + (long)z2 * sB2;
    C += (long)z1 * sC1 + (long)z2 * sC2;

    __shared__ float As[16][68];
    __shared__ float Bs[16][68];

    int t = threadIdx.x;
    int tx = t & 15, ty = t >> 4;
    int row0 = blockIdx.y * 64, col0 = blockIdx.x * 64;

    float acc[4][4] = {};

    for (int kt = 0; kt < K; kt += 16) {
        {
            int r = t >> 2;
            int c4 = (t & 3) << 2;
            int gr = row0 + r;
            int gk = kt + c4;
            float4 v = make_float4(0.f, 0.f, 0.f, 0.f);
            if (gr < M) {
                if (gk + 3 < K) {
                    v = *(const float4*)(A + (long)gr * lda + gk);
                } else {
                    float x0 = (gk < K) ? A[(long)gr * lda + gk] : 0.f;
                    float x1 = (gk + 1 < K) ? A[(long)gr * lda + gk + 1] : 0.f;
                    float x2 = (gk + 2 < K) ? A[(long)gr * lda + gk + 2] : 0.f;
                    float x3 = (gk + 3 < K) ? A[(long)gr * lda + gk + 3] : 0.f;
                    v = make_float4(x0, x1, x2, x3);
                }
            }
            As[c4 + 0][r] = v.x; As[c4 + 1][r] = v.y; As[c4 + 2][r] = v.z; As[c4 + 3][r] = v.w;
        }
        {
            int r = t >> 4;
            int c4 = (t & 15) << 2;
            int gk = kt + r;
            int gc = col0 + c4;
            float4 v = make_float4(0.f, 0.f, 0.f, 0.f);
            if (gk < K && gc + 3 < N) {
                v = *(const float4*)(B + (long)gk * ldb + gc);
            }
            Bs[r][c4 + 0] = v.x; Bs[r][c4 + 1] = v.y; Bs[r][c4 + 2] = v.z; Bs[r][c4 + 3] = v.w;
        }
        __syncthreads();
#pragma unroll
        for (int kk = 0; kk < 16; kk++) {
            float av[4], bv[4];
#pragma unroll
            for (int i = 0; i < 4; i++) av[i] = As[kk][ty * 4 + i];
#pragma unroll
            for (int j = 0; j < 4; j++) bv[j] = Bs[kk][tx * 4 + j];
#pragma unroll
            for (int i = 0; i < 4; i++)
#pragma unroll
                for (int j = 0; j < 4; j++) acc[i][j] += av[i] * bv[j];
        }
        __syncthreads();
    }
#pragma unroll
    for (int i = 0; i < 4; i++) {
        int gr = row0 + ty * 4 + i;
        if (gr >= M) continue;
#pragma unroll
        for (int j = 0; j < 4; j++) {
            int gc = col0 + tx * 4 + j;
            if (gc >= N) continue;
            float v = acc[i][j];
            if (bias) v += bias[gc];
            if (flags & 2) v = fmaxf(v, 0.f);
            long idx = (long)gr * ldc + gc;
            if (flags & 1) C[idx] += v;
            else C[idx] = v;
        }
    }
}

// split prep for xi (new path feeding gemm_split)
__global__ __launch_bounds__(256) void prep_transpose(const float* __restrict__ src,
                                                      u16* __restrict__ dh, u16* __restrict__ dl, int R, int C) {
    int idx = blockIdx.x * 256 + threadIdx.x;
    if (idx >= R * C) return;
    int r = idx % R, c = idx / R;
    float v = src[(long)r * C + c];
    u16 hv = f2b(v);
    dh[idx] = hv;
    dl[idx] = f2b(v - b2f(hv));
}
__global__ __launch_bounds__(256) void prep_convert(const float* __restrict__ src,
                                                    u16* __restrict__ dh, u16* __restrict__ dl, int n) {
    int idx = blockIdx.x * 256 + threadIdx.x;
    if (idx >= n) return;
    float v = src[idx];
    u16 hv = f2b(v);
    dh[idx] = hv;
    dl[idx] = f2b(v - b2f(hv));
}

extern "C" void kernel_launch(void* const* d_in, const int* in_sizes, int n_in,
                              void* d_out, int out_size, void* d_ws, size_t ws_size,
                              hipStream_t stream) {
    const float* x        = (const float*)d_in[0];
    const float* patch_w  = (const float*)d_in[1];
    const float* patch_b  = (const float*)d_in[2];
    const float* cls_tok  = (const float*)d_in[3];
    const float* pos_emb  = (const float*)d_in[4];
    const float* ln_gamma = (const float*)d_in[5];
    const float* ln_beta  = (const float*)d_in[6];
    const float* wq       = (const float*)d_in[7];
    const float* wk       = (const float*)d_in[8];
    const float* xi       = (const float*)d_in[9];
    const float* out_gamma= (const float*)d_in[10];
    const float* out_beta = (const float*)d_in[11];
    const float* out_w    = (const float*)d_in[12];
    const float* out_b    = (const float*)d_in[13];
    float* out = (float*)d_out;

    float* ws = (float*)d_ws;
    const long SZ = (long)NB * NTOK * D;
    float* h   = ws;
    float* g   = ws + SZ;
    float* Qb  = ws + 2 * SZ;
    float* Kb  = ws + 3 * SZ;
    float* G1  = ws + 4 * SZ;
    float* G2  = ws + 5 * SZ;
    float* Wq  = ws + 6 * SZ;
    float* Wk  = Wq + (long)D * D;
    float* WqT = Wk + (long)D * D;
    float* WkT = WqT + (long)D * D;
    // split buffers
    u16* gh   = (u16*)(WkT + (long)D * D);
    u16* gl   = gh + (long)AROWS * D;
    u16* xiTh = gl + (long)AROWS * D;
    u16* xiTl = xiTh + (long)HOP * D;
    u16* xibh = xiTl + (long)HOP * D;
    u16* xibl = xibh + (long)HOP * D;
    // shared region: {Pt,Pn} | {HHh,HHl} | tok
    float* R1 = (float*)(xibl + (long)HOP * D);
    float* Pt = R1;
    float* Pn = R1 + (long)NB * NH * PBH;
    u16* HHh  = (u16*)R1;
    u16* HHl  = HHh + (long)AROWS * HOP;
    float* tok = R1;

    auto gemm = [&](const float* A, const float* B, float* C, const float* bias,
                    int M, int N, int K, int lda, int ldb, int ldc,
                    int gz, int zdiv, long sA1, long sA2, long sB1, long sB2,
                    long sC1, long sC2, int flags) {
        dim3 grid((N + 63) / 64, (M + 63) / 64, gz);
        gemm_f32<<<grid, 256, 0, stream>>>(A, B, C, bias, M, N, K, lda, ldb, ldc,
                                           zdiv, sA1, sA2, sB1, sB2, sC1, sC2, flags);
    };

    // ---- setup (R0-verbatim + xi split preps) ----
    patchify_kernel<<<(NB * NPATCH * D + 255) / 256, 256, 0, stream>>>(x, tok);
    wcat_kernel<<<(NH * D * HD + 255) / 256, 256, 0, stream>>>(wq, Wq);
    wcat_kernel<<<(NH * D * HD + 255) / 256, 256, 0, stream>>>(wk, Wk);
    transpose_kernel<<<dim3(2, 24, 12), 256, 0, stream>>>(wq, WqT, D, HD, (long)D * HD, (long)HD * D);
    transpose_kernel<<<dim3(2, 24, 12), 256, 0, stream>>>(wk, WkT, D, HD, (long)D * HD, (long)HD * D);
    prep_transpose<<<(D * HOP + 255) / 256, 256, 0, stream>>>(xi, xiTh, xiTl, D, HOP);
    prep_convert<<<(D * HOP + 255) / 256, 256, 0, stream>>>(xi, xibh, xibl, D * HOP);
    gemm(tok, patch_w, h + D, patch_b, NPATCH, D, D, D, D, D,
         NB, 1, (long)NPATCH * D, 0, 0, 0, (long)NTOK * D, 0, 0);
    cls_pos_kernel<<<(NB * NTOK * D + 255) / 256, 256, 0, stream>>>(h, cls_tok, pos_emb);

    const size_t attn_lds = (size_t)(2 * NTOK * 65) * sizeof(float);

    for (int step = 0; step < TSTEPS; step++) {
        ln_kernel<<<NB * NTOK, 256, 0, stream>>>(h, g, gh, gl, ln_gamma, ln_beta, 0);
        gemm(g, Wq, Qb, nullptr, NROWS, D, D, D, D, D, 1, 1, 0, 0, 0, 0, 0, 0, 0);
        gemm(g, Wk, Kb, nullptr, NROWS, D, D, D, D, D, 1, 1, 0, 0, 0, 0, 0, 0, 0);
        attn_softmax_kernel<<<NB * NH, 256, attn_lds, stream>>>(Qb, Kb, Pt, Pn);
        gemm(Pt, Kb, G1, nullptr, NTOK, HD, NTOK, PLD, D, D,
             NB * NH, NH, (long)NH * PBH, PBH, (long)NTOK * D, HD, (long)NTOK * D, HD, 0);
        gemm(Pn, Qb, G2, nullptr, NTOK, HD, NTOK, PLD, D, D,
             NB * NH, NH, (long)NH * PBH, PBH, (long)NTOK * D, HD, (long)NTOK * D, HD, 0);
        gemm(G1, WqT, h, nullptr, NROWS, D, D, D, D, D, 1, 1, 0, 0, 0, 0, 0, 0, 1);
        gemm(G2, WkT, h, nullptr, NROWS, D, D, D, D, D, 1, 1, 0, 0, 0, 0, 0, 0, 1);
        // ---- Hopfield via gemm_split (THE bisect probe) ----
        {
            dim3 g1(HOP / 128, (NROWS + 127) / 128, 1);
            gemm_split<<<g1, 256, 0, stream>>>(gh, gl, xiTh, xiTl, HHh, HHl, nullptr,
                                               NROWS, HOP, D, D, D, HOP, FLAG_SPLIT | FLAG_RELU);
            dim3 g2(D / 128, (NROWS + 127) / 128, 1);
            gemm_split<<<g2, 256, 0, stream>>>(HHh, HHl, xibh, xibl, h, nullptr, nullptr,
                                               NROWS, D, HOP, HOP, HOP, D, FLAG_ACC);
        }
    }

    // ---- final LN (compact, f32) + output projection (R0-verbatim) ----
    ln_kernel<<<NB * NPATCH, 256, 0, stream>>>(h, g, nullptr, nullptr, out_gamma, out_beta, 1);
    gemm(g, out_w, out, out_b, NPROWS, D, D, D, D, D, 1, 1, 0, 0, 0, 0, 0, 0, 0);
}

// Round 8
// 4206.779 us; speedup vs baseline: 1.6820x; 1.3143x over previous
//
#include <hip/hip_runtime.h>

#define NB 16
#define NTOK 197
#define NPATCH 196
#define D 768
#define NH 12
#define HD 64
#define HOP 3072
#define TSTEPS 6
#define BETA_F 0.125f
#define PLD 208                 // P leading dim (f32, R0 layout)
#define PBH (NTOK * PLD)        // 40976
#define NROWS (NB * NTOK)       // 3152
#define NPROWS (NB * NPATCH)    // 3136
#define AROWS 3200              // padded rows for MFMA A-side staging

typedef unsigned short u16;
typedef __attribute__((ext_vector_type(8))) short bf16x8;
typedef __attribute__((ext_vector_type(4))) float f32x4;

#define FLAG_ACC 1
#define FLAG_RELU 2
#define FLAG_SPLIT 4

__device__ __forceinline__ u16 f2b(float f) {
    unsigned u = __float_as_uint(f);
    u = (u + 0x7fffu + ((u >> 16) & 1u)) >> 16;
    return (u16)u;
}
__device__ __forceinline__ float b2f(u16 u) { return __uint_as_float(((unsigned)u) << 16); }

__device__ __forceinline__ void gld16(const void* g, void* l) {
    __builtin_amdgcn_global_load_lds((const __attribute__((address_space(1))) void*)g,
                                     (__attribute__((address_space(3))) void*)l, 16, 0, 0);
}

// ---------------- split-bf16 MFMA GEMM (exonerated; Hopfield only) ----------------
__global__ __launch_bounds__(256) void gemm_split(
    const u16* __restrict__ Ah, const u16* __restrict__ Al,
    const u16* __restrict__ Bh, const u16* __restrict__ Bl,
    void* __restrict__ Cv, u16* __restrict__ Cl, const float* __restrict__ bias,
    int M, int N, int K, int lda, int ldbt, int ldc, int flags) {
    __shared__ __align__(16) u16 AsH[128 * 32];
    __shared__ __align__(16) u16 AsL[128 * 32];
    __shared__ __align__(16) u16 BsH[128 * 32];
    __shared__ __align__(16) u16 BsL[128 * 32];
    int t = threadIdx.x;
    int w = t >> 6, lane = t & 63;
    int lr = lane & 15, lg = lane >> 4, ko = lg * 8;
    int wr = w >> 1, wc = w & 1;
    long row0 = (long)blockIdx.y * 128, col0 = (long)blockIdx.x * 128;

    f32x4 acc[4][4];
#pragma unroll
    for (int i = 0; i < 4; i++)
#pragma unroll
        for (int j = 0; j < 4; j++) acc[i][j] = (f32x4){0.f, 0.f, 0.f, 0.f};

    int c0 = w * 64 + lane;
    int r0s = c0 >> 2, k0s = (c0 & 3) << 3;
    int c1 = 256 + w * 64 + lane;
    int r1s = c1 >> 2, k1s = (c1 & 3) << 3;

    for (int kt = 0; kt < K; kt += 32) {
        const u16* AhB = Ah + row0 * lda + kt;
        const u16* AlB = Al + row0 * lda + kt;
        const u16* BhB = Bh + col0 * ldbt + kt;
        const u16* BlB = Bl + col0 * ldbt + kt;
        gld16(AhB + (long)r0s * lda + k0s, (char*)AsH + (w * 64) * 16);
        gld16(AhB + (long)r1s * lda + k1s, (char*)AsH + (256 + w * 64) * 16);
        gld16(AlB + (long)r0s * lda + k0s, (char*)AsL + (w * 64) * 16);
        gld16(AlB + (long)r1s * lda + k1s, (char*)AsL + (256 + w * 64) * 16);
        gld16(BhB + (long)r0s * ldbt + k0s, (char*)BsH + (w * 64) * 16);
        gld16(BhB + (long)r1s * ldbt + k1s, (char*)BsH + (256 + w * 64) * 16);
        gld16(BlB + (long)r0s * ldbt + k0s, (char*)BsL + (w * 64) * 16);
        gld16(BlB + (long)r1s * ldbt + k1s, (char*)BsL + (256 + w * 64) * 16);
        __syncthreads();
        bf16x8 afh[4], afl[4], bfh[4], bfl[4];
#pragma unroll
        for (int mi = 0; mi < 4; mi++) {
            int o = (wr * 64 + mi * 16 + lr) * 32 + ko;
            afh[mi] = *(const bf16x8*)&AsH[o];
            afl[mi] = *(const bf16x8*)&AsL[o];
        }
#pragma unroll
        for (int ni = 0; ni < 4; ni++) {
            int o = (wc * 64 + ni * 16 + lr) * 32 + ko;
            bfh[ni] = *(const bf16x8*)&BsH[o];
            bfl[ni] = *(const bf16x8*)&BsL[o];
        }
#pragma unroll
        for (int mi = 0; mi < 4; mi++)
#pragma unroll
            for (int ni = 0; ni < 4; ni++) {
                acc[mi][ni] = __builtin_amdgcn_mfma_f32_16x16x32_bf16(afl[mi], bfh[ni], acc[mi][ni], 0, 0, 0);
                acc[mi][ni] = __builtin_amdgcn_mfma_f32_16x16x32_bf16(afh[mi], bfl[ni], acc[mi][ni], 0, 0, 0);
                acc[mi][ni] = __builtin_amdgcn_mfma_f32_16x16x32_bf16(afh[mi], bfh[ni], acc[mi][ni], 0, 0, 0);
            }
        __syncthreads();
    }

    long mbase = row0 + wr * 64;
    long nbase = col0 + wc * 64;
#pragma unroll
    for (int mi = 0; mi < 4; mi++) {
#pragma unroll
        for (int r = 0; r < 4; r++) {
            long grow = mbase + mi * 16 + lg * 4 + r;
            if (grow >= M) continue;
#pragma unroll
            for (int ni = 0; ni < 4; ni++) {
                long gcol = nbase + ni * 16 + lr;
                float v = acc[mi][ni][r];
                if (bias) v += bias[gcol];
                if (flags & FLAG_RELU) v = fmaxf(v, 0.f);
                long idx = grow * ldc + gcol;
                if (flags & FLAG_ACC) ((float*)Cv)[idx] += v;
                else if (flags & FLAG_SPLIT) {
                    u16 hv = f2b(v);
                    ((u16*)Cv)[idx] = hv;
                    Cl[idx] = f2b(v - b2f(hv));
                } else ((float*)Cv)[idx] = v;
            }
        }
    }
}

// ================= R6 f32 PIPELINE =================

__global__ __launch_bounds__(256) void patchify_kernel(const float* __restrict__ x, float* __restrict__ tok) {
    int idx = blockIdx.x * 256 + threadIdx.x;
    const int total = NB * NPATCH * D;
    if (idx >= total) return;
    int d = idx % D;
    int p = (idx / D) % NPATCH;
    int b = idx / (D * NPATCH);
    int c = d >> 8;
    int pi = (d >> 4) & 15;
    int pj = d & 15;
    int hp = p / 14, wp = p % 14;
    int row = hp * 16 + pi, col = wp * 16 + pj;
    tok[idx] = x[(((long)b * 3 + c) * 224 + row) * 224 + col];
}

__global__ __launch_bounds__(256) void cls_pos_kernel(float* __restrict__ h, const float* __restrict__ cls,
                                                      const float* __restrict__ pos) {
    int idx = blockIdx.x * 256 + threadIdx.x;
    const int total = NB * NTOK * D;
    if (idx >= total) return;
    int d = idx % D;
    int n = (idx / D) % NTOK;
    float v = pos[n * D + d];
    if (n == 0) h[idx] = cls[d] + v;
    else        h[idx] = h[idx] + v;
}

__global__ __launch_bounds__(256) void wcat_kernel(const float* __restrict__ w, float* __restrict__ Wm) {
    int idx = blockIdx.x * 256 + threadIdx.x;
    const int total = NH * D * HD;
    if (idx >= total) return;
    int k = idx & 63;
    int d = (idx >> 6) % D;
    int hh = idx / (D * HD);
    Wm[d * D + hh * HD + k] = w[idx];
}

__global__ __launch_bounds__(256) void transpose_kernel(const float* __restrict__ src, float* __restrict__ dst,
                                                        int R, int C, long sStride, long dStride) {
    __shared__ float tile[32][33];
    const float* s = src + (long)blockIdx.z * sStride;
    float* d = dst + (long)blockIdx.z * dStride;
    int c0 = blockIdx.x * 32, r0 = blockIdx.y * 32;
    int tx = threadIdx.x % 32, ty = threadIdx.x / 32;
    for (int i = ty; i < 32; i += 8) {
        int r = r0 + i, c = c0 + tx;
        tile[i][tx] = (r < R && c < C) ? s[(long)r * C + c] : 0.f;
    }
    __syncthreads();
    for (int i = ty; i < 32; i += 8) {
        int c = c0 + i, r = r0 + tx;
        if (c < C && r < R) d[(long)c * R + r] = tile[tx][i];
    }
}

// ln: f32 out + OPTIONAL split bf16 out (for the Hopfield gemm_split)
__global__ __launch_bounds__(256) void ln_kernel(const float* __restrict__ X, float* __restrict__ Y,
                                                 u16* __restrict__ Yh, u16* __restrict__ Yl,
                                                 const float* __restrict__ gamma, const float* __restrict__ beta,
                                                 int compact) {
    int r = blockIdx.x;
    long xrow = compact ? ((long)(r / NPATCH) * NTOK + 1 + (r % NPATCH)) : (long)r;
    const float* x = X + xrow * D;
    float* y = Y + (long)r * D;
    int t = threadIdx.x;
    float v[3];
    float s = 0.f, ss = 0.f;
#pragma unroll
    for (int i = 0; i < 3; i++) {
        v[i] = x[t + 256 * i];
        s += v[i];
        ss += v[i] * v[i];
    }
    __shared__ float red[8];
    for (int off = 32; off; off >>= 1) {
        s += __shfl_down(s, off, 64);
        ss += __shfl_down(ss, off, 64);
    }
    int wid = t >> 6, lane = t & 63;
    if (lane == 0) { red[wid] = s; red[4 + wid] = ss; }
    __syncthreads();
    s = red[0] + red[1] + red[2] + red[3];
    ss = red[4] + red[5] + red[6] + red[7];
    float mu = s * (1.f / 768.f);
    float var = ss * (1.f / 768.f) - mu * mu;
    float inv = rsqrtf(var + 1e-5f);
#pragma unroll
    for (int i = 0; i < 3; i++) {
        int c = t + 256 * i;
        float yv = gamma[c] * (v[i] - mu) * inv + beta[c];
        y[c] = yv;
        if (Yh) {
            u16 hv = f2b(yv);
            Yh[(long)r * D + c] = hv;
            Yl[(long)r * D + c] = f2b(yv - b2f(hv));
        }
    }
}

// ---------------- NEW: parallel f32 attention softmax ----------------
// grid (192 bh, 13 m-tiles), block 256 = 16 queries x 16 lanes.
// K-block staged in LDS (coalesced); dot order identical to R6's inner loop.
__global__ __launch_bounds__(256) void attn_p_kernel(const float* __restrict__ Q, const float* __restrict__ K,
                                                     float* __restrict__ Pt, float* __restrict__ Pn) {
    __shared__ float Ks[NTOK][68];
    int bh = blockIdx.x, mt = blockIdx.y;
    int b = bh / NH, h = bh % NH;
    int t = threadIdx.x;
    const float* Kb = K + (long)b * NTOK * D + h * HD;
    for (int i = t; i < NTOK * 16; i += 256) {
        int n = i >> 4, k4 = (i & 15) << 2;
        float4 v = *(const float4*)(Kb + (long)n * D + k4);
        Ks[n][k4] = v.x; Ks[n][k4 + 1] = v.y; Ks[n][k4 + 2] = v.z; Ks[n][k4 + 3] = v.w;
    }
    __syncthreads();
    int ql = t >> 4, l16 = t & 15;
    int m = mt * 16 + ql;
    int mr = m < NTOK ? m : NTOK - 1;
    const float* Qrow = Q + (long)(b * NTOK + mr) * D + h * HD;
    float q[64];
#pragma unroll
    for (int k = 0; k < 64; k += 4) {
        float4 v = *(const float4*)(Qrow + k);
        q[k] = v.x; q[k + 1] = v.y; q[k + 2] = v.z; q[k + 3] = v.w;
    }
    float s[13];
    float mx = -1e30f;
#pragma unroll
    for (int i = 0; i < 13; i++) {
        int n = i * 16 + l16;
        const float* kr = Ks[n < NTOK ? n : 0];
        float a0 = 0.f, a1 = 0.f, a2 = 0.f, a3 = 0.f;
#pragma unroll
        for (int k = 0; k < 64; k += 4) {
            a0 += kr[k] * q[k];
            a1 += kr[k + 1] * q[k + 1];
            a2 += kr[k + 2] * q[k + 2];
            a3 += kr[k + 3] * q[k + 3];
        }
        float sv = ((a0 + a1) + (a2 + a3)) * BETA_F;
        s[i] = (n < NTOK) ? sv : -1e30f;
        mx = fmaxf(mx, s[i]);
    }
    mx = fmaxf(mx, __shfl_xor(mx, 1, 64));
    mx = fmaxf(mx, __shfl_xor(mx, 2, 64));
    mx = fmaxf(mx, __shfl_xor(mx, 4, 64));
    mx = fmaxf(mx, __shfl_xor(mx, 8, 64));
    float ssum = 0.f;
#pragma unroll
    for (int i = 0; i < 13; i++) {
        float e = (s[i] > -1e29f) ? __expf(s[i] - mx) : 0.f;
        s[i] = e;
        ssum += e;
    }
    ssum += __shfl_xor(ssum, 1, 64);
    ssum += __shfl_xor(ssum, 2, 64);
    ssum += __shfl_xor(ssum, 4, 64);
    ssum += __shfl_xor(ssum, 8, 64);
    float inv = 1.f / ssum;
    if (m < NTOK) {
        float* PtB = Pt + (long)bh * PBH;
        float* PnB = Pn + (long)bh * PBH;
#pragma unroll
        for (int i = 0; i < 13; i++) {
            int n = i * 16 + l16;
            if (n < NTOK) {
                float p = s[i] * inv;
                PtB[(long)m * PLD + n] = p;
                PnB[(long)n * PLD + m] = p;
            }
        }
    }
}

__global__ __launch_bounds__(256) void gemm_f32(
    const float* __restrict__ A, const float* __restrict__ B, float* __restrict__ C,
    const float* __restrict__ bias,
    int M, int N, int K, int lda, int ldb, int ldc,
    int zdiv, long sA1, long sA2, long sB1, long sB2, long sC1, long sC2,
    int flags) {
    int z = blockIdx.z;
    int z1 = z / zdiv, z2 = z - z1 * zdiv;
    A += (long)z1 * sA1 + (long)z2 * sA2;
    B += (long)z1 * sB1 + (long)z2 * sB2;
    C += (long)z1 * sC1 + (long)z2 * sC2;

    __shared__ float As[16][68];
    __shared__ float Bs[16][68];

    int t = threadIdx.x;
    int tx = t & 15, ty = t >> 4;
    int row0 = blockIdx.y * 64, col0 = blockIdx.x * 64;

    float acc[4][4] = {};

    for (int kt = 0; kt < K; kt += 16) {
        {
            int r = t >> 2;
            int c4 = (t & 3) << 2;
            int gr = row0 + r;
            int gk = kt + c4;
            float4 v = make_float4(0.f, 0.f, 0.f, 0.f);
            if (gr < M) {
                if (gk + 3 < K) {
                    v = *(const float4*)(A + (long)gr * lda + gk);
                } else {
                    float x0 = (gk < K) ? A[(long)gr * lda + gk] : 0.f;
                    float x1 = (gk + 1 < K) ? A[(long)gr * lda + gk + 1] : 0.f;
                    float x2 = (gk + 2 < K) ? A[(long)gr * lda + gk + 2] : 0.f;
                    float x3 = (gk + 3 < K) ? A[(long)gr * lda + gk + 3] : 0.f;
                    v = make_float4(x0, x1, x2, x3);
                }
            }
            As[c4 + 0][r] = v.x; As[c4 + 1][r] = v.y; As[c4 + 2][r] = v.z; As[c4 + 3][r] = v.w;
        }
        {
            int r = t >> 4;
            int c4 = (t & 15) << 2;
            int gk = kt + r;
            int gc = col0 + c4;
            float4 v = make_float4(0.f, 0.f, 0.f, 0.f);
            if (gk < K && gc + 3 < N) {
                v = *(const float4*)(B + (long)gk * ldb + gc);
            }
            Bs[r][c4 + 0] = v.x; Bs[r][c4 + 1] = v.y; Bs[r][c4 + 2] = v.z; Bs[r][c4 + 3] = v.w;
        }
        __syncthreads();
#pragma unroll
        for (int kk = 0; kk < 16; kk++) {
            float av[4], bv[4];
#pragma unroll
            for (int i = 0; i < 4; i++) av[i] = As[kk][ty * 4 + i];
#pragma unroll
            for (int j = 0; j < 4; j++) bv[j] = Bs[kk][tx * 4 + j];
#pragma unroll
            for (int i = 0; i < 4; i++)
#pragma unroll
                for (int j = 0; j < 4; j++) acc[i][j] += av[i] * bv[j];
        }
        __syncthreads();
    }
#pragma unroll
    for (int i = 0; i < 4; i++) {
        int gr = row0 + ty * 4 + i;
        if (gr >= M) continue;
#pragma unroll
        for (int j = 0; j < 4; j++) {
            int gc = col0 + tx * 4 + j;
            if (gc >= N) continue;
            float v = acc[i][j];
            if (bias) v += bias[gc];
            if (flags & 2) v = fmaxf(v, 0.f);
            long idx = (long)gr * ldc + gc;
            if (flags & 1) C[idx] += v;
            else C[idx] = v;
        }
    }
}

// split prep for xi
__global__ __launch_bounds__(256) void prep_transpose(const float* __restrict__ src,
                                                      u16* __restrict__ dh, u16* __restrict__ dl, int R, int C) {
    int idx = blockIdx.x * 256 + threadIdx.x;
    if (idx >= R * C) return;
    int r = idx % R, c = idx / R;
    float v = src[(long)r * C + c];
    u16 hv = f2b(v);
    dh[idx] = hv;
    dl[idx] = f2b(v - b2f(hv));
}
__global__ __launch_bounds__(256) void prep_convert(const float* __restrict__ src,
                                                    u16* __restrict__ dh, u16* __restrict__ dl, int n) {
    int idx = blockIdx.x * 256 + threadIdx.x;
    if (idx >= n) return;
    float v = src[idx];
    u16 hv = f2b(v);
    dh[idx] = hv;
    dl[idx] = f2b(v - b2f(hv));
}

extern "C" void kernel_launch(void* const* d_in, const int* in_sizes, int n_in,
                              void* d_out, int out_size, void* d_ws, size_t ws_size,
                              hipStream_t stream) {
    const float* x        = (const float*)d_in[0];
    const float* patch_w  = (const float*)d_in[1];
    const float* patch_b  = (const float*)d_in[2];
    const float* cls_tok  = (const float*)d_in[3];
    const float* pos_emb  = (const float*)d_in[4];
    const float* ln_gamma = (const float*)d_in[5];
    const float* ln_beta  = (const float*)d_in[6];
    const float* wq       = (const float*)d_in[7];
    const float* wk       = (const float*)d_in[8];
    const float* xi       = (const float*)d_in[9];
    const float* out_gamma= (const float*)d_in[10];
    const float* out_beta = (const float*)d_in[11];
    const float* out_w    = (const float*)d_in[12];
    const float* out_b    = (const float*)d_in[13];
    float* out = (float*)d_out;

    float* ws = (float*)d_ws;
    const long SZ = (long)NB * NTOK * D;
    float* h   = ws;
    float* g   = ws + SZ;
    float* Qb  = ws + 2 * SZ;
    float* Kb  = ws + 3 * SZ;
    float* G1  = ws + 4 * SZ;
    float* G2  = ws + 5 * SZ;
    float* Wq  = ws + 6 * SZ;
    float* Wk  = Wq + (long)D * D;
    float* WqT = Wk + (long)D * D;
    float* WkT = WqT + (long)D * D;
    // split buffers
    u16* gh   = (u16*)(WkT + (long)D * D);
    u16* gl   = gh + (long)AROWS * D;
    u16* xiTh = gl + (long)AROWS * D;
    u16* xiTl = xiTh + (long)HOP * D;
    u16* xibh = xiTl + (long)HOP * D;
    u16* xibl = xibh + (long)HOP * D;
    // shared region: {Pt,Pn} | {HHh,HHl} | tok
    float* R1 = (float*)(xibl + (long)HOP * D);
    float* Pt = R1;
    float* Pn = R1 + (long)NB * NH * PBH;
    u16* HHh  = (u16*)R1;
    u16* HHl  = HHh + (long)AROWS * HOP;
    float* tok = R1;

    auto gemm = [&](const float* A, const float* B, float* C, const float* bias,
                    int M, int N, int K, int lda, int ldb, int ldc,
                    int gz, int zdiv, long sA1, long sA2, long sB1, long sB2,
                    long sC1, long sC2, int flags) {
        dim3 grid((N + 63) / 64, (M + 63) / 64, gz);
        gemm_f32<<<grid, 256, 0, stream>>>(A, B, C, bias, M, N, K, lda, ldb, ldc,
                                           zdiv, sA1, sA2, sB1, sB2, sC1, sC2, flags);
    };

    // ---- setup (R6-verbatim) ----
    patchify_kernel<<<(NB * NPATCH * D + 255) / 256, 256, 0, stream>>>(x, tok);
    wcat_kernel<<<(NH * D * HD + 255) / 256, 256, 0, stream>>>(wq, Wq);
    wcat_kernel<<<(NH * D * HD + 255) / 256, 256, 0, stream>>>(wk, Wk);
    transpose_kernel<<<dim3(2, 24, 12), 256, 0, stream>>>(wq, WqT, D, HD, (long)D * HD, (long)HD * D);
    transpose_kernel<<<dim3(2, 24, 12), 256, 0, stream>>>(wk, WkT, D, HD, (long)D * HD, (long)HD * D);
    prep_transpose<<<(D * HOP + 255) / 256, 256, 0, stream>>>(xi, xiTh, xiTl, D, HOP);
    prep_convert<<<(D * HOP + 255) / 256, 256, 0, stream>>>(xi, xibh, xibl, D * HOP);
    gemm(tok, patch_w, h + D, patch_b, NPATCH, D, D, D, D, D,
         NB, 1, (long)NPATCH * D, 0, 0, 0, (long)NTOK * D, 0, 0);
    cls_pos_kernel<<<(NB * NTOK * D + 255) / 256, 256, 0, stream>>>(h, cls_tok, pos_emb);

    for (int step = 0; step < TSTEPS; step++) {
        ln_kernel<<<NB * NTOK, 256, 0, stream>>>(h, g, gh, gl, ln_gamma, ln_beta, 0);
        gemm(g, Wq, Qb, nullptr, NROWS, D, D, D, D, D, 1, 1, 0, 0, 0, 0, 0, 0, 0);
        gemm(g, Wk, Kb, nullptr, NROWS, D, D, D, D, D, 1, 1, 0, 0, 0, 0, 0, 0, 0);
        // NEW: parallel f32 softmax (replaces the 312us serial kernel)
        attn_p_kernel<<<dim3(192, 13), 256, 0, stream>>>(Qb, Kb, Pt, Pn);
        gemm(Pt, Kb, G1, nullptr, NTOK, HD, NTOK, PLD, D, D,
             NB * NH, NH, (long)NH * PBH, PBH, (long)NTOK * D, HD, (long)NTOK * D, HD, 0);
        gemm(Pn, Qb, G2, nullptr, NTOK, HD, NTOK, PLD, D, D,
             NB * NH, NH, (long)NH * PBH, PBH, (long)NTOK * D, HD, (long)NTOK * D, HD, 0);
        gemm(G1, WqT, h, nullptr, NROWS, D, D, D, D, D, 1, 1, 0, 0, 0, 0, 0, 0, 1);
        gemm(G2, WkT, h, nullptr, NROWS, D, D, D, D, D, 1, 1, 0, 0, 0, 0, 0, 0, 1);
        // Hopfield via gemm_split (exonerated)
        {
            dim3 g1(HOP / 128, (NROWS + 127) / 128, 1);
            gemm_split<<<g1, 256, 0, stream>>>(gh, gl, xiTh, xiTl, HHh, HHl, nullptr,
                                               NROWS, HOP, D, D, D, HOP, FLAG_SPLIT | FLAG_RELU);
            dim3 g2(D / 128, (NROWS + 127) / 128, 1);
            gemm_split<<<g2, 256, 0, stream>>>(HHh, HHl, xibh, xibl, h, nullptr, nullptr,
                                               NROWS, D, HOP, HOP, HOP, D, FLAG_ACC);
        }
    }

    // ---- final LN (compact, f32) + output projection ----
    ln_kernel<<<NB * NPATCH, 256, 0, stream>>>(h, g, nullptr, nullptr, out_gamma, out_beta, 1);
    gemm(g, out_w, out, out_b, NPROWS, D, D, D, D, D, 1, 1, 0, 0, 0, 0, 0, 0, 0);
}

// Round 9
// 3417.756 us; speedup vs baseline: 2.0703x; 1.2309x over previous
//
#include <hip/hip_runtime.h>

#define NB 16
#define NTOK 197
#define NPATCH 196
#define D 768
#define NH 12
#define HD 64
#define HOP 3072
#define TSTEPS 6
#define BETA_F 0.125f
#define PLD 208                 // P leading dim (f32)
#define PBH (NTOK * PLD)        // 40976
#define NROWS (NB * NTOK)       // 3152
#define NPROWS (NB * NPATCH)    // 3136
#define AROWS 3200              // padded rows for MFMA A-side staging
#define DD (768 * 768)

typedef unsigned short u16;
typedef __attribute__((ext_vector_type(8))) short bf16x8;
typedef __attribute__((ext_vector_type(4))) float f32x4;

#define FLAG_ACC 1
#define FLAG_RELU 2
#define FLAG_SPLIT 4

__device__ __forceinline__ u16 f2b(float f) {
    unsigned u = __float_as_uint(f);
    u = (u + 0x7fffu + ((u >> 16) & 1u)) >> 16;
    return (u16)u;
}
__device__ __forceinline__ float b2f(u16 u) { return __uint_as_float(((unsigned)u) << 16); }

__device__ __forceinline__ void gld16(const void* g, void* l) {
    __builtin_amdgcn_global_load_lds((const __attribute__((address_space(1))) void*)g,
                                     (__attribute__((address_space(3))) void*)l, 16, 0, 0);
}

// ---------------- split-bf16 MFMA GEMM (exonerated core; + z-stride batching) ----------------
__global__ __launch_bounds__(256) void gemm_split(
    const u16* __restrict__ Ah, const u16* __restrict__ Al,
    const u16* __restrict__ Bh, const u16* __restrict__ Bl,
    void* __restrict__ Cv, u16* __restrict__ Cl, const float* __restrict__ bias,
    int M, int N, int K, int lda, int ldbt, int ldc, int flags,
    long sAz, long sBz, long sCz) {
    __shared__ __align__(16) u16 AsH[128 * 32];
    __shared__ __align__(16) u16 AsL[128 * 32];
    __shared__ __align__(16) u16 BsH[128 * 32];
    __shared__ __align__(16) u16 BsL[128 * 32];
    int zz = blockIdx.z;
    Ah += (long)zz * sAz; Al += (long)zz * sAz;
    Bh += (long)zz * sBz; Bl += (long)zz * sBz;
    long czoff = (long)zz * sCz;
    int t = threadIdx.x;
    int w = t >> 6, lane = t & 63;
    int lr = lane & 15, lg = lane >> 4, ko = lg * 8;
    int wr = w >> 1, wc = w & 1;
    long row0 = (long)blockIdx.y * 128, col0 = (long)blockIdx.x * 128;

    f32x4 acc[4][4];
#pragma unroll
    for (int i = 0; i < 4; i++)
#pragma unroll
        for (int j = 0; j < 4; j++) acc[i][j] = (f32x4){0.f, 0.f, 0.f, 0.f};

    int c0 = w * 64 + lane;
    int r0s = c0 >> 2, k0s = (c0 & 3) << 3;
    int c1 = 256 + w * 64 + lane;
    int r1s = c1 >> 2, k1s = (c1 & 3) << 3;

    for (int kt = 0; kt < K; kt += 32) {
        const u16* AhB = Ah + row0 * lda + kt;
        const u16* AlB = Al + row0 * lda + kt;
        const u16* BhB = Bh + col0 * ldbt + kt;
        const u16* BlB = Bl + col0 * ldbt + kt;
        gld16(AhB + (long)r0s * lda + k0s, (char*)AsH + (w * 64) * 16);
        gld16(AhB + (long)r1s * lda + k1s, (char*)AsH + (256 + w * 64) * 16);
        gld16(AlB + (long)r0s * lda + k0s, (char*)AsL + (w * 64) * 16);
        gld16(AlB + (long)r1s * lda + k1s, (char*)AsL + (256 + w * 64) * 16);
        gld16(BhB + (long)r0s * ldbt + k0s, (char*)BsH + (w * 64) * 16);
        gld16(BhB + (long)r1s * ldbt + k1s, (char*)BsH + (256 + w * 64) * 16);
        gld16(BlB + (long)r0s * ldbt + k0s, (char*)BsL + (w * 64) * 16);
        gld16(BlB + (long)r1s * ldbt + k1s, (char*)BsL + (256 + w * 64) * 16);
        __syncthreads();
        bf16x8 afh[4], afl[4], bfh[4], bfl[4];
#pragma unroll
        for (int mi = 0; mi < 4; mi++) {
            int o = (wr * 64 + mi * 16 + lr) * 32 + ko;
            afh[mi] = *(const bf16x8*)&AsH[o];
            afl[mi] = *(const bf16x8*)&AsL[o];
        }
#pragma unroll
        for (int ni = 0; ni < 4; ni++) {
            int o = (wc * 64 + ni * 16 + lr) * 32 + ko;
            bfh[ni] = *(const bf16x8*)&BsH[o];
            bfl[ni] = *(const bf16x8*)&BsL[o];
        }
#pragma unroll
        for (int mi = 0; mi < 4; mi++)
#pragma unroll
            for (int ni = 0; ni < 4; ni++) {
                acc[mi][ni] = __builtin_amdgcn_mfma_f32_16x16x32_bf16(afl[mi], bfh[ni], acc[mi][ni], 0, 0, 0);
                acc[mi][ni] = __builtin_amdgcn_mfma_f32_16x16x32_bf16(afh[mi], bfl[ni], acc[mi][ni], 0, 0, 0);
                acc[mi][ni] = __builtin_amdgcn_mfma_f32_16x16x32_bf16(afh[mi], bfh[ni], acc[mi][ni], 0, 0, 0);
            }
        __syncthreads();
    }

    long mbase = row0 + wr * 64;
    long nbase = col0 + wc * 64;
#pragma unroll
    for (int mi = 0; mi < 4; mi++) {
#pragma unroll
        for (int r = 0; r < 4; r++) {
            long grow = mbase + mi * 16 + lg * 4 + r;
            if (grow >= M) continue;
#pragma unroll
            for (int ni = 0; ni < 4; ni++) {
                long gcol = nbase + ni * 16 + lr;
                float v = acc[mi][ni][r];
                if (bias) v += bias[gcol];
                if (flags & FLAG_RELU) v = fmaxf(v, 0.f);
                long idx = czoff + grow * ldc + gcol;
                if (flags & FLAG_ACC) ((float*)Cv)[idx] += v;
                else if (flags & FLAG_SPLIT) {
                    u16 hv = f2b(v);
                    ((u16*)Cv)[idx] = hv;
                    Cl[idx] = f2b(v - b2f(hv));
                } else ((float*)Cv)[idx] = v;
            }
        }
    }
}

// ================= f32 PIPELINE PIECES (R0/R6/R8-verbatim) =================

__global__ __launch_bounds__(256) void patchify_kernel(const float* __restrict__ x, float* __restrict__ tok) {
    int idx = blockIdx.x * 256 + threadIdx.x;
    const int total = NB * NPATCH * D;
    if (idx >= total) return;
    int d = idx % D;
    int p = (idx / D) % NPATCH;
    int b = idx / (D * NPATCH);
    int c = d >> 8;
    int pi = (d >> 4) & 15;
    int pj = d & 15;
    int hp = p / 14, wp = p % 14;
    int row = hp * 16 + pi, col = wp * 16 + pj;
    tok[idx] = x[(((long)b * 3 + c) * 224 + row) * 224 + col];
}

__global__ __launch_bounds__(256) void cls_pos_kernel(float* __restrict__ h, const float* __restrict__ cls,
                                                      const float* __restrict__ pos) {
    int idx = blockIdx.x * 256 + threadIdx.x;
    const int total = NB * NTOK * D;
    if (idx >= total) return;
    int d = idx % D;
    int n = (idx / D) % NTOK;
    float v = pos[n * D + d];
    if (n == 0) h[idx] = cls[d] + v;
    else        h[idx] = h[idx] + v;
}

__global__ __launch_bounds__(256) void wcat_kernel(const float* __restrict__ w, float* __restrict__ Wm) {
    int idx = blockIdx.x * 256 + threadIdx.x;
    const int total = NH * D * HD;
    if (idx >= total) return;
    int k = idx & 63;
    int d = (idx >> 6) % D;
    int hh = idx / (D * HD);
    Wm[d * D + hh * HD + k] = w[idx];
}

__global__ __launch_bounds__(256) void transpose_kernel(const float* __restrict__ src, float* __restrict__ dst,
                                                        int R, int C, long sStride, long dStride) {
    __shared__ float tile[32][33];
    const float* s = src + (long)blockIdx.z * sStride;
    float* d = dst + (long)blockIdx.z * dStride;
    int c0 = blockIdx.x * 32, r0 = blockIdx.y * 32;
    int tx = threadIdx.x % 32, ty = threadIdx.x / 32;
    for (int i = ty; i < 32; i += 8) {
        int r = r0 + i, c = c0 + tx;
        tile[i][tx] = (r < R && c < C) ? s[(long)r * C + c] : 0.f;
    }
    __syncthreads();
    for (int i = ty; i < 32; i += 8) {
        int c = c0 + i, r = r0 + tx;
        if (c < C && r < R) d[(long)c * R + r] = tile[tx][i];
    }
}

// ln: f32 out + OPTIONAL split bf16 out
__global__ __launch_bounds__(256) void ln_kernel(const float* __restrict__ X, float* __restrict__ Y,
                                                 u16* __restrict__ Yh, u16* __restrict__ Yl,
                                                 const float* __restrict__ gamma, const float* __restrict__ beta,
                                                 int compact) {
    int r = blockIdx.x;
    long xrow = compact ? ((long)(r / NPATCH) * NTOK + 1 + (r % NPATCH)) : (long)r;
    const float* x = X + xrow * D;
    float* y = Y + (long)r * D;
    int t = threadIdx.x;
    float v[3];
    float s = 0.f, ss = 0.f;
#pragma unroll
    for (int i = 0; i < 3; i++) {
        v[i] = x[t + 256 * i];
        s += v[i];
        ss += v[i] * v[i];
    }
    __shared__ float red[8];
    for (int off = 32; off; off >>= 1) {
        s += __shfl_down(s, off, 64);
        ss += __shfl_down(ss, off, 64);
    }
    int wid = t >> 6, lane = t & 63;
    if (lane == 0) { red[wid] = s; red[4 + wid] = ss; }
    __syncthreads();
    s = red[0] + red[1] + red[2] + red[3];
    ss = red[4] + red[5] + red[6] + red[7];
    float mu = s * (1.f / 768.f);
    float var = ss * (1.f / 768.f) - mu * mu;
    float inv = rsqrtf(var + 1e-5f);
#pragma unroll
    for (int i = 0; i < 3; i++) {
        int c = t + 256 * i;
        float yv = gamma[c] * (v[i] - mu) * inv + beta[c];
        y[c] = yv;
        if (Yh) {
            u16 hv = f2b(yv);
            Yh[(long)r * D + c] = hv;
            Yl[(long)r * D + c] = f2b(yv - b2f(hv));
        }
    }
}

// ---------------- parallel f32 attention softmax (R8-verbatim) ----------------
__global__ __launch_bounds__(256) void attn_p_kernel(const float* __restrict__ Q, const float* __restrict__ K,
                                                     float* __restrict__ Pt, float* __restrict__ Pn) {
    __shared__ float Ks[NTOK][68];
    int bh = blockIdx.x, mt = blockIdx.y;
    int b = bh / NH, h = bh % NH;
    int t = threadIdx.x;
    const float* Kb = K + (long)b * NTOK * D + h * HD;
    for (int i = t; i < NTOK * 16; i += 256) {
        int n = i >> 4, k4 = (i & 15) << 2;
        float4 v = *(const float4*)(Kb + (long)n * D + k4);
        Ks[n][k4] = v.x; Ks[n][k4 + 1] = v.y; Ks[n][k4 + 2] = v.z; Ks[n][k4 + 3] = v.w;
    }
    __syncthreads();
    int ql = t >> 4, l16 = t & 15;
    int m = mt * 16 + ql;
    int mr = m < NTOK ? m : NTOK - 1;
    const float* Qrow = Q + (long)(b * NTOK + mr) * D + h * HD;
    float q[64];
#pragma unroll
    for (int k = 0; k < 64; k += 4) {
        float4 v = *(const float4*)(Qrow + k);
        q[k] = v.x; q[k + 1] = v.y; q[k + 2] = v.z; q[k + 3] = v.w;
    }
    float s[13];
    float mx = -1e30f;
#pragma unroll
    for (int i = 0; i < 13; i++) {
        int n = i * 16 + l16;
        const float* kr = Ks[n < NTOK ? n : 0];
        float a0 = 0.f, a1 = 0.f, a2 = 0.f, a3 = 0.f;
#pragma unroll
        for (int k = 0; k < 64; k += 4) {
            a0 += kr[k] * q[k];
            a1 += kr[k + 1] * q[k + 1];
            a2 += kr[k + 2] * q[k + 2];
            a3 += kr[k + 3] * q[k + 3];
        }
        float sv = ((a0 + a1) + (a2 + a3)) * BETA_F;
        s[i] = (n < NTOK) ? sv : -1e30f;
        mx = fmaxf(mx, s[i]);
    }
    mx = fmaxf(mx, __shfl_xor(mx, 1, 64));
    mx = fmaxf(mx, __shfl_xor(mx, 2, 64));
    mx = fmaxf(mx, __shfl_xor(mx, 4, 64));
    mx = fmaxf(mx, __shfl_xor(mx, 8, 64));
    float ssum = 0.f;
#pragma unroll
    for (int i = 0; i < 13; i++) {
        float e = (s[i] > -1e29f) ? __expf(s[i] - mx) : 0.f;
        s[i] = e;
        ssum += e;
    }
    ssum += __shfl_xor(ssum, 1, 64);
    ssum += __shfl_xor(ssum, 2, 64);
    ssum += __shfl_xor(ssum, 4, 64);
    ssum += __shfl_xor(ssum, 8, 64);
    float inv = 1.f / ssum;
    if (m < NTOK) {
        float* PtB = Pt + (long)bh * PBH;
        float* PnB = Pn + (long)bh * PBH;
#pragma unroll
        for (int i = 0; i < 13; i++) {
            int n = i * 16 + l16;
            if (n < NTOK) {
                float p = s[i] * inv;
                PtB[(long)m * PLD + n] = p;
                PnB[(long)n * PLD + m] = p;
            }
        }
    }
}

__global__ __launch_bounds__(256) void gemm_f32(
    const float* __restrict__ A, const float* __restrict__ B, float* __restrict__ C,
    const float* __restrict__ bias,
    int M, int N, int K, int lda, int ldb, int ldc,
    int zdiv, long sA1, long sA2, long sB1, long sB2, long sC1, long sC2,
    int flags) {
    int z = blockIdx.z;
    int z1 = z / zdiv, z2 = z - z1 * zdiv;
    A += (long)z1 * sA1 + (long)z2 * sA2;
    B += (long)z1 * sB1 + (long)z2 * sB2;
    C += (long)z1 * sC1 + (long)z2 * sC2;

    __shared__ float As[16][68];
    __shared__ float Bs[16][68];

    int t = threadIdx.x;
    int tx = t & 15, ty = t >> 4;
    int row0 = blockIdx.y * 64, col0 = blockIdx.x * 64;

    float acc[4][4] = {};

    for (int kt = 0; kt < K; kt += 16) {
        {
            int r = t >> 2;
            int c4 = (t & 3) << 2;
            int gr = row0 + r;
            int gk = kt + c4;
            float4 v = make_float4(0.f, 0.f, 0.f, 0.f);
            if (gr < M) {
                if (gk + 3 < K) {
                    v = *(const float4*)(A + (long)gr * lda + gk);
                } else {
                    float x0 = (gk < K) ? A[(long)gr * lda + gk] : 0.f;
                    float x1 = (gk + 1 < K) ? A[(long)gr * lda + gk + 1] : 0.f;
                    float x2 = (gk + 2 < K) ? A[(long)gr * lda + gk + 2] : 0.f;
                    float x3 = (gk + 3 < K) ? A[(long)gr * lda + gk + 3] : 0.f;
                    v = make_float4(x0, x1, x2, x3);
                }
            }
            As[c4 + 0][r] = v.x; As[c4 + 1][r] = v.y; As[c4 + 2][r] = v.z; As[c4 + 3][r] = v.w;
        }
        {
            int r = t >> 4;
            int c4 = (t & 15) << 2;
            int gk = kt + r;
            int gc = col0 + c4;
            float4 v = make_float4(0.f, 0.f, 0.f, 0.f);
            if (gk < K && gc + 3 < N) {
                v = *(const float4*)(B + (long)gk * ldb + gc);
            }
            Bs[r][c4 + 0] = v.x; Bs[r][c4 + 1] = v.y; Bs[r][c4 + 2] = v.z; Bs[r][c4 + 3] = v.w;
        }
        __syncthreads();
#pragma unroll
        for (int kk = 0; kk < 16; kk++) {
            float av[4], bv[4];
#pragma unroll
            for (int i = 0; i < 4; i++) av[i] = As[kk][ty * 4 + i];
#pragma unroll
            for (int j = 0; j < 4; j++) bv[j] = Bs[kk][tx * 4 + j];
#pragma unroll
            for (int i = 0; i < 4; i++)
#pragma unroll
                for (int j = 0; j < 4; j++) acc[i][j] += av[i] * bv[j];
        }
        __syncthreads();
    }
#pragma unroll
    for (int i = 0; i < 4; i++) {
        int gr = row0 + ty * 4 + i;
        if (gr >= M) continue;
#pragma unroll
        for (int j = 0; j < 4; j++) {
            int gc = col0 + tx * 4 + j;
            if (gc >= N) continue;
            float v = acc[i][j];
            if (bias) v += bias[gc];
            if (flags & 2) v = fmaxf(v, 0.f);
            long idx = (long)gr * ldc + gc;
            if (flags & 1) C[idx] += v;
            else C[idx] = v;
        }
    }
}

// split preps (exonerated R6 patterns)
__global__ __launch_bounds__(256) void prep_transpose(const float* __restrict__ src,
                                                      u16* __restrict__ dh, u16* __restrict__ dl, int R, int C) {
    int idx = blockIdx.x * 256 + threadIdx.x;
    if (idx >= R * C) return;
    int r = idx % R, c = idx / R;
    float v = src[(long)r * C + c];
    u16 hv = f2b(v);
    dh[idx] = hv;
    dl[idx] = f2b(v - b2f(hv));
}
__global__ __launch_bounds__(256) void prep_convert(const float* __restrict__ src,
                                                    u16* __restrict__ dh, u16* __restrict__ dl, int n) {
    int idx = blockIdx.x * 256 + threadIdx.x;
    if (idx >= n) return;
    float v = src[idx];
    u16 hv = f2b(v);
    dh[idx] = hv;
    dl[idx] = f2b(v - b2f(hv));
}

extern "C" void kernel_launch(void* const* d_in, const int* in_sizes, int n_in,
                              void* d_out, int out_size, void* d_ws, size_t ws_size,
                              hipStream_t stream) {
    const float* x        = (const float*)d_in[0];
    const float* patch_w  = (const float*)d_in[1];
    const float* patch_b  = (const float*)d_in[2];
    const float* cls_tok  = (const float*)d_in[3];
    const float* pos_emb  = (const float*)d_in[4];
    const float* ln_gamma = (const float*)d_in[5];
    const float* ln_beta  = (const float*)d_in[6];
    const float* wq       = (const float*)d_in[7];
    const float* wk       = (const float*)d_in[8];
    const float* xi       = (const float*)d_in[9];
    const float* out_gamma= (const float*)d_in[10];
    const float* out_beta = (const float*)d_in[11];
    const float* out_w    = (const float*)d_in[12];
    const float* out_b    = (const float*)d_in[13];
    float* out = (float*)d_out;

    float* ws = (float*)d_ws;
    const long SZ = (long)NB * NTOK * D;       // 2,420,736
    const long AR = (long)AROWS * D;           // 2,457,600
    const long DH = (long)D * HOP;             // 2,359,296
    float* h    = ws;
    float* g    = ws + SZ;
    float* Qb   = ws + 2 * SZ;
    float* Kb   = ws + 3 * SZ;                 // Qb,Kb adjacent: z-stride SZ
    float* G1   = ws + 4 * SZ;
    float* G2   = ws + 5 * SZ;
    float* WmQ  = ws + 6 * SZ;                 // [768 d][768 j] = wq[h_j,d,k_j]
    float* WmK  = WmQ + DD;
    float* WmQT = WmK + DD;                    // [768 j][768 d]
    float* WmKT = WmQT + DD;
    u16* gh     = (u16*)(WmKT + DD);
    u16* gl     = gh + AR;
    u16* WmQTh  = gl + AR;                     // pair for z-batch (WmKTh adjacent)
    u16* WmKTh  = WmQTh + DD;
    u16* WmQTl  = WmKTh + DD;
    u16* WmKTl  = WmQTl + DD;
    u16* WmQh   = WmKTl + DD;
    u16* WmQl   = WmQh + DD;
    u16* WmKh   = WmQl + DD;
    u16* WmKl   = WmKh + DD;
    u16* xiTh   = WmKl + DD;
    u16* xiTl   = xiTh + DH;
    u16* xibh   = xiTl + DH;
    u16* xibl   = xibh + DH;
    u16* G1h    = xibl + DH;
    u16* G1l    = G1h + AR;
    u16* G2h    = G1l + AR;
    u16* G2l    = G2h + AR;
    // shared region: {Pt,Pn} | {HHh,HHl} | tok
    float* R1 = (float*)(G2l + AR);
    float* Pt = R1;
    float* Pn = R1 + (long)NB * NH * PBH;
    u16* HHh  = (u16*)R1;
    u16* HHl  = HHh + (long)AROWS * HOP;
    float* tok = R1;

    auto gemm = [&](const float* A, const float* B, float* C, const float* bias,
                    int M, int N, int K, int lda, int ldb, int ldc,
                    int gz, int zdiv, long sA1, long sA2, long sB1, long sB2,
                    long sC1, long sC2, int flags) {
        dim3 grid((N + 63) / 64, (M + 63) / 64, gz);
        gemm_f32<<<grid, 256, 0, stream>>>(A, B, C, bias, M, N, K, lda, ldb, ldc,
                                           zdiv, sA1, sA2, sB1, sB2, sC1, sC2, flags);
    };

    // ---- setup ----
    patchify_kernel<<<(NB * NPATCH * D + 255) / 256, 256, 0, stream>>>(x, tok);
    wcat_kernel<<<(NH * D * HD + 255) / 256, 256, 0, stream>>>(wq, WmQ);
    wcat_kernel<<<(NH * D * HD + 255) / 256, 256, 0, stream>>>(wk, WmK);
    transpose_kernel<<<dim3(24, 24, 1), 256, 0, stream>>>(WmQ, WmQT, 768, 768, 0, 0);
    transpose_kernel<<<dim3(24, 24, 1), 256, 0, stream>>>(WmK, WmKT, 768, 768, 0, 0);
    prep_convert<<<(DD + 255) / 256, 256, 0, stream>>>(WmQT, WmQTh, WmQTl, DD);
    prep_convert<<<(DD + 255) / 256, 256, 0, stream>>>(WmKT, WmKTh, WmKTl, DD);
    prep_convert<<<(DD + 255) / 256, 256, 0, stream>>>(WmQ, WmQh, WmQl, DD);
    prep_convert<<<(DD + 255) / 256, 256, 0, stream>>>(WmK, WmKh, WmKl, DD);
    prep_transpose<<<(D * HOP + 255) / 256, 256, 0, stream>>>(xi, xiTh, xiTl, D, HOP);
    prep_convert<<<(D * HOP + 255) / 256, 256, 0, stream>>>(xi, xibh, xibl, D * HOP);
    gemm(tok, patch_w, h + D, patch_b, NPATCH, D, D, D, D, D,
         NB, 1, (long)NPATCH * D, 0, 0, 0, (long)NTOK * D, 0, 0);
    cls_pos_kernel<<<(NB * NTOK * D + 255) / 256, 256, 0, stream>>>(h, cls_tok, pos_emb);

    for (int step = 0; step < TSTEPS; step++) {
        ln_kernel<<<NB * NTOK, 256, 0, stream>>>(h, g, gh, gl, ln_gamma, ln_beta, 0);
        // Q|K projection in ONE z=2 launch: z=0 -> Qb (WmQT), z=1 -> Kb (WmKT). f32 out.
        gemm_split<<<dim3(6, 25, 2), 256, 0, stream>>>(
            gh, gl, WmQTh, WmQTl, Qb, nullptr, nullptr,
            NROWS, D, D, D, D, D, 0, /*sAz*/0, /*sBz*/DD, /*sCz*/SZ);
        attn_p_kernel<<<dim3(192, 13), 256, 0, stream>>>(Qb, Kb, Pt, Pn);
        gemm(Pt, Kb, G1, nullptr, NTOK, HD, NTOK, PLD, D, D,
             NB * NH, NH, (long)NH * PBH, PBH, (long)NTOK * D, HD, (long)NTOK * D, HD, 0);
        gemm(Pn, Qb, G2, nullptr, NTOK, HD, NTOK, PLD, D, D,
             NB * NH, NH, (long)NH * PBH, PBH, (long)NTOK * D, HD, (long)NTOK * D, HD, 0);
        // split G1/G2 (exonerated convert), then h += G1@WmQ^T ; h += G2@WmK^T (sequential: same output)
        prep_convert<<<((int)SZ + 255) / 256, 256, 0, stream>>>(G1, G1h, G1l, (int)SZ);
        prep_convert<<<((int)SZ + 255) / 256, 256, 0, stream>>>(G2, G2h, G2l, (int)SZ);
        gemm_split<<<dim3(6, 25, 1), 256, 0, stream>>>(
            G1h, G1l, WmQh, WmQl, h, nullptr, nullptr,
            NROWS, D, D, D, D, D, FLAG_ACC, 0, 0, 0);
        gemm_split<<<dim3(6, 25, 1), 256, 0, stream>>>(
            G2h, G2l, WmKh, WmKl, h, nullptr, nullptr,
            NROWS, D, D, D, D, D, FLAG_ACC, 0, 0, 0);
        // Hopfield (exonerated)
        gemm_split<<<dim3(24, 25, 1), 256, 0, stream>>>(
            gh, gl, xiTh, xiTl, HHh, HHl, nullptr,
            NROWS, HOP, D, D, D, HOP, FLAG_SPLIT | FLAG_RELU, 0, 0, 0);
        gemm_split<<<dim3(6, 25, 1), 256, 0, stream>>>(
            HHh, HHl, xibh, xibl, h, nullptr, nullptr,
            NROWS, D, HOP, HOP, HOP, D, FLAG_ACC, 0, 0, 0);
    }

    // ---- final LN (compact, f32) + output projection ----
    ln_kernel<<<NB * NPATCH, 256, 0, stream>>>(h, g, nullptr, nullptr, out_gamma, out_beta, 1);
    gemm(g, out_w, out, out_b, NPROWS, D, D, D, D, D, 1, 1, 0, 0, 0, 0, 0, 0, 0);
}

// Round 10
// 2497.347 us; speedup vs baseline: 2.8333x; 1.3686x over previous
//
#include <hip/hip_runtime.h>

#define NB 16
#define NTOK 197
#define NPATCH 196
#define D 768
#define NH 12
#define HD 64
#define HOP 3072
#define TSTEPS 6
#define BETA_F 0.125f
#define PLD 208                 // P leading dim (f32)
#define PBH (NTOK * PLD)        // 40976
#define NROWS (NB * NTOK)       // 3152
#define NPROWS (NB * NPATCH)    // 3136
#define AROWS 3200              // padded rows for MFMA A-side staging
#define DD (768 * 768)
#define DH (768 * 3072)

typedef unsigned short u16;
typedef __attribute__((ext_vector_type(8))) _Float16 f16x8;
typedef __attribute__((ext_vector_type(4))) float f32x4;

#define FLAG_ACC 1
#define FLAG_RELU 2
#define FLAG_H16 4

__device__ __forceinline__ u16 f2h(float f) {
    union { _Float16 h; u16 u; } cv;
    cv.h = (_Float16)f;
    return cv.u;
}

__device__ __forceinline__ void gld16(const void* g, void* l) {
    __builtin_amdgcn_global_load_lds((const __attribute__((address_space(1))) void*)g,
                                     (__attribute__((address_space(3))) void*)l, 16, 0, 0);
}

// ---------------- single-fp16 MFMA GEMM: C[M,N] (+)= A[M,K] * B[N,K]^T ----------------
// Same structure/wiring as the exonerated gemm_split; 1 MFMA per fragment pair.
__global__ __launch_bounds__(256) void gemm_h16(
    const u16* __restrict__ A, const u16* __restrict__ B,
    void* __restrict__ Cv, const float* __restrict__ bias,
    int M, int N, int K, int lda, int ldbt, int ldc, int flags,
    long sAz, long sBz, long sCz) {
    __shared__ __align__(16) u16 As[128 * 32];
    __shared__ __align__(16) u16 Bs[128 * 32];
    int zz = blockIdx.z;
    A += (long)zz * sAz;
    B += (long)zz * sBz;
    long czoff = (long)zz * sCz;
    int t = threadIdx.x;
    int w = t >> 6, lane = t & 63;
    int lr = lane & 15, lg = lane >> 4, ko = lg * 8;
    int wr = w >> 1, wc = w & 1;
    long row0 = (long)blockIdx.y * 128, col0 = (long)blockIdx.x * 128;

    f32x4 acc[4][4];
#pragma unroll
    for (int i = 0; i < 4; i++)
#pragma unroll
        for (int j = 0; j < 4; j++) acc[i][j] = (f32x4){0.f, 0.f, 0.f, 0.f};

    int c0 = w * 64 + lane;
    int r0s = c0 >> 2, k0s = (c0 & 3) << 3;
    int c1 = 256 + w * 64 + lane;
    int r1s = c1 >> 2, k1s = (c1 & 3) << 3;

    for (int kt = 0; kt < K; kt += 32) {
        const u16* AB = A + row0 * lda + kt;
        const u16* BB = B + col0 * ldbt + kt;
        gld16(AB + (long)r0s * lda + k0s, (char*)As + (w * 64) * 16);
        gld16(AB + (long)r1s * lda + k1s, (char*)As + (256 + w * 64) * 16);
        gld16(BB + (long)r0s * ldbt + k0s, (char*)Bs + (w * 64) * 16);
        gld16(BB + (long)r1s * ldbt + k1s, (char*)Bs + (256 + w * 64) * 16);
        __syncthreads();
        f16x8 af[4], bf[4];
#pragma unroll
        for (int mi = 0; mi < 4; mi++) af[mi] = *(const f16x8*)&As[(wr * 64 + mi * 16 + lr) * 32 + ko];
#pragma unroll
        for (int ni = 0; ni < 4; ni++) bf[ni] = *(const f16x8*)&Bs[(wc * 64 + ni * 16 + lr) * 32 + ko];
#pragma unroll
        for (int mi = 0; mi < 4; mi++)
#pragma unroll
            for (int ni = 0; ni < 4; ni++)
                acc[mi][ni] = __builtin_amdgcn_mfma_f32_16x16x32_f16(af[mi], bf[ni], acc[mi][ni], 0, 0, 0);
        __syncthreads();
    }

    long mbase = row0 + wr * 64;
    long nbase = col0 + wc * 64;
#pragma unroll
    for (int mi = 0; mi < 4; mi++) {
#pragma unroll
        for (int r = 0; r < 4; r++) {
            long grow = mbase + mi * 16 + lg * 4 + r;
            if (grow >= M) continue;
#pragma unroll
            for (int ni = 0; ni < 4; ni++) {
                long gcol = nbase + ni * 16 + lr;
                float v = acc[mi][ni][r];
                if (bias) v += bias[gcol];
                if (flags & FLAG_RELU) v = fmaxf(v, 0.f);
                long idx = czoff + grow * ldc + gcol;
                if (flags & FLAG_ACC) ((float*)Cv)[idx] += v;
                else if (flags & FLAG_H16) ((u16*)Cv)[idx] = f2h(v);
                else ((float*)Cv)[idx] = v;
            }
        }
    }
}

// ================= f32 PIPELINE PIECES (R9-verbatim) =================

__global__ __launch_bounds__(256) void patchify_kernel(const float* __restrict__ x, float* __restrict__ tok) {
    int idx = blockIdx.x * 256 + threadIdx.x;
    const int total = NB * NPATCH * D;
    if (idx >= total) return;
    int d = idx % D;
    int p = (idx / D) % NPATCH;
    int b = idx / (D * NPATCH);
    int c = d >> 8;
    int pi = (d >> 4) & 15;
    int pj = d & 15;
    int hp = p / 14, wp = p % 14;
    int row = hp * 16 + pi, col = wp * 16 + pj;
    tok[idx] = x[(((long)b * 3 + c) * 224 + row) * 224 + col];
}

__global__ __launch_bounds__(256) void cls_pos_kernel(float* __restrict__ h, const float* __restrict__ cls,
                                                      const float* __restrict__ pos) {
    int idx = blockIdx.x * 256 + threadIdx.x;
    const int total = NB * NTOK * D;
    if (idx >= total) return;
    int d = idx % D;
    int n = (idx / D) % NTOK;
    float v = pos[n * D + d];
    if (n == 0) h[idx] = cls[d] + v;
    else        h[idx] = h[idx] + v;
}

__global__ __launch_bounds__(256) void wcat_kernel(const float* __restrict__ w, float* __restrict__ Wm) {
    int idx = blockIdx.x * 256 + threadIdx.x;
    const int total = NH * D * HD;
    if (idx >= total) return;
    int k = idx & 63;
    int d = (idx >> 6) % D;
    int hh = idx / (D * HD);
    Wm[d * D + hh * HD + k] = w[idx];
}

__global__ __launch_bounds__(256) void transpose_kernel(const float* __restrict__ src, float* __restrict__ dst,
                                                        int R, int C, long sStride, long dStride) {
    __shared__ float tile[32][33];
    const float* s = src + (long)blockIdx.z * sStride;
    float* d = dst + (long)blockIdx.z * dStride;
    int c0 = blockIdx.x * 32, r0 = blockIdx.y * 32;
    int tx = threadIdx.x % 32, ty = threadIdx.x / 32;
    for (int i = ty; i < 32; i += 8) {
        int r = r0 + i, c = c0 + tx;
        tile[i][tx] = (r < R && c < C) ? s[(long)r * C + c] : 0.f;
    }
    __syncthreads();
    for (int i = ty; i < 32; i += 8) {
        int c = c0 + i, r = r0 + tx;
        if (c < C && r < R) d[(long)c * R + r] = tile[tx][i];
    }
}

// ln: f32 out + OPTIONAL fp16 out
__global__ __launch_bounds__(256) void ln_kernel(const float* __restrict__ X, float* __restrict__ Y,
                                                 u16* __restrict__ Yh16,
                                                 const float* __restrict__ gamma, const float* __restrict__ beta,
                                                 int compact) {
    int r = blockIdx.x;
    long xrow = compact ? ((long)(r / NPATCH) * NTOK + 1 + (r % NPATCH)) : (long)r;
    const float* x = X + xrow * D;
    float* y = Y + (long)r * D;
    int t = threadIdx.x;
    float v[3];
    float s = 0.f, ss = 0.f;
#pragma unroll
    for (int i = 0; i < 3; i++) {
        v[i] = x[t + 256 * i];
        s += v[i];
        ss += v[i] * v[i];
    }
    __shared__ float red[8];
    for (int off = 32; off; off >>= 1) {
        s += __shfl_down(s, off, 64);
        ss += __shfl_down(ss, off, 64);
    }
    int wid = t >> 6, lane = t & 63;
    if (lane == 0) { red[wid] = s; red[4 + wid] = ss; }
    __syncthreads();
    s = red[0] + red[1] + red[2] + red[3];
    ss = red[4] + red[5] + red[6] + red[7];
    float mu = s * (1.f / 768.f);
    float var = ss * (1.f / 768.f) - mu * mu;
    float inv = rsqrtf(var + 1e-5f);
#pragma unroll
    for (int i = 0; i < 3; i++) {
        int c = t + 256 * i;
        float yv = gamma[c] * (v[i] - mu) * inv + beta[c];
        y[c] = yv;
        if (Yh16) Yh16[(long)r * D + c] = f2h(yv);
    }
}

// ---------------- parallel f32 attention softmax (R8-verbatim) ----------------
__global__ __launch_bounds__(256) void attn_p_kernel(const float* __restrict__ Q, const float* __restrict__ K,
                                                     float* __restrict__ Pt, float* __restrict__ Pn) {
    __shared__ float Ks[NTOK][68];
    int bh = blockIdx.x, mt = blockIdx.y;
    int b = bh / NH, h = bh % NH;
    int t = threadIdx.x;
    const float* Kb = K + (long)b * NTOK * D + h * HD;
    for (int i = t; i < NTOK * 16; i += 256) {
        int n = i >> 4, k4 = (i & 15) << 2;
        float4 v = *(const float4*)(Kb + (long)n * D + k4);
        Ks[n][k4] = v.x; Ks[n][k4 + 1] = v.y; Ks[n][k4 + 2] = v.z; Ks[n][k4 + 3] = v.w;
    }
    __syncthreads();
    int ql = t >> 4, l16 = t & 15;
    int m = mt * 16 + ql;
    int mr = m < NTOK ? m : NTOK - 1;
    const float* Qrow = Q + (long)(b * NTOK + mr) * D + h * HD;
    float q[64];
#pragma unroll
    for (int k = 0; k < 64; k += 4) {
        float4 v = *(const float4*)(Qrow + k);
        q[k] = v.x; q[k + 1] = v.y; q[k + 2] = v.z; q[k + 3] = v.w;
    }
    float s[13];
    float mx = -1e30f;
#pragma unroll
    for (int i = 0; i < 13; i++) {
        int n = i * 16 + l16;
        const float* kr = Ks[n < NTOK ? n : 0];
        float a0 = 0.f, a1 = 0.f, a2 = 0.f, a3 = 0.f;
#pragma unroll
        for (int k = 0; k < 64; k += 4) {
            a0 += kr[k] * q[k];
            a1 += kr[k + 1] * q[k + 1];
            a2 += kr[k + 2] * q[k + 2];
            a3 += kr[k + 3] * q[k + 3];
        }
        float sv = ((a0 + a1) + (a2 + a3)) * BETA_F;
        s[i] = (n < NTOK) ? sv : -1e30f;
        mx = fmaxf(mx, s[i]);
    }
    mx = fmaxf(mx, __shfl_xor(mx, 1, 64));
    mx = fmaxf(mx, __shfl_xor(mx, 2, 64));
    mx = fmaxf(mx, __shfl_xor(mx, 4, 64));
    mx = fmaxf(mx, __shfl_xor(mx, 8, 64));
    float ssum = 0.f;
#pragma unroll
    for (int i = 0; i < 13; i++) {
        float e = (s[i] > -1e29f) ? __expf(s[i] - mx) : 0.f;
        s[i] = e;
        ssum += e;
    }
    ssum += __shfl_xor(ssum, 1, 64);
    ssum += __shfl_xor(ssum, 2, 64);
    ssum += __shfl_xor(ssum, 4, 64);
    ssum += __shfl_xor(ssum, 8, 64);
    float inv = 1.f / ssum;
    if (m < NTOK) {
        float* PtB = Pt + (long)bh * PBH;
        float* PnB = Pn + (long)bh * PBH;
#pragma unroll
        for (int i = 0; i < 13; i++) {
            int n = i * 16 + l16;
            if (n < NTOK) {
                float p = s[i] * inv;
                PtB[(long)m * PLD + n] = p;
                PnB[(long)n * PLD + m] = p;
            }
        }
    }
}

__global__ __launch_bounds__(256) void gemm_f32(
    const float* __restrict__ A, const float* __restrict__ B, float* __restrict__ C,
    const float* __restrict__ bias,
    int M, int N, int K, int lda, int ldb, int ldc,
    int zdiv, long sA1, long sA2, long sB1, long sB2, long sC1, long sC2,
    int flags) {
    int z = blockIdx.z;
    int z1 = z / zdiv, z2 = z - z1 * zdiv;
    A += (long)z1 * sA1 + (long)z2 * sA2;
    B += (long)z1 * sB1 + (long)z2 * sB2;
    C += (long)z1 * sC1 + (long)z2 * sC2;

    __shared__ float As[16][68];
    __shared__ float Bs[16][68];

    int t = threadIdx.x;
    int tx = t & 15, ty = t >> 4;
    int row0 = blockIdx.y * 64, col0 = blockIdx.x * 64;

    float acc[4][4] = {};

    for (int kt = 0; kt < K; kt += 16) {
        {
            int r = t >> 2;
            int c4 = (t & 3) << 2;
            int gr = row0 + r;
            int gk = kt + c4;
            float4 v = make_float4(0.f, 0.f, 0.f, 0.f);
            if (gr < M) {
                if (gk + 3 < K) {
                    v = *(const float4*)(A + (long)gr * lda + gk);
                } else {
                    float x0 = (gk < K) ? A[(long)gr * lda + gk] : 0.f;
                    float x1 = (gk + 1 < K) ? A[(long)gr * lda + gk + 1] : 0.f;
                    float x2 = (gk + 2 < K) ? A[(long)gr * lda + gk + 2] : 0.f;
                    float x3 = (gk + 3 < K) ? A[(long)gr * lda + gk + 3] : 0.f;
                    v = make_float4(x0, x1, x2, x3);
                }
            }
            As[c4 + 0][r] = v.x; As[c4 + 1][r] = v.y; As[c4 + 2][r] = v.z; As[c4 + 3][r] = v.w;
        }
        {
            int r = t >> 4;
            int c4 = (t & 15) << 2;
            int gk = kt + r;
            int gc = col0 + c4;
            float4 v = make_float4(0.f, 0.f, 0.f, 0.f);
            if (gk < K && gc + 3 < N) {
                v = *(const float4*)(B + (long)gk * ldb + gc);
            }
            Bs[r][c4 + 0] = v.x; Bs[r][c4 + 1] = v.y; Bs[r][c4 + 2] = v.z; Bs[r][c4 + 3] = v.w;
        }
        __syncthreads();
#pragma unroll
        for (int kk = 0; kk < 16; kk++) {
            float av[4], bv[4];
#pragma unroll
            for (int i = 0; i < 4; i++) av[i] = As[kk][ty * 4 + i];
#pragma unroll
            for (int j = 0; j < 4; j++) bv[j] = Bs[kk][tx * 4 + j];
#pragma unroll
            for (int i = 0; i < 4; i++)
#pragma unroll
                for (int j = 0; j < 4; j++) acc[i][j] += av[i] * bv[j];
        }
        __syncthreads();
    }
#pragma unroll
    for (int i = 0; i < 4; i++) {
        int gr = row0 + ty * 4 + i;
        if (gr >= M) continue;
#pragma unroll
        for (int j = 0; j < 4; j++) {
            int gc = col0 + tx * 4 + j;
            if (gc >= N) continue;
            float v = acc[i][j];
            if (bias) v += bias[gc];
            if (flags & 2) v = fmaxf(v, 0.f);
            long idx = (long)gr * ldc + gc;
            if (flags & 1) C[idx] += v;
            else C[idx] = v;
        }
    }
}

// fp16 preps (exonerated patterns, fp16 cast)
__global__ __launch_bounds__(256) void prep_transpose_h(const float* __restrict__ src,
                                                        u16* __restrict__ dst, int R, int C) {
    int idx = blockIdx.x * 256 + threadIdx.x;
    if (idx >= R * C) return;
    int r = idx % R, c = idx / R;
    dst[idx] = f2h(src[(long)r * C + c]);
}
__global__ __launch_bounds__(256) void prep_convert_h(const float* __restrict__ src,
                                                      u16* __restrict__ dst, int n) {
    int idx = blockIdx.x * 256 + threadIdx.x;
    if (idx >= n) return;
    dst[idx] = f2h(src[idx]);
}

extern "C" void kernel_launch(void* const* d_in, const int* in_sizes, int n_in,
                              void* d_out, int out_size, void* d_ws, size_t ws_size,
                              hipStream_t stream) {
    const float* x        = (const float*)d_in[0];
    const float* patch_w  = (const float*)d_in[1];
    const float* patch_b  = (const float*)d_in[2];
    const float* cls_tok  = (const float*)d_in[3];
    const float* pos_emb  = (const float*)d_in[4];
    const float* ln_gamma = (const float*)d_in[5];
    const float* ln_beta  = (const float*)d_in[6];
    const float* wq       = (const float*)d_in[7];
    const float* wk       = (const float*)d_in[8];
    const float* xi       = (const float*)d_in[9];
    const float* out_gamma= (const float*)d_in[10];
    const float* out_beta = (const float*)d_in[11];
    const float* out_w    = (const float*)d_in[12];
    const float* out_b    = (const float*)d_in[13];
    float* out = (float*)d_out;

    float* ws = (float*)d_ws;
    const long SZ = (long)NB * NTOK * D;       // 2,420,736
    const long AR = (long)AROWS * D;           // 2,457,600
    float* h    = ws;
    float* g    = ws + SZ;
    float* Qb   = ws + 2 * SZ;
    float* Kb   = ws + 3 * SZ;                 // Qb,Kb adjacent: z-stride SZ
    float* G1   = ws + 4 * SZ;
    float* G2   = ws + 5 * SZ;
    float* WmQ  = ws + 6 * SZ;
    float* WmK  = WmQ + DD;
    float* WmQT = WmK + DD;
    float* WmKT = WmQT + DD;
    // fp16 buffers (u16 storage)
    u16* gh16    = (u16*)(WmKT + DD);
    u16* WmQTh16 = gh16 + AR;                  // WmQT|WmKT adjacent for z-batch
    u16* WmKTh16 = WmQTh16 + DD;
    u16* WmQh16  = WmKTh16 + DD;
    u16* WmKh16  = WmQh16 + DD;
    u16* xiTh16  = WmKh16 + DD;
    u16* xibh16  = xiTh16 + DH;
    u16* G1h16   = xibh16 + DH;
    u16* G2h16   = G1h16 + AR;
    // shared region: {Pt,Pn} | HH16 | tok
    float* R1 = (float*)(G2h16 + AR);
    float* Pt = R1;
    float* Pn = R1 + (long)NB * NH * PBH;
    u16* HH16 = (u16*)R1;
    float* tok = R1;

    auto gemm = [&](const float* A, const float* B, float* C, const float* bias,
                    int M, int N, int K, int lda, int ldb, int ldc,
                    int gz, int zdiv, long sA1, long sA2, long sB1, long sB2,
                    long sC1, long sC2, int flags) {
        dim3 grid((N + 63) / 64, (M + 63) / 64, gz);
        gemm_f32<<<grid, 256, 0, stream>>>(A, B, C, bias, M, N, K, lda, ldb, ldc,
                                           zdiv, sA1, sA2, sB1, sB2, sC1, sC2, flags);
    };

    // ---- setup ----
    patchify_kernel<<<(NB * NPATCH * D + 255) / 256, 256, 0, stream>>>(x, tok);
    wcat_kernel<<<(NH * D * HD + 255) / 256, 256, 0, stream>>>(wq, WmQ);
    wcat_kernel<<<(NH * D * HD + 255) / 256, 256, 0, stream>>>(wk, WmK);
    transpose_kernel<<<dim3(24, 24, 1), 256, 0, stream>>>(WmQ, WmQT, 768, 768, 0, 0);
    transpose_kernel<<<dim3(24, 24, 1), 256, 0, stream>>>(WmK, WmKT, 768, 768, 0, 0);
    prep_convert_h<<<(DD + 255) / 256, 256, 0, stream>>>(WmQT, WmQTh16, DD);
    prep_convert_h<<<(DD + 255) / 256, 256, 0, stream>>>(WmKT, WmKTh16, DD);
    prep_convert_h<<<(DD + 255) / 256, 256, 0, stream>>>(WmQ, WmQh16, DD);
    prep_convert_h<<<(DD + 255) / 256, 256, 0, stream>>>(WmK, WmKh16, DD);
    prep_transpose_h<<<(DH + 255) / 256, 256, 0, stream>>>(xi, xiTh16, D, HOP);
    prep_convert_h<<<(DH + 255) / 256, 256, 0, stream>>>(xi, xibh16, DH);
    // patch embed: f32 R0 path (h0 seed stays f32 — sensitivity firewall)
    gemm(tok, patch_w, h + D, patch_b, NPATCH, D, D, D, D, D,
         NB, 1, (long)NPATCH * D, 0, 0, 0, (long)NTOK * D, 0, 0);
    cls_pos_kernel<<<(NB * NTOK * D + 255) / 256, 256, 0, stream>>>(h, cls_tok, pos_emb);

    for (int step = 0; step < TSTEPS; step++) {
        ln_kernel<<<NB * NTOK, 256, 0, stream>>>(h, g, gh16, ln_gamma, ln_beta, 0);
        // Q|K projection in ONE z=2 launch (f32 out)
        gemm_h16<<<dim3(6, 25, 2), 256, 0, stream>>>(
            gh16, WmQTh16, Qb, nullptr,
            NROWS, D, D, D, D, D, 0, /*sAz*/0, /*sBz*/(long)DD, /*sCz*/SZ);
        attn_p_kernel<<<dim3(192, 13), 256, 0, stream>>>(Qb, Kb, Pt, Pn);
        gemm(Pt, Kb, G1, nullptr, NTOK, HD, NTOK, PLD, D, D,
             NB * NH, NH, (long)NH * PBH, PBH, (long)NTOK * D, HD, (long)NTOK * D, HD, 0);
        gemm(Pn, Qb, G2, nullptr, NTOK, HD, NTOK, PLD, D, D,
             NB * NH, NH, (long)NH * PBH, PBH, (long)NTOK * D, HD, (long)NTOK * D, HD, 0);
        prep_convert_h<<<((int)SZ + 255) / 256, 256, 0, stream>>>(G1, G1h16, (int)SZ);
        prep_convert_h<<<((int)SZ + 255) / 256, 256, 0, stream>>>(G2, G2h16, (int)SZ);
        // h += G1 @ WmQ^T ; h += G2 @ WmK^T  (sequential: same output buffer)
        gemm_h16<<<dim3(6, 25, 1), 256, 0, stream>>>(
            G1h16, WmQh16, h, nullptr, NROWS, D, D, D, D, D, FLAG_ACC, 0, 0, 0);
        gemm_h16<<<dim3(6, 25, 1), 256, 0, stream>>>(
            G2h16, WmKh16, h, nullptr, NROWS, D, D, D, D, D, FLAG_ACC, 0, 0, 0);
        // Hopfield: HH = relu(g @ xi) (fp16 out), h += HH @ xi^T
        gemm_h16<<<dim3(24, 25, 1), 256, 0, stream>>>(
            gh16, xiTh16, HH16, nullptr, NROWS, HOP, D, D, D, HOP, FLAG_H16 | FLAG_RELU, 0, 0, 0);
        gemm_h16<<<dim3(6, 25, 1), 256, 0, stream>>>(
            HH16, xibh16, h, nullptr, NROWS, D, HOP, HOP, HOP, D, FLAG_ACC, 0, 0, 0);
    }

    // ---- final LN (compact, f32) + output projection (f32) ----
    ln_kernel<<<NB * NPATCH, 256, 0, stream>>>(h, g, nullptr, out_gamma, out_beta, 1);
    gemm(g, out_w, out, out_b, NPROWS, D, D, D, D, D, 1, 1, 0, 0, 0, 0, 0, 0, 0);
}

// Round 11
// 1772.131 us; speedup vs baseline: 3.9928x; 1.4092x over previous
//
#include <hip/hip_runtime.h>

#define NB 16
#define NTOK 197
#define NPATCH 196
#define D 768
#define NH 12
#define HD 64
#define HOP 3072
#define TSTEPS 6
#define BETA_F 0.125f
#define PLD 208                 // P leading dim (f32)
#define PBH (NTOK * PLD)        // 40976
#define NROWS (NB * NTOK)       // 3152
#define NPROWS (NB * NPATCH)    // 3136
#define AROWS 3200              // padded rows for MFMA A-side staging
#define DD (768 * 768)
#define DH (768 * 3072)
#define SZL ((long)NROWS * D)   // 2,420,736

typedef unsigned short u16;
typedef __attribute__((ext_vector_type(8))) _Float16 f16x8;
typedef __attribute__((ext_vector_type(4))) float f32x4;

#define FLAG_ACC 1
#define FLAG_RELU 2
#define FLAG_H16 4

__device__ __forceinline__ u16 f2h(float f) {
    union { _Float16 h; u16 u; } cv;
    cv.h = (_Float16)f;
    return cv.u;
}

__device__ __forceinline__ void gld16(const void* g, void* l) {
    __builtin_amdgcn_global_load_lds((const __attribute__((address_space(1))) void*)g,
                                     (__attribute__((address_space(3))) void*)l, 16, 0, 0);
}

// ---------------- single-fp16 MFMA GEMM (R10-verbatim core) ----------------
__global__ __launch_bounds__(256) void gemm_h16(
    const u16* __restrict__ A, const u16* __restrict__ B,
    void* __restrict__ Cv, const float* __restrict__ bias,
    int M, int N, int K, int lda, int ldbt, int ldc, int flags,
    long sAz, long sBz, long sCz) {
    __shared__ __align__(16) u16 As[128 * 32];
    __shared__ __align__(16) u16 Bs[128 * 32];
    int zz = blockIdx.z;
    A += (long)zz * sAz;
    B += (long)zz * sBz;
    long czoff = (long)zz * sCz;
    int t = threadIdx.x;
    int w = t >> 6, lane = t & 63;
    int lr = lane & 15, lg = lane >> 4, ko = lg * 8;
    int wr = w >> 1, wc = w & 1;
    long row0 = (long)blockIdx.y * 128, col0 = (long)blockIdx.x * 128;

    f32x4 acc[4][4];
#pragma unroll
    for (int i = 0; i < 4; i++)
#pragma unroll
        for (int j = 0; j < 4; j++) acc[i][j] = (f32x4){0.f, 0.f, 0.f, 0.f};

    int c0 = w * 64 + lane;
    int r0s = c0 >> 2, k0s = (c0 & 3) << 3;
    int c1 = 256 + w * 64 + lane;
    int r1s = c1 >> 2, k1s = (c1 & 3) << 3;

    for (int kt = 0; kt < K; kt += 32) {
        const u16* AB = A + row0 * lda + kt;
        const u16* BB = B + col0 * ldbt + kt;
        gld16(AB + (long)r0s * lda + k0s, (char*)As + (w * 64) * 16);
        gld16(AB + (long)r1s * lda + k1s, (char*)As + (256 + w * 64) * 16);
        gld16(BB + (long)r0s * ldbt + k0s, (char*)Bs + (w * 64) * 16);
        gld16(BB + (long)r1s * ldbt + k1s, (char*)Bs + (256 + w * 64) * 16);
        __syncthreads();
        f16x8 af[4], bf[4];
#pragma unroll
        for (int mi = 0; mi < 4; mi++) af[mi] = *(const f16x8*)&As[(wr * 64 + mi * 16 + lr) * 32 + ko];
#pragma unroll
        for (int ni = 0; ni < 4; ni++) bf[ni] = *(const f16x8*)&Bs[(wc * 64 + ni * 16 + lr) * 32 + ko];
#pragma unroll
        for (int mi = 0; mi < 4; mi++)
#pragma unroll
            for (int ni = 0; ni < 4; ni++)
                acc[mi][ni] = __builtin_amdgcn_mfma_f32_16x16x32_f16(af[mi], bf[ni], acc[mi][ni], 0, 0, 0);
        __syncthreads();
    }

    long mbase = row0 + wr * 64;
    long nbase = col0 + wc * 64;
#pragma unroll
    for (int mi = 0; mi < 4; mi++) {
#pragma unroll
        for (int r = 0; r < 4; r++) {
            long grow = mbase + mi * 16 + lg * 4 + r;
            if (grow >= M) continue;
#pragma unroll
            for (int ni = 0; ni < 4; ni++) {
                long gcol = nbase + ni * 16 + lr;
                float v = acc[mi][ni][r];
                if (bias) v += bias[gcol];
                if (flags & FLAG_RELU) v = fmaxf(v, 0.f);
                long idx = czoff + grow * ldc + gcol;
                if (flags & FLAG_ACC) ((float*)Cv)[idx] += v;
                else if (flags & FLAG_H16) ((u16*)Cv)[idx] = f2h(v);
                else ((float*)Cv)[idx] = v;
            }
        }
    }
}

// ---------------- fused accumulate GEMM: 6 split-K partials (z-scheduled) ----------------
// z=0: G1 @ WmQ^T (K=768); z=1: G2 @ WmK^T (K=768); z in [2,6): HH @ xib^T K-chunk 768.
// Each z writes partial[z][NROWS*D] (f32). Deterministic reduce afterwards.
__global__ __launch_bounds__(256) void gemm_h16_fused(
    const u16* __restrict__ G1, const u16* __restrict__ G2, const u16* __restrict__ HH,
    const u16* __restrict__ WQ, const u16* __restrict__ WK, const u16* __restrict__ XB,
    float* __restrict__ part) {
    __shared__ __align__(16) u16 As[128 * 32];
    __shared__ __align__(16) u16 Bs[128 * 32];
    int zz = blockIdx.z;
    const u16* A; const u16* B; int lda; int K0;
    if (zz == 0)      { A = G1; B = WQ; lda = 768;  K0 = 0; }
    else if (zz == 1) { A = G2; B = WK; lda = 768;  K0 = 0; }
    else              { A = HH; B = XB; lda = 3072; K0 = (zz - 2) * 768; }
    float* C = part + (long)zz * SZL;

    int t = threadIdx.x;
    int w = t >> 6, lane = t & 63;
    int lr = lane & 15, lg = lane >> 4, ko = lg * 8;
    int wr = w >> 1, wc = w & 1;
    long row0 = (long)blockIdx.y * 128, col0 = (long)blockIdx.x * 128;

    f32x4 acc[4][4];
#pragma unroll
    for (int i = 0; i < 4; i++)
#pragma unroll
        for (int j = 0; j < 4; j++) acc[i][j] = (f32x4){0.f, 0.f, 0.f, 0.f};

    int c0 = w * 64 + lane;
    int r0s = c0 >> 2, k0s = (c0 & 3) << 3;
    int c1 = 256 + w * 64 + lane;
    int r1s = c1 >> 2, k1s = (c1 & 3) << 3;

    for (int kt = K0; kt < K0 + 768; kt += 32) {
        const u16* AB = A + row0 * lda + kt;
        const u16* BB = B + col0 * (long)lda + kt;   // ldbt == lda for all three cases
        gld16(AB + (long)r0s * lda + k0s, (char*)As + (w * 64) * 16);
        gld16(AB + (long)r1s * lda + k1s, (char*)As + (256 + w * 64) * 16);
        gld16(BB + (long)r0s * lda + k0s, (char*)Bs + (w * 64) * 16);
        gld16(BB + (long)r1s * lda + k1s, (char*)Bs + (256 + w * 64) * 16);
        __syncthreads();
        f16x8 af[4], bf[4];
#pragma unroll
        for (int mi = 0; mi < 4; mi++) af[mi] = *(const f16x8*)&As[(wr * 64 + mi * 16 + lr) * 32 + ko];
#pragma unroll
        for (int ni = 0; ni < 4; ni++) bf[ni] = *(const f16x8*)&Bs[(wc * 64 + ni * 16 + lr) * 32 + ko];
#pragma unroll
        for (int mi = 0; mi < 4; mi++)
#pragma unroll
            for (int ni = 0; ni < 4; ni++)
                acc[mi][ni] = __builtin_amdgcn_mfma_f32_16x16x32_f16(af[mi], bf[ni], acc[mi][ni], 0, 0, 0);
        __syncthreads();
    }

    long mbase = row0 + wr * 64;
    long nbase = col0 + wc * 64;
#pragma unroll
    for (int mi = 0; mi < 4; mi++) {
#pragma unroll
        for (int r = 0; r < 4; r++) {
            long grow = mbase + mi * 16 + lg * 4 + r;
            if (grow >= NROWS) continue;
#pragma unroll
            for (int ni = 0; ni < 4; ni++) {
                long gcol = nbase + ni * 16 + lr;
                C[grow * D + gcol] = acc[mi][ni][r];
            }
        }
    }
}

// ---------------- deterministic reduce: h += sum of 6 partial slabs ----------------
__global__ __launch_bounds__(256) void reduce6_kernel(float* __restrict__ h, const float* __restrict__ part) {
    long idx = (long)blockIdx.x * 256 + threadIdx.x;
    const long n4 = SZL / 4;
    if (idx >= n4) return;
    float4 a = ((const float4*)h)[idx];
    float4 p0 = ((const float4*)(part + 0 * SZL))[idx];
    float4 p1 = ((const float4*)(part + 1 * SZL))[idx];
    float4 p2 = ((const float4*)(part + 2 * SZL))[idx];
    float4 p3 = ((const float4*)(part + 3 * SZL))[idx];
    float4 p4 = ((const float4*)(part + 4 * SZL))[idx];
    float4 p5 = ((const float4*)(part + 5 * SZL))[idx];
    a.x += ((((p0.x + p1.x) + (p2.x + p3.x)) + (p4.x + p5.x)));
    a.y += ((((p0.y + p1.y) + (p2.y + p3.y)) + (p4.y + p5.y)));
    a.z += ((((p0.z + p1.z) + (p2.z + p3.z)) + (p4.z + p5.z)));
    a.w += ((((p0.w + p1.w) + (p2.w + p3.w)) + (p4.w + p5.w)));
    ((float4*)h)[idx] = a;
}

// ================= f32 PIPELINE PIECES (R10-verbatim) =================

__global__ __launch_bounds__(256) void patchify_kernel(const float* __restrict__ x, float* __restrict__ tok) {
    int idx = blockIdx.x * 256 + threadIdx.x;
    const int total = NB * NPATCH * D;
    if (idx >= total) return;
    int d = idx % D;
    int p = (idx / D) % NPATCH;
    int b = idx / (D * NPATCH);
    int c = d >> 8;
    int pi = (d >> 4) & 15;
    int pj = d & 15;
    int hp = p / 14, wp = p % 14;
    int row = hp * 16 + pi, col = wp * 16 + pj;
    tok[idx] = x[(((long)b * 3 + c) * 224 + row) * 224 + col];
}

__global__ __launch_bounds__(256) void cls_pos_kernel(float* __restrict__ h, const float* __restrict__ cls,
                                                      const float* __restrict__ pos) {
    int idx = blockIdx.x * 256 + threadIdx.x;
    const int total = NB * NTOK * D;
    if (idx >= total) return;
    int d = idx % D;
    int n = (idx / D) % NTOK;
    float v = pos[n * D + d];
    if (n == 0) h[idx] = cls[d] + v;
    else        h[idx] = h[idx] + v;
}

__global__ __launch_bounds__(256) void wcat_kernel(const float* __restrict__ w, float* __restrict__ Wm) {
    int idx = blockIdx.x * 256 + threadIdx.x;
    const int total = NH * D * HD;
    if (idx >= total) return;
    int k = idx & 63;
    int d = (idx >> 6) % D;
    int hh = idx / (D * HD);
    Wm[d * D + hh * HD + k] = w[idx];
}

// ln: f32 out + OPTIONAL fp16 out
__global__ __launch_bounds__(256) void ln_kernel(const float* __restrict__ X, float* __restrict__ Y,
                                                 u16* __restrict__ Yh16,
                                                 const float* __restrict__ gamma, const float* __restrict__ beta,
                                                 int compact) {
    int r = blockIdx.x;
    long xrow = compact ? ((long)(r / NPATCH) * NTOK + 1 + (r % NPATCH)) : (long)r;
    const float* x = X + xrow * D;
    float* y = Y + (long)r * D;
    int t = threadIdx.x;
    float v[3];
    float s = 0.f, ss = 0.f;
#pragma unroll
    for (int i = 0; i < 3; i++) {
        v[i] = x[t + 256 * i];
        s += v[i];
        ss += v[i] * v[i];
    }
    __shared__ float red[8];
    for (int off = 32; off; off >>= 1) {
        s += __shfl_down(s, off, 64);
        ss += __shfl_down(ss, off, 64);
    }
    int wid = t >> 6, lane = t & 63;
    if (lane == 0) { red[wid] = s; red[4 + wid] = ss; }
    __syncthreads();
    s = red[0] + red[1] + red[2] + red[3];
    ss = red[4] + red[5] + red[6] + red[7];
    float mu = s * (1.f / 768.f);
    float var = ss * (1.f / 768.f) - mu * mu;
    float inv = rsqrtf(var + 1e-5f);
#pragma unroll
    for (int i = 0; i < 3; i++) {
        int c = t + 256 * i;
        float yv = gamma[c] * (v[i] - mu) * inv + beta[c];
        y[c] = yv;
        if (Yh16) Yh16[(long)r * D + c] = f2h(yv);
    }
}

// ---------------- parallel f32 attention softmax (R8-verbatim) ----------------
__global__ __launch_bounds__(256) void attn_p_kernel(const float* __restrict__ Q, const float* __restrict__ K,
                                                     float* __restrict__ Pt, float* __restrict__ Pn) {
    __shared__ float Ks[NTOK][68];
    int bh = blockIdx.x, mt = blockIdx.y;
    int b = bh / NH, h = bh % NH;
    int t = threadIdx.x;
    const float* Kb = K + (long)b * NTOK * D + h * HD;
    for (int i = t; i < NTOK * 16; i += 256) {
        int n = i >> 4, k4 = (i & 15) << 2;
        float4 v = *(const float4*)(Kb + (long)n * D + k4);
        Ks[n][k4] = v.x; Ks[n][k4 + 1] = v.y; Ks[n][k4 + 2] = v.z; Ks[n][k4 + 3] = v.w;
    }
    __syncthreads();
    int ql = t >> 4, l16 = t & 15;
    int m = mt * 16 + ql;
    int mr = m < NTOK ? m : NTOK - 1;
    const float* Qrow = Q + (long)(b * NTOK + mr) * D + h * HD;
    float q[64];
#pragma unroll
    for (int k = 0; k < 64; k += 4) {
        float4 v = *(const float4*)(Qrow + k);
        q[k] = v.x; q[k + 1] = v.y; q[k + 2] = v.z; q[k + 3] = v.w;
    }
    float s[13];
    float mx = -1e30f;
#pragma unroll
    for (int i = 0; i < 13; i++) {
        int n = i * 16 + l16;
        const float* kr = Ks[n < NTOK ? n : 0];
        float a0 = 0.f, a1 = 0.f, a2 = 0.f, a3 = 0.f;
#pragma unroll
        for (int k = 0; k < 64; k += 4) {
            a0 += kr[k] * q[k];
            a1 += kr[k + 1] * q[k + 1];
            a2 += kr[k + 2] * q[k + 2];
            a3 += kr[k + 3] * q[k + 3];
        }
        float sv = ((a0 + a1) + (a2 + a3)) * BETA_F;
        s[i] = (n < NTOK) ? sv : -1e30f;
        mx = fmaxf(mx, s[i]);
    }
    mx = fmaxf(mx, __shfl_xor(mx, 1, 64));
    mx = fmaxf(mx, __shfl_xor(mx, 2, 64));
    mx = fmaxf(mx, __shfl_xor(mx, 4, 64));
    mx = fmaxf(mx, __shfl_xor(mx, 8, 64));
    float ssum = 0.f;
#pragma unroll
    for (int i = 0; i < 13; i++) {
        float e = (s[i] > -1e29f) ? __expf(s[i] - mx) : 0.f;
        s[i] = e;
        ssum += e;
    }
    ssum += __shfl_xor(ssum, 1, 64);
    ssum += __shfl_xor(ssum, 2, 64);
    ssum += __shfl_xor(ssum, 4, 64);
    ssum += __shfl_xor(ssum, 8, 64);
    float inv = 1.f / ssum;
    if (m < NTOK) {
        float* PtB = Pt + (long)bh * PBH;
        float* PnB = Pn + (long)bh * PBH;
#pragma unroll
        for (int i = 0; i < 13; i++) {
            int n = i * 16 + l16;
            if (n < NTOK) {
                float p = s[i] * inv;
                PtB[(long)m * PLD + n] = p;
                PnB[(long)n * PLD + m] = p;
            }
        }
    }
}

// ---------------- f32 GEMM (R10 body + optional fp16-out epilogue) ----------------
__global__ __launch_bounds__(256) void gemm_f32(
    const float* __restrict__ A, const float* __restrict__ B, float* __restrict__ C,
    u16* __restrict__ Ch, const float* __restrict__ bias,
    int M, int N, int K, int lda, int ldb, int ldc,
    int zdiv, long sA1, long sA2, long sB1, long sB2, long sC1, long sC2,
    int flags) {
    int z = blockIdx.z;
    int z1 = z / zdiv, z2 = z - z1 * zdiv;
    A += (long)z1 * sA1 + (long)z2 * sA2;
    B += (long)z1 * sB1 + (long)z2 * sB2;
    long coff = (long)z1 * sC1 + (long)z2 * sC2;

    __shared__ float As[16][68];
    __shared__ float Bs[16][68];

    int t = threadIdx.x;
    int tx = t & 15, ty = t >> 4;
    int row0 = blockIdx.y * 64, col0 = blockIdx.x * 64;

    float acc[4][4] = {};

    for (int kt = 0; kt < K; kt += 16) {
        {
            int r = t >> 2;
            int c4 = (t & 3) << 2;
            int gr = row0 + r;
            int gk = kt + c4;
            float4 v = make_float4(0.f, 0.f, 0.f, 0.f);
            if (gr < M) {
                if (gk + 3 < K) {
                    v = *(const float4*)(A + (long)gr * lda + gk);
                } else {
                    float x0 = (gk < K) ? A[(long)gr * lda + gk] : 0.f;
                    float x1 = (gk + 1 < K) ? A[(long)gr * lda + gk + 1] : 0.f;
                    float x2 = (gk + 2 < K) ? A[(long)gr * lda + gk + 2] : 0.f;
                    float x3 = (gk + 3 < K) ? A[(long)gr * lda + gk + 3] : 0.f;
                    v = make_float4(x0, x1, x2, x3);
                }
            }
            As[c4 + 0][r] = v.x; As[c4 + 1][r] = v.y; As[c4 + 2][r] = v.z; As[c4 + 3][r] = v.w;
        }
        {
            int r = t >> 4;
            int c4 = (t & 15) << 2;
            int gk = kt + r;
            int gc = col0 + c4;
            float4 v = make_float4(0.f, 0.f, 0.f, 0.f);
            if (gk < K && gc + 3 < N) {
                v = *(const float4*)(B + (long)gk * ldb + gc);
            }
            Bs[r][c4 + 0] = v.x; Bs[r][c4 + 1] = v.y; Bs[r][c4 + 2] = v.z; Bs[r][c4 + 3] = v.w;
        }
        __syncthreads();
#pragma unroll
        for (int kk = 0; kk < 16; kk++) {
            float av[4], bv[4];
#pragma unroll
            for (int i = 0; i < 4; i++) av[i] = As[kk][ty * 4 + i];
#pragma unroll
            for (int j = 0; j < 4; j++) bv[j] = Bs[kk][tx * 4 + j];
#pragma unroll
            for (int i = 0; i < 4; i++)
#pragma unroll
                for (int j = 0; j < 4; j++) acc[i][j] += av[i] * bv[j];
        }
        __syncthreads();
    }
#pragma unroll
    for (int i = 0; i < 4; i++) {
        int gr = row0 + ty * 4 + i;
        if (gr >= M) continue;
#pragma unroll
        for (int j = 0; j < 4; j++) {
            int gc = col0 + tx * 4 + j;
            if (gc >= N) continue;
            float v = acc[i][j];
            if (bias) v += bias[gc];
            if (flags & FLAG_RELU) v = fmaxf(v, 0.f);
            long idx = coff + (long)gr * ldc + gc;
            if (flags & FLAG_ACC) C[idx] += v;
            else if (flags & FLAG_H16) Ch[idx] = f2h(v);
            else C[idx] = v;
        }
    }
}

// fp16 preps (exonerated patterns)
__global__ __launch_bounds__(256) void prep_transpose_h(const float* __restrict__ src,
                                                        u16* __restrict__ dst, int R, int C) {
    int idx = blockIdx.x * 256 + threadIdx.x;
    if (idx >= R * C) return;
    int r = idx % R, c = idx / R;
    dst[idx] = f2h(src[(long)r * C + c]);
}
__global__ __launch_bounds__(256) void prep_convert_h(const float* __restrict__ src,
                                                      u16* __restrict__ dst, int n) {
    int idx = blockIdx.x * 256 + threadIdx.x;
    if (idx >= n) return;
    dst[idx] = f2h(src[idx]);
}

extern "C" void kernel_launch(void* const* d_in, const int* in_sizes, int n_in,
                              void* d_out, int out_size, void* d_ws, size_t ws_size,
                              hipStream_t stream) {
    const float* x        = (const float*)d_in[0];
    const float* patch_w  = (const float*)d_in[1];
    const float* patch_b  = (const float*)d_in[2];
    const float* cls_tok  = (const float*)d_in[3];
    const float* pos_emb  = (const float*)d_in[4];
    const float* ln_gamma = (const float*)d_in[5];
    const float* ln_beta  = (const float*)d_in[6];
    const float* wq       = (const float*)d_in[7];
    const float* wk       = (const float*)d_in[8];
    const float* xi       = (const float*)d_in[9];
    const float* out_gamma= (const float*)d_in[10];
    const float* out_beta = (const float*)d_in[11];
    const float* out_w    = (const float*)d_in[12];
    const float* out_b    = (const float*)d_in[13];
    float* out = (float*)d_out;

    float* ws = (float*)d_ws;
    const long SZ = SZL;                       // 2,420,736
    const long AR = (long)AROWS * D;           // 2,457,600
    float* h    = ws;
    float* g    = ws + SZ;
    float* Qb   = ws + 2 * SZ;
    float* Kb   = ws + 3 * SZ;                 // adjacent: z-stride SZ
    float* WmQ  = ws + 4 * SZ;
    float* WmK  = WmQ + DD;
    float* part = WmK + DD;                    // 6 × SZ f32 partial slabs
    // fp16 buffers (u16 storage)
    u16* gh16    = (u16*)(part + 6 * SZ);
    u16* WmQTh16 = gh16 + AR;                  // adjacent WmKTh16 for z-batch
    u16* WmKTh16 = WmQTh16 + DD;
    u16* WmQh16  = WmKTh16 + DD;
    u16* WmKh16  = WmQh16 + DD;
    u16* xiTh16  = WmKh16 + DD;
    u16* xibh16  = xiTh16 + DH;
    u16* G1h16   = xibh16 + DH;
    u16* G2h16   = G1h16 + AR;
    // shared region: {Pt,Pn} | HH16 | tok
    float* R1 = (float*)(G2h16 + AR);
    float* Pt = R1;
    float* Pn = R1 + (long)NB * NH * PBH;
    u16* HH16 = (u16*)R1;
    float* tok = R1;

    auto gemm = [&](const float* A, const float* B, float* C, u16* Ch, const float* bias,
                    int M, int N, int K, int lda, int ldb, int ldc,
                    int gz, int zdiv, long sA1, long sA2, long sB1, long sB2,
                    long sC1, long sC2, int flags) {
        dim3 grid((N + 63) / 64, (M + 63) / 64, gz);
        gemm_f32<<<grid, 256, 0, stream>>>(A, B, C, Ch, bias, M, N, K, lda, ldb, ldc,
                                           zdiv, sA1, sA2, sB1, sB2, sC1, sC2, flags);
    };

    // ---- setup ----
    patchify_kernel<<<(NB * NPATCH * D + 255) / 256, 256, 0, stream>>>(x, tok);
    wcat_kernel<<<(NH * D * HD + 255) / 256, 256, 0, stream>>>(wq, WmQ);
    wcat_kernel<<<(NH * D * HD + 255) / 256, 256, 0, stream>>>(wk, WmK);
    prep_transpose_h<<<(DD + 255) / 256, 256, 0, stream>>>(WmQ, WmQTh16, 768, 768);
    prep_transpose_h<<<(DD + 255) / 256, 256, 0, stream>>>(WmK, WmKTh16, 768, 768);
    prep_convert_h<<<(DD + 255) / 256, 256, 0, stream>>>(WmQ, WmQh16, DD);
    prep_convert_h<<<(DD + 255) / 256, 256, 0, stream>>>(WmK, WmKh16, DD);
    prep_transpose_h<<<(DH + 255) / 256, 256, 0, stream>>>(xi, xiTh16, 768, HOP);
    prep_convert_h<<<(DH + 255) / 256, 256, 0, stream>>>(xi, xibh16, DH);
    // patch embed: f32 (h0 seed stays f32 — sensitivity firewall)
    gemm(tok, patch_w, h + D, nullptr, patch_b, NPATCH, D, D, D, D, D,
         NB, 1, (long)NPATCH * D, 0, 0, 0, (long)NTOK * D, 0, 0);
    cls_pos_kernel<<<(NB * NTOK * D + 255) / 256, 256, 0, stream>>>(h, cls_tok, pos_emb);

    const int RED_BLOCKS = (int)((SZ / 4 + 255) / 256);

    for (int step = 0; step < TSTEPS; step++) {
        ln_kernel<<<NB * NTOK, 256, 0, stream>>>(h, g, gh16, ln_gamma, ln_beta, 0);
        // Q|K projection: one z=2 launch (f32 out)
        gemm_h16<<<dim3(6, 25, 2), 256, 0, stream>>>(
            gh16, WmQTh16, Qb, nullptr,
            NROWS, D, D, D, D, D, 0, /*sAz*/0, /*sBz*/(long)DD, /*sCz*/SZ);
        attn_p_kernel<<<dim3(192, 13), 256, 0, stream>>>(Qb, Kb, Pt, Pn);
        // G1 = Pt@K, G2 = Pn@Q -> direct fp16 out
        gemm(Pt, Kb, nullptr, G1h16, nullptr, NTOK, HD, NTOK, PLD, D, D,
             NB * NH, NH, (long)NH * PBH, PBH, (long)NTOK * D, HD, (long)NTOK * D, HD, FLAG_H16);
        gemm(Pn, Qb, nullptr, G2h16, nullptr, NTOK, HD, NTOK, PLD, D, D,
             NB * NH, NH, (long)NH * PBH, PBH, (long)NTOK * D, HD, (long)NTOK * D, HD, FLAG_H16);
        // Hopfield-1: HH = relu(g @ xi), fp16 out  (after Pt/Pn consumed: HH16 aliases Pt)
        gemm_h16<<<dim3(24, 25, 1), 256, 0, stream>>>(
            gh16, xiTh16, HH16, nullptr, NROWS, HOP, D, D, D, HOP, FLAG_H16 | FLAG_RELU, 0, 0, 0);
        // fused split-K accumulate: 6 partial slabs in one 900-block launch
        gemm_h16_fused<<<dim3(6, 25, 6), 256, 0, stream>>>(
            G1h16, G2h16, HH16, WmQh16, WmKh16, xibh16, part);
        reduce6_kernel<<<RED_BLOCKS, 256, 0, stream>>>(h, part);
    }

    // ---- final LN (compact, f32) + output projection (f32) ----
    ln_kernel<<<NB * NPATCH, 256, 0, stream>>>(h, g, nullptr, out_gamma, out_beta, 1);
    gemm(g, out_w, out, nullptr, out_b, NPROWS, D, D, D, D, D, 1, 1, 0, 0, 0, 0, 0, 0, 0);
}

// Round 12
// 1402.324 us; speedup vs baseline: 5.0458x; 1.2637x over previous
//
#include <hip/hip_runtime.h>

#define NB 16
#define NTOK 197
#define NPATCH 196
#define D 768
#define NH 12
#define HD 64
#define HOP 3072
#define TSTEPS 6
#define BETA_F 0.125f
#define PLD 208                 // Pt leading dim (f32)
#define PBH (NTOK * PLD)        // 40976
#define NROWS (NB * NTOK)       // 3152
#define NPROWS (NB * NPATCH)    // 3136
#define AROWS 3200              // padded rows for MFMA A-side staging
#define DD (768 * 768)
#define DH (768 * 3072)
#define SZL ((long)NROWS * D)   // 2,420,736

typedef unsigned short u16;
typedef __attribute__((ext_vector_type(8))) _Float16 f16x8;
typedef __attribute__((ext_vector_type(4))) float f32x4;

#define FLAG_ACC 1
#define FLAG_RELU 2
#define FLAG_H16 4

__device__ __forceinline__ u16 f2h(float f) {
    union { _Float16 h; u16 u; } cv;
    cv.h = (_Float16)f;
    return cv.u;
}

__device__ __forceinline__ void gld16(const void* g, void* l) {
    __builtin_amdgcn_global_load_lds((const __attribute__((address_space(1))) void*)g,
                                     (__attribute__((address_space(3))) void*)l, 16, 0, 0);
}

// ---------------- single-fp16 MFMA GEMM (R11-verbatim; used for out-projection) ----------------
__global__ __launch_bounds__(256) void gemm_h16(
    const u16* __restrict__ A, const u16* __restrict__ B,
    void* __restrict__ Cv, const float* __restrict__ bias,
    int M, int N, int K, int lda, int ldbt, int ldc, int flags,
    long sAz, long sBz, long sCz) {
    __shared__ __align__(16) u16 As[128 * 32];
    __shared__ __align__(16) u16 Bs[128 * 32];
    int zz = blockIdx.z;
    A += (long)zz * sAz;
    B += (long)zz * sBz;
    long czoff = (long)zz * sCz;
    int t = threadIdx.x;
    int w = t >> 6, lane = t & 63;
    int lr = lane & 15, lg = lane >> 4, ko = lg * 8;
    int wr = w >> 1, wc = w & 1;
    long row0 = (long)blockIdx.y * 128, col0 = (long)blockIdx.x * 128;

    f32x4 acc[4][4];
#pragma unroll
    for (int i = 0; i < 4; i++)
#pragma unroll
        for (int j = 0; j < 4; j++) acc[i][j] = (f32x4){0.f, 0.f, 0.f, 0.f};

    int c0 = w * 64 + lane;
    int r0s = c0 >> 2, k0s = (c0 & 3) << 3;
    int c1 = 256 + w * 64 + lane;
    int r1s = c1 >> 2, k1s = (c1 & 3) << 3;

    for (int kt = 0; kt < K; kt += 32) {
        const u16* AB = A + row0 * lda + kt;
        const u16* BB = B + col0 * ldbt + kt;
        gld16(AB + (long)r0s * lda + k0s, (char*)As + (w * 64) * 16);
        gld16(AB + (long)r1s * lda + k1s, (char*)As + (256 + w * 64) * 16);
        gld16(BB + (long)r0s * ldbt + k0s, (char*)Bs + (w * 64) * 16);
        gld16(BB + (long)r1s * ldbt + k1s, (char*)Bs + (256 + w * 64) * 16);
        __syncthreads();
        f16x8 af[4], bf[4];
#pragma unroll
        for (int mi = 0; mi < 4; mi++) af[mi] = *(const f16x8*)&As[(wr * 64 + mi * 16 + lr) * 32 + ko];
#pragma unroll
        for (int ni = 0; ni < 4; ni++) bf[ni] = *(const f16x8*)&Bs[(wc * 64 + ni * 16 + lr) * 32 + ko];
#pragma unroll
        for (int mi = 0; mi < 4; mi++)
#pragma unroll
            for (int ni = 0; ni < 4; ni++)
                acc[mi][ni] = __builtin_amdgcn_mfma_f32_16x16x32_f16(af[mi], bf[ni], acc[mi][ni], 0, 0, 0);
        __syncthreads();
    }

    long mbase = row0 + wr * 64;
    long nbase = col0 + wc * 64;
#pragma unroll
    for (int mi = 0; mi < 4; mi++) {
#pragma unroll
        for (int r = 0; r < 4; r++) {
            long grow = mbase + mi * 16 + lg * 4 + r;
            if (grow >= M) continue;
#pragma unroll
            for (int ni = 0; ni < 4; ni++) {
                long gcol = nbase + ni * 16 + lr;
                float v = acc[mi][ni][r];
                if (bias) v += bias[gcol];
                if (flags & FLAG_RELU) v = fmaxf(v, 0.f);
                long idx = czoff + grow * ldc + gcol;
                if (flags & FLAG_ACC) ((float*)Cv)[idx] += v;
                else if (flags & FLAG_H16) ((u16*)Cv)[idx] = f2h(v);
                else ((float*)Cv)[idx] = v;
            }
        }
    }
}

// ---------------- fused projection: QK (f32 out) + Hopfield-1 (fp16+relu) in one launch ----------------
// grid (36, 25): x<6 -> Qb cols, x<12 -> Kb cols, x>=12 -> HH cols (xiT).
__global__ __launch_bounds__(256) void fused_proj(
    const u16* __restrict__ A,
    const u16* __restrict__ WQT, const u16* __restrict__ WKT, const u16* __restrict__ XIT,
    float* __restrict__ Qb, float* __restrict__ Kb, u16* __restrict__ HH) {
    __shared__ __align__(16) u16 As[128 * 32];
    __shared__ __align__(16) u16 Bs[128 * 32];
    int cx = blockIdx.x;
    const u16* B; int ldc; long col0; int mode;
    if (cx < 6)       { B = WQT; ldc = 768;  col0 = (long)cx * 128;        mode = 0; }
    else if (cx < 12) { B = WKT; ldc = 768;  col0 = (long)(cx - 6) * 128;  mode = 1; }
    else              { B = XIT; ldc = 3072; col0 = (long)(cx - 12) * 128; mode = 2; }
    int t = threadIdx.x;
    int w = t >> 6, lane = t & 63;
    int lr = lane & 15, lg = lane >> 4, ko = lg * 8;
    int wr = w >> 1, wc = w & 1;
    long row0 = (long)blockIdx.y * 128;

    f32x4 acc[4][4];
#pragma unroll
    for (int i = 0; i < 4; i++)
#pragma unroll
        for (int j = 0; j < 4; j++) acc[i][j] = (f32x4){0.f, 0.f, 0.f, 0.f};

    int c0 = w * 64 + lane;
    int r0s = c0 >> 2, k0s = (c0 & 3) << 3;
    int c1 = 256 + w * 64 + lane;
    int r1s = c1 >> 2, k1s = (c1 & 3) << 3;

    for (int kt = 0; kt < 768; kt += 32) {
        const u16* AB = A + row0 * 768 + kt;
        const u16* BB = B + col0 * 768 + kt;
        gld16(AB + (long)r0s * 768 + k0s, (char*)As + (w * 64) * 16);
        gld16(AB + (long)r1s * 768 + k1s, (char*)As + (256 + w * 64) * 16);
        gld16(BB + (long)r0s * 768 + k0s, (char*)Bs + (w * 64) * 16);
        gld16(BB + (long)r1s * 768 + k1s, (char*)Bs + (256 + w * 64) * 16);
        __syncthreads();
        f16x8 af[4], bf[4];
#pragma unroll
        for (int mi = 0; mi < 4; mi++) af[mi] = *(const f16x8*)&As[(wr * 64 + mi * 16 + lr) * 32 + ko];
#pragma unroll
        for (int ni = 0; ni < 4; ni++) bf[ni] = *(const f16x8*)&Bs[(wc * 64 + ni * 16 + lr) * 32 + ko];
#pragma unroll
        for (int mi = 0; mi < 4; mi++)
#pragma unroll
            for (int ni = 0; ni < 4; ni++)
                acc[mi][ni] = __builtin_amdgcn_mfma_f32_16x16x32_f16(af[mi], bf[ni], acc[mi][ni], 0, 0, 0);
        __syncthreads();
    }

    long mbase = row0 + wr * 64;
    long nbase = col0 + wc * 64;
#pragma unroll
    for (int mi = 0; mi < 4; mi++) {
#pragma unroll
        for (int r = 0; r < 4; r++) {
            long grow = mbase + mi * 16 + lg * 4 + r;
            if (grow >= NROWS) continue;
#pragma unroll
            for (int ni = 0; ni < 4; ni++) {
                long gcol = nbase + ni * 16 + lr;
                float v = acc[mi][ni][r];
                long idx = grow * ldc + gcol;
                if (mode == 0)      Qb[idx] = v;
                else if (mode == 1) Kb[idx] = v;
                else                HH[idx] = f2h(fmaxf(v, 0.f));
            }
        }
    }
}

// ---------------- fused accumulate GEMM: 6 split-K partials (R11-verbatim) ----------------
__global__ __launch_bounds__(256) void gemm_h16_fused(
    const u16* __restrict__ G1, const u16* __restrict__ G2, const u16* __restrict__ HH,
    const u16* __restrict__ WQ, const u16* __restrict__ WK, const u16* __restrict__ XB,
    float* __restrict__ part) {
    __shared__ __align__(16) u16 As[128 * 32];
    __shared__ __align__(16) u16 Bs[128 * 32];
    int zz = blockIdx.z;
    const u16* A; const u16* B; int lda; int K0;
    if (zz == 0)      { A = G1; B = WQ; lda = 768;  K0 = 0; }
    else if (zz == 1) { A = G2; B = WK; lda = 768;  K0 = 0; }
    else              { A = HH; B = XB; lda = 3072; K0 = (zz - 2) * 768; }
    float* C = part + (long)zz * SZL;

    int t = threadIdx.x;
    int w = t >> 6, lane = t & 63;
    int lr = lane & 15, lg = lane >> 4, ko = lg * 8;
    int wr = w >> 1, wc = w & 1;
    long row0 = (long)blockIdx.y * 128, col0 = (long)blockIdx.x * 128;

    f32x4 acc[4][4];
#pragma unroll
    for (int i = 0; i < 4; i++)
#pragma unroll
        for (int j = 0; j < 4; j++) acc[i][j] = (f32x4){0.f, 0.f, 0.f, 0.f};

    int c0 = w * 64 + lane;
    int r0s = c0 >> 2, k0s = (c0 & 3) << 3;
    int c1 = 256 + w * 64 + lane;
    int r1s = c1 >> 2, k1s = (c1 & 3) << 3;

    for (int kt = K0; kt < K0 + 768; kt += 32) {
        const u16* AB = A + row0 * lda + kt;
        const u16* BB = B + col0 * (long)lda + kt;
        gld16(AB + (long)r0s * lda + k0s, (char*)As + (w * 64) * 16);
        gld16(AB + (long)r1s * lda + k1s, (char*)As + (256 + w * 64) * 16);
        gld16(BB + (long)r0s * lda + k0s, (char*)Bs + (w * 64) * 16);
        gld16(BB + (long)r1s * lda + k1s, (char*)Bs + (256 + w * 64) * 16);
        __syncthreads();
        f16x8 af[4], bf[4];
#pragma unroll
        for (int mi = 0; mi < 4; mi++) af[mi] = *(const f16x8*)&As[(wr * 64 + mi * 16 + lr) * 32 + ko];
#pragma unroll
        for (int ni = 0; ni < 4; ni++) bf[ni] = *(const f16x8*)&Bs[(wc * 64 + ni * 16 + lr) * 32 + ko];
#pragma unroll
        for (int mi = 0; mi < 4; mi++)
#pragma unroll
            for (int ni = 0; ni < 4; ni++)
                acc[mi][ni] = __builtin_amdgcn_mfma_f32_16x16x32_f16(af[mi], bf[ni], acc[mi][ni], 0, 0, 0);
        __syncthreads();
    }

    long mbase = row0 + wr * 64;
    long nbase = col0 + wc * 64;
#pragma unroll
    for (int mi = 0; mi < 4; mi++) {
#pragma unroll
        for (int r = 0; r < 4; r++) {
            long grow = mbase + mi * 16 + lg * 4 + r;
            if (grow >= NROWS) continue;
#pragma unroll
            for (int ni = 0; ni < 4; ni++) {
                long gcol = nbase + ni * 16 + lr;
                C[grow * D + gcol] = acc[mi][ni][r];
            }
        }
    }
}

// ---------------- fused reduce + layernorm: h (+= 6 slabs) -> LN -> fp16 ----------------
__global__ __launch_bounds__(256) void ln_fuse_kernel(
    float* __restrict__ X, u16* __restrict__ Yh16, const float* __restrict__ part,
    const float* __restrict__ gamma, const float* __restrict__ beta,
    int compact, int doReduce, int writeBack) {
    int r = blockIdx.x;
    long xrow = compact ? ((long)(r / NPATCH) * NTOK + 1 + (r % NPATCH)) : (long)r;
    float* x = X + xrow * D;
    int t = threadIdx.x;
    float v[3];
    float s = 0.f, ss = 0.f;
#pragma unroll
    for (int i = 0; i < 3; i++) {
        int c = t + 256 * i;
        float val = x[c];
        if (doReduce) {
            long off = xrow * D + c;
            float p01 = part[off] + part[SZL + off];
            float p23 = part[2 * SZL + off] + part[3 * SZL + off];
            float p45 = part[4 * SZL + off] + part[5 * SZL + off];
            val += (p01 + p23) + p45;
            if (writeBack) x[c] = val;
        }
        v[i] = val;
        s += val;
        ss += val * val;
    }
    __shared__ float red[8];
    for (int off = 32; off; off >>= 1) {
        s += __shfl_down(s, off, 64);
        ss += __shfl_down(ss, off, 64);
    }
    int wid = t >> 6, lane = t & 63;
    if (lane == 0) { red[wid] = s; red[4 + wid] = ss; }
    __syncthreads();
    s = red[0] + red[1] + red[2] + red[3];
    ss = red[4] + red[5] + red[6] + red[7];
    float mu = s * (1.f / 768.f);
    float var = ss * (1.f / 768.f) - mu * mu;
    float inv = rsqrtf(var + 1e-5f);
#pragma unroll
    for (int i = 0; i < 3; i++) {
        int c = t + 256 * i;
        float yv = gamma[c] * (v[i] - mu) * inv + beta[c];
        Yh16[(long)r * D + c] = f2h(yv);
    }
}

// ---------------- parallel f32 attention softmax (stride-65 LDS, Pt only) ----------------
__global__ __launch_bounds__(256) void attn_p_kernel(const float* __restrict__ Q, const float* __restrict__ K,
                                                     float* __restrict__ Pt) {
    __shared__ float Ks[NTOK][65];
    int bh = blockIdx.x, mt = blockIdx.y;
    int b = bh / NH, h = bh % NH;
    int t = threadIdx.x;
    const float* Kb = K + (long)b * NTOK * D + h * HD;
    for (int i = t; i < NTOK * 16; i += 256) {
        int n = i >> 4, k4 = (i & 15) << 2;
        float4 v = *(const float4*)(Kb + (long)n * D + k4);
        Ks[n][k4] = v.x; Ks[n][k4 + 1] = v.y; Ks[n][k4 + 2] = v.z; Ks[n][k4 + 3] = v.w;
    }
    __syncthreads();
    int ql = t >> 4, l16 = t & 15;
    int m = mt * 16 + ql;
    int mr = m < NTOK ? m : NTOK - 1;
    const float* Qrow = Q + (long)(b * NTOK + mr) * D + h * HD;
    float q[64];
#pragma unroll
    for (int k = 0; k < 64; k += 4) {
        float4 v = *(const float4*)(Qrow + k);
        q[k] = v.x; q[k + 1] = v.y; q[k + 2] = v.z; q[k + 3] = v.w;
    }
    float s[13];
    float mx = -1e30f;
#pragma unroll
    for (int i = 0; i < 13; i++) {
        int n = i * 16 + l16;
        const float* kr = Ks[n < NTOK ? n : 0];
        float a0 = 0.f, a1 = 0.f, a2 = 0.f, a3 = 0.f;
#pragma unroll
        for (int k = 0; k < 64; k += 4) {
            a0 += kr[k] * q[k];
            a1 += kr[k + 1] * q[k + 1];
            a2 += kr[k + 2] * q[k + 2];
            a3 += kr[k + 3] * q[k + 3];
        }
        float sv = ((a0 + a1) + (a2 + a3)) * BETA_F;
        s[i] = (n < NTOK) ? sv : -1e30f;
        mx = fmaxf(mx, s[i]);
    }
    mx = fmaxf(mx, __shfl_xor(mx, 1, 64));
    mx = fmaxf(mx, __shfl_xor(mx, 2, 64));
    mx = fmaxf(mx, __shfl_xor(mx, 4, 64));
    mx = fmaxf(mx, __shfl_xor(mx, 8, 64));
    float ssum = 0.f;
#pragma unroll
    for (int i = 0; i < 13; i++) {
        float e = (s[i] > -1e29f) ? __expf(s[i] - mx) : 0.f;
        s[i] = e;
        ssum += e;
    }
    ssum += __shfl_xor(ssum, 1, 64);
    ssum += __shfl_xor(ssum, 2, 64);
    ssum += __shfl_xor(ssum, 4, 64);
    ssum += __shfl_xor(ssum, 8, 64);
    float inv = 1.f / ssum;
    if (m < NTOK) {
        float* PtB = Pt + (long)bh * PBH;
#pragma unroll
        for (int i = 0; i < 13; i++) {
            int n = i * 16 + l16;
            if (n < NTOK) PtB[(long)m * PLD + n] = s[i] * inv;
        }
    }
}

// ---------------- attention grads: G1 (A normal) + G2 (A transposed) in one launch ----------------
// z = which*192 + bh. which=0: G1[m,k] = sum_n Pt[m,n]*K[n,k]; which=1: G2[n,k] = sum_m Pt[m,n]*Q[m,k].
__global__ __launch_bounds__(256) void attn_g_kernel(
    const float* __restrict__ Pt, const float* __restrict__ Qb, const float* __restrict__ Kb,
    u16* __restrict__ G1, u16* __restrict__ G2) {
    __shared__ float As[16][68];
    __shared__ float Bs[16][68];
    int z = blockIdx.z;
    int which = z / 192, bh = z - which * 192;
    int b = bh / NH, h = bh % NH;
    const float* A = Pt + (long)bh * PBH;
    const float* B = (which ? Qb : Kb) + (long)b * NTOK * D + h * HD;
    u16* G = which ? G2 : G1;

    int t = threadIdx.x;
    int tx = t & 15, ty = t >> 4;
    int row0 = blockIdx.y * 64;

    float acc[4][4] = {};

    for (int kt = 0; kt < NTOK; kt += 16) {
        if (which == 0) {
            // As[k][r] = Pt[row0+r][kt+k]
            int r = t >> 2, c4 = (t & 3) << 2;
            int gr = row0 + r, gk = kt + c4;
            float4 v = make_float4(0.f, 0.f, 0.f, 0.f);
            if (gr < NTOK) {
                if (gk + 3 < NTOK) {
                    v = *(const float4*)(A + (long)gr * PLD + gk);
                } else {
                    float x0 = (gk < NTOK) ? A[(long)gr * PLD + gk] : 0.f;
                    float x1 = (gk + 1 < NTOK) ? A[(long)gr * PLD + gk + 1] : 0.f;
                    float x2 = (gk + 2 < NTOK) ? A[(long)gr * PLD + gk + 2] : 0.f;
                    float x3 = (gk + 3 < NTOK) ? A[(long)gr * PLD + gk + 3] : 0.f;
                    v = make_float4(x0, x1, x2, x3);
                }
            }
            As[c4 + 0][r] = v.x; As[c4 + 1][r] = v.y; As[c4 + 2][r] = v.z; As[c4 + 3][r] = v.w;
        } else {
            // As[k][r] = Pt[kt+k][row0+r]  (transposed A: coalesced rows of Pt)
            int rr = t >> 4, c4 = (t & 15) << 2;
            int gk = kt + rr, gc = row0 + c4;
            float4 v = make_float4(0.f, 0.f, 0.f, 0.f);
            if (gk < NTOK && gc + 3 < PLD) v = *(const float4*)(A + (long)gk * PLD + gc);
            As[rr][c4 + 0] = v.x; As[rr][c4 + 1] = v.y; As[rr][c4 + 2] = v.z; As[rr][c4 + 3] = v.w;
        }
        {
            int r = t >> 4, c4 = (t & 15) << 2;
            int gk = kt + r;
            float4 v = make_float4(0.f, 0.f, 0.f, 0.f);
            if (gk < NTOK) v = *(const float4*)(B + (long)gk * D + c4);
            Bs[r][c4 + 0] = v.x; Bs[r][c4 + 1] = v.y; Bs[r][c4 + 2] = v.z; Bs[r][c4 + 3] = v.w;
        }
        __syncthreads();
#pragma unroll
        for (int kk = 0; kk < 16; kk++) {
            float av[4], bv[4];
#pragma unroll
            for (int i = 0; i < 4; i++) av[i] = As[kk][ty * 4 + i];
#pragma unroll
            for (int j = 0; j < 4; j++) bv[j] = Bs[kk][tx * 4 + j];
#pragma unroll
            for (int i = 0; i < 4; i++)
#pragma unroll
                for (int j = 0; j < 4; j++) acc[i][j] += av[i] * bv[j];
        }
        __syncthreads();
    }
#pragma unroll
    for (int i = 0; i < 4; i++) {
        int gr = row0 + ty * 4 + i;
        if (gr >= NTOK) continue;
#pragma unroll
        for (int j = 0; j < 4; j++) {
            int gc = tx * 4 + j;
            long idx = ((long)(b * NTOK + gr)) * D + h * HD + gc;
            G[idx] = f2h(acc[i][j]);
        }
    }
}

// ================= setup pieces =================

__global__ __launch_bounds__(256) void patchify_kernel(const float* __restrict__ x, float* __restrict__ tok) {
    int idx = blockIdx.x * 256 + threadIdx.x;
    const int total = NB * NPATCH * D;
    if (idx >= total) return;
    int d = idx % D;
    int p = (idx / D) % NPATCH;
    int b = idx / (D * NPATCH);
    int c = d >> 8;
    int pi = (d >> 4) & 15;
    int pj = d & 15;
    int hp = p / 14, wp = p % 14;
    int row = hp * 16 + pi, col = wp * 16 + pj;
    tok[idx] = x[(((long)b * 3 + c) * 224 + row) * 224 + col];
}

__global__ __launch_bounds__(256) void cls_pos_kernel(float* __restrict__ h, const float* __restrict__ cls,
                                                      const float* __restrict__ pos) {
    int idx = blockIdx.x * 256 + threadIdx.x;
    const int total = NB * NTOK * D;
    if (idx >= total) return;
    int d = idx % D;
    int n = (idx / D) % NTOK;
    float v = pos[n * D + d];
    if (n == 0) h[idx] = cls[d] + v;
    else        h[idx] = h[idx] + v;
}

__global__ __launch_bounds__(256) void wcat_kernel(const float* __restrict__ w, float* __restrict__ Wm) {
    int idx = blockIdx.x * 256 + threadIdx.x;
    const int total = NH * D * HD;
    if (idx >= total) return;
    int k = idx & 63;
    int d = (idx >> 6) % D;
    int hh = idx / (D * HD);
    Wm[d * D + hh * HD + k] = w[idx];
}

// ---------------- f32 GEMM (patch embed only; R11-verbatim minus unused paths) ----------------
__global__ __launch_bounds__(256) void gemm_f32(
    const float* __restrict__ A, const float* __restrict__ B, float* __restrict__ C,
    const float* __restrict__ bias,
    int M, int N, int K, int lda, int ldb, int ldc,
    long sA1, long sC1) {
    int z = blockIdx.z;
    A += (long)z * sA1;
    long coff = (long)z * sC1;

    __shared__ float As[16][68];
    __shared__ float Bs[16][68];

    int t = threadIdx.x;
    int tx = t & 15, ty = t >> 4;
    int row0 = blockIdx.y * 64, col0 = blockIdx.x * 64;

    float acc[4][4] = {};

    for (int kt = 0; kt < K; kt += 16) {
        {
            int r = t >> 2;
            int c4 = (t & 3) << 2;
            int gr = row0 + r;
            int gk = kt + c4;
            float4 v = make_float4(0.f, 0.f, 0.f, 0.f);
            if (gr < M && gk + 3 < K) v = *(const float4*)(A + (long)gr * lda + gk);
            As[c4 + 0][r] = v.x; As[c4 + 1][r] = v.y; As[c4 + 2][r] = v.z; As[c4 + 3][r] = v.w;
        }
        {
            int r = t >> 4;
            int c4 = (t & 15) << 2;
            int gk = kt + r;
            int gc = col0 + c4;
            float4 v = make_float4(0.f, 0.f, 0.f, 0.f);
            if (gk < K && gc + 3 < N) v = *(const float4*)(B + (long)gk * ldb + gc);
            Bs[r][c4 + 0] = v.x; Bs[r][c4 + 1] = v.y; Bs[r][c4 + 2] = v.z; Bs[r][c4 + 3] = v.w;
        }
        __syncthreads();
#pragma unroll
        for (int kk = 0; kk < 16; kk++) {
            float av[4], bv[4];
#pragma unroll
            for (int i = 0; i < 4; i++) av[i] = As[kk][ty * 4 + i];
#pragma unroll
            for (int j = 0; j < 4; j++) bv[j] = Bs[kk][tx * 4 + j];
#pragma unroll
            for (int i = 0; i < 4; i++)
#pragma unroll
                for (int j = 0; j < 4; j++) acc[i][j] += av[i] * bv[j];
        }
        __syncthreads();
    }
#pragma unroll
    for (int i = 0; i < 4; i++) {
        int gr = row0 + ty * 4 + i;
        if (gr >= M) continue;
#pragma unroll
        for (int j = 0; j < 4; j++) {
            int gc = col0 + tx * 4 + j;
            if (gc >= N) continue;
            float v = acc[i][j];
            if (bias) v += bias[gc];
            C[coff + (long)gr * ldc + gc] = v;
        }
    }
}

// fp16 preps
__global__ __launch_bounds__(256) void prep_transpose_h(const float* __restrict__ src,
                                                        u16* __restrict__ dst, int R, int C) {
    int idx = blockIdx.x * 256 + threadIdx.x;
    if (idx >= R * C) return;
    int r = idx % R, c = idx / R;
    dst[idx] = f2h(src[(long)r * C + c]);
}
__global__ __launch_bounds__(256) void prep_convert_h(const float* __restrict__ src,
                                                      u16* __restrict__ dst, int n) {
    int idx = blockIdx.x * 256 + threadIdx.x;
    if (idx >= n) return;
    dst[idx] = f2h(src[idx]);
}

extern "C" void kernel_launch(void* const* d_in, const int* in_sizes, int n_in,
                              void* d_out, int out_size, void* d_ws, size_t ws_size,
                              hipStream_t stream) {
    const float* x        = (const float*)d_in[0];
    const float* patch_w  = (const float*)d_in[1];
    const float* patch_b  = (const float*)d_in[2];
    const float* cls_tok  = (const float*)d_in[3];
    const float* pos_emb  = (const float*)d_in[4];
    const float* ln_gamma = (const float*)d_in[5];
    const float* ln_beta  = (const float*)d_in[6];
    const float* wq       = (const float*)d_in[7];
    const float* wk       = (const float*)d_in[8];
    const float* xi       = (const float*)d_in[9];
    const float* out_gamma= (const float*)d_in[10];
    const float* out_beta = (const float*)d_in[11];
    const float* out_w    = (const float*)d_in[12];
    const float* out_b    = (const float*)d_in[13];
    float* out = (float*)d_out;

    float* ws = (float*)d_ws;
    const long SZ = SZL;
    const long AR = (long)AROWS * D;
    float* h  = ws;
    float* Qb = ws + SZ;
    float* Kb = ws + 2 * SZ;
    u16* gh16    = (u16*)(ws + 3 * SZ);
    u16* WmQTh16 = gh16 + AR;
    u16* WmKTh16 = WmQTh16 + DD;
    u16* WmQh16  = WmKTh16 + DD;
    u16* WmKh16  = WmQh16 + DD;
    u16* xiTh16  = WmKh16 + DD;
    u16* xibh16  = xiTh16 + DH;
    u16* G1h16   = xibh16 + DH;
    u16* G2h16   = G1h16 + AR;
    u16* HH16    = G2h16 + AR;
    u16* owTh16  = HH16 + (long)AROWS * HOP;
    // shared region: part (6*SZ f32) | Pt (192*PBH f32) | tok + WmQ/WmK (setup)
    float* R1  = (float*)(owTh16 + DD);
    float* Pt  = R1;
    float* part = R1;
    float* tok = R1;
    float* WmQ = R1 + SZ;
    float* WmK = WmQ + DD;

    // ---- setup ----
    patchify_kernel<<<(NB * NPATCH * D + 255) / 256, 256, 0, stream>>>(x, tok);
    wcat_kernel<<<(NH * D * HD + 255) / 256, 256, 0, stream>>>(wq, WmQ);
    wcat_kernel<<<(NH * D * HD + 255) / 256, 256, 0, stream>>>(wk, WmK);
    prep_transpose_h<<<(DD + 255) / 256, 256, 0, stream>>>(WmQ, WmQTh16, 768, 768);
    prep_transpose_h<<<(DD + 255) / 256, 256, 0, stream>>>(WmK, WmKTh16, 768, 768);
    prep_convert_h<<<(DD + 255) / 256, 256, 0, stream>>>(WmQ, WmQh16, DD);
    prep_convert_h<<<(DD + 255) / 256, 256, 0, stream>>>(WmK, WmKh16, DD);
    prep_transpose_h<<<(DH + 255) / 256, 256, 0, stream>>>(xi, xiTh16, 768, HOP);
    prep_convert_h<<<(DH + 255) / 256, 256, 0, stream>>>(xi, xibh16, DH);
    prep_transpose_h<<<(DD + 255) / 256, 256, 0, stream>>>(out_w, owTh16, 768, 768);
    // patch embed: f32 (h0 seed stays f32 — sensitivity firewall)
    gemm_f32<<<dim3(12, 4, NB), 256, 0, stream>>>(
        tok, patch_w, h + D, patch_b, NPATCH, D, D, D, D, D,
        (long)NPATCH * D, (long)NTOK * D);
    cls_pos_kernel<<<(NB * NTOK * D + 255) / 256, 256, 0, stream>>>(h, cls_tok, pos_emb);

    for (int step = 0; step < TSTEPS; step++) {
        // LN (+ deferred accumulate of previous step's partials)
        ln_fuse_kernel<<<NROWS, 256, 0, stream>>>(h, gh16, part, ln_gamma, ln_beta,
                                                  0, step > 0 ? 1 : 0, 1);
        // QK projection + Hopfield-1 in one 900-block launch
        fused_proj<<<dim3(36, 25), 256, 0, stream>>>(gh16, WmQTh16, WmKTh16, xiTh16, Qb, Kb, HH16);
        // attention softmax -> Pt only (overwrites part region; part already consumed)
        attn_p_kernel<<<dim3(192, 13), 256, 0, stream>>>(Qb, Kb, Pt);
        // G1 + G2 in one launch (G2 via transposed-A staging)
        attn_g_kernel<<<dim3(1, 4, 384), 256, 0, stream>>>(Pt, Qb, Kb, G1h16, G2h16);
        // fused split-K accumulate -> 6 partial slabs (overwrites Pt; Pt already consumed)
        gemm_h16_fused<<<dim3(6, 25, 6), 256, 0, stream>>>(
            G1h16, G2h16, HH16, WmQh16, WmKh16, xibh16, part);
    }

    // ---- final: reduce + LN (compact) -> fp16, then out projection (fp16 MFMA) ----
    ln_fuse_kernel<<<NPROWS, 256, 0, stream>>>(h, gh16, part, out_gamma, out_beta, 1, 1, 0);
    gemm_h16<<<dim3(6, 25, 1), 256, 0, stream>>>(
        gh16, owTh16, out, out_b, NPROWS, D, D, D, D, D, 0, 0, 0, 0);
}

// Round 13
// 1393.537 us; speedup vs baseline: 5.0776x; 1.0063x over previous
//
#include <hip/hip_runtime.h>

#define NB 16
#define NTOK 197
#define NPATCH 196
#define D 768
#define NH 12
#define HD 64
#define HOP 3072
#define TSTEPS 6
#define BETA_F 0.125f
#define PLD 208                 // Pt leading dim (f32)
#define PBH (NTOK * PLD)        // 40976
#define NROWS (NB * NTOK)       // 3152
#define NPROWS (NB * NPATCH)    // 3136
#define AROWS 3200              // padded rows for MFMA A-side staging
#define DD (768 * 768)
#define DH (768 * 3072)
#define SZL ((long)NROWS * D)   // 2,420,736

typedef unsigned short u16;
typedef __attribute__((ext_vector_type(8))) _Float16 f16x8;
typedef __attribute__((ext_vector_type(4))) float f32x4;

#define FLAG_ACC 1
#define FLAG_RELU 2
#define FLAG_H16 4

__device__ __forceinline__ u16 f2h(float f) {
    union { _Float16 h; u16 u; } cv;
    cv.h = (_Float16)f;
    return cv.u;
}

__device__ __forceinline__ void gld16(const void* g, void* l) {
    __builtin_amdgcn_global_load_lds((const __attribute__((address_space(1))) void*)g,
                                     (__attribute__((address_space(3))) void*)l, 16, 0, 0);
}

// Swizzle note (T2 adapted for global_load_lds, rule #21):
// LDS slot (r, js) holds global 16B-chunk (r, js ^ ((r>>1)&3)).
// Staging: global k-offset for chunk c is ((c&3) ^ ((r>>1)&3))*8, r = c>>2 (per-lane global addr, LDS dest linear).
// Read: fragment (row, lg) reads slot js = lg ^ ((row>>1)&3)  -> 16-lane reads cover all 8 LDS 16B positions 2x (free).

// ---------------- single-fp16 MFMA GEMM (swizzled; used for out-projection) ----------------
__global__ __launch_bounds__(256) void gemm_h16(
    const u16* __restrict__ A, const u16* __restrict__ B,
    void* __restrict__ Cv, const float* __restrict__ bias,
    int M, int N, int K, int lda, int ldbt, int ldc, int flags,
    long sAz, long sBz, long sCz) {
    __shared__ __align__(16) u16 As[128 * 32];
    __shared__ __align__(16) u16 Bs[128 * 32];
    int zz = blockIdx.z;
    A += (long)zz * sAz;
    B += (long)zz * sBz;
    long czoff = (long)zz * sCz;
    int t = threadIdx.x;
    int w = t >> 6, lane = t & 63;
    int lr = lane & 15, lg = lane >> 4;
    int wr = w >> 1, wc = w & 1;
    long row0 = (long)blockIdx.y * 128, col0 = (long)blockIdx.x * 128;

    f32x4 acc[4][4];
#pragma unroll
    for (int i = 0; i < 4; i++)
#pragma unroll
        for (int j = 0; j < 4; j++) acc[i][j] = (f32x4){0.f, 0.f, 0.f, 0.f};

    int c0 = w * 64 + lane;
    int r0s = c0 >> 2, k0s = (((c0 & 3) ^ ((r0s >> 1) & 3)) << 3);
    int c1 = 256 + w * 64 + lane;
    int r1s = c1 >> 2, k1s = (((c1 & 3) ^ ((r1s >> 1) & 3)) << 3);

    for (int kt = 0; kt < K; kt += 32) {
        const u16* AB = A + row0 * lda + kt;
        const u16* BB = B + col0 * ldbt + kt;
        gld16(AB + (long)r0s * lda + k0s, (char*)As + (w * 64) * 16);
        gld16(AB + (long)r1s * lda + k1s, (char*)As + (256 + w * 64) * 16);
        gld16(BB + (long)r0s * ldbt + k0s, (char*)Bs + (w * 64) * 16);
        gld16(BB + (long)r1s * ldbt + k1s, (char*)Bs + (256 + w * 64) * 16);
        __syncthreads();
        f16x8 af[4], bf[4];
#pragma unroll
        for (int mi = 0; mi < 4; mi++) {
            int row = wr * 64 + mi * 16 + lr;
            af[mi] = *(const f16x8*)&As[row * 32 + ((lg ^ ((row >> 1) & 3)) << 3)];
        }
#pragma unroll
        for (int ni = 0; ni < 4; ni++) {
            int row = wc * 64 + ni * 16 + lr;
            bf[ni] = *(const f16x8*)&Bs[row * 32 + ((lg ^ ((row >> 1) & 3)) << 3)];
        }
#pragma unroll
        for (int mi = 0; mi < 4; mi++)
#pragma unroll
            for (int ni = 0; ni < 4; ni++)
                acc[mi][ni] = __builtin_amdgcn_mfma_f32_16x16x32_f16(af[mi], bf[ni], acc[mi][ni], 0, 0, 0);
        __syncthreads();
    }

    long mbase = row0 + wr * 64;
    long nbase = col0 + wc * 64;
#pragma unroll
    for (int mi = 0; mi < 4; mi++) {
#pragma unroll
        for (int r = 0; r < 4; r++) {
            long grow = mbase + mi * 16 + lg * 4 + r;
            if (grow >= M) continue;
#pragma unroll
            for (int ni = 0; ni < 4; ni++) {
                long gcol = nbase + ni * 16 + lr;
                float v = acc[mi][ni][r];
                if (bias) v += bias[gcol];
                if (flags & FLAG_RELU) v = fmaxf(v, 0.f);
                long idx = czoff + grow * ldc + gcol;
                if (flags & FLAG_ACC) ((float*)Cv)[idx] += v;
                else if (flags & FLAG_H16) ((u16*)Cv)[idx] = f2h(v);
                else ((float*)Cv)[idx] = v;
            }
        }
    }
}

// ---------------- fused projection: QK (f32 out) + Hopfield-1 (fp16+relu), swizzled ----------------
__global__ __launch_bounds__(256) void fused_proj(
    const u16* __restrict__ A,
    const u16* __restrict__ WQT, const u16* __restrict__ WKT, const u16* __restrict__ XIT,
    float* __restrict__ Qb, float* __restrict__ Kb, u16* __restrict__ HH) {
    __shared__ __align__(16) u16 As[128 * 32];
    __shared__ __align__(16) u16 Bs[128 * 32];
    int cx = blockIdx.x;
    const u16* B; int ldc; long col0; int mode;
    if (cx < 6)       { B = WQT; ldc = 768;  col0 = (long)cx * 128;        mode = 0; }
    else if (cx < 12) { B = WKT; ldc = 768;  col0 = (long)(cx - 6) * 128;  mode = 1; }
    else              { B = XIT; ldc = 3072; col0 = (long)(cx - 12) * 128; mode = 2; }
    int t = threadIdx.x;
    int w = t >> 6, lane = t & 63;
    int lr = lane & 15, lg = lane >> 4;
    int wr = w >> 1, wc = w & 1;
    long row0 = (long)blockIdx.y * 128;

    f32x4 acc[4][4];
#pragma unroll
    for (int i = 0; i < 4; i++)
#pragma unroll
        for (int j = 0; j < 4; j++) acc[i][j] = (f32x4){0.f, 0.f, 0.f, 0.f};

    int c0 = w * 64 + lane;
    int r0s = c0 >> 2, k0s = (((c0 & 3) ^ ((r0s >> 1) & 3)) << 3);
    int c1 = 256 + w * 64 + lane;
    int r1s = c1 >> 2, k1s = (((c1 & 3) ^ ((r1s >> 1) & 3)) << 3);

    for (int kt = 0; kt < 768; kt += 32) {
        const u16* AB = A + row0 * 768 + kt;
        const u16* BB = B + col0 * 768 + kt;
        gld16(AB + (long)r0s * 768 + k0s, (char*)As + (w * 64) * 16);
        gld16(AB + (long)r1s * 768 + k1s, (char*)As + (256 + w * 64) * 16);
        gld16(BB + (long)r0s * 768 + k0s, (char*)Bs + (w * 64) * 16);
        gld16(BB + (long)r1s * 768 + k1s, (char*)Bs + (256 + w * 64) * 16);
        __syncthreads();
        f16x8 af[4], bf[4];
#pragma unroll
        for (int mi = 0; mi < 4; mi++) {
            int row = wr * 64 + mi * 16 + lr;
            af[mi] = *(const f16x8*)&As[row * 32 + ((lg ^ ((row >> 1) & 3)) << 3)];
        }
#pragma unroll
        for (int ni = 0; ni < 4; ni++) {
            int row = wc * 64 + ni * 16 + lr;
            bf[ni] = *(const f16x8*)&Bs[row * 32 + ((lg ^ ((row >> 1) & 3)) << 3)];
        }
#pragma unroll
        for (int mi = 0; mi < 4; mi++)
#pragma unroll
            for (int ni = 0; ni < 4; ni++)
                acc[mi][ni] = __builtin_amdgcn_mfma_f32_16x16x32_f16(af[mi], bf[ni], acc[mi][ni], 0, 0, 0);
        __syncthreads();
    }

    long mbase = row0 + wr * 64;
    long nbase = col0 + wc * 64;
#pragma unroll
    for (int mi = 0; mi < 4; mi++) {
#pragma unroll
        for (int r = 0; r < 4; r++) {
            long grow = mbase + mi * 16 + lg * 4 + r;
            if (grow >= NROWS) continue;
#pragma unroll
            for (int ni = 0; ni < 4; ni++) {
                long gcol = nbase + ni * 16 + lr;
                float v = acc[mi][ni][r];
                long idx = grow * ldc + gcol;
                if (mode == 0)      Qb[idx] = v;
                else if (mode == 1) Kb[idx] = v;
                else                HH[idx] = f2h(fmaxf(v, 0.f));
            }
        }
    }
}

// ---------------- fused accumulate GEMM: 6 split-K partials (swizzled) ----------------
__global__ __launch_bounds__(256) void gemm_h16_fused(
    const u16* __restrict__ G1, const u16* __restrict__ G2, const u16* __restrict__ HH,
    const u16* __restrict__ WQ, const u16* __restrict__ WK, const u16* __restrict__ XB,
    float* __restrict__ part) {
    __shared__ __align__(16) u16 As[128 * 32];
    __shared__ __align__(16) u16 Bs[128 * 32];
    int zz = blockIdx.z;
    const u16* A; const u16* B; int lda; int K0;
    if (zz == 0)      { A = G1; B = WQ; lda = 768;  K0 = 0; }
    else if (zz == 1) { A = G2; B = WK; lda = 768;  K0 = 0; }
    else              { A = HH; B = XB; lda = 3072; K0 = (zz - 2) * 768; }
    float* C = part + (long)zz * SZL;

    int t = threadIdx.x;
    int w = t >> 6, lane = t & 63;
    int lr = lane & 15, lg = lane >> 4;
    int wr = w >> 1, wc = w & 1;
    long row0 = (long)blockIdx.y * 128, col0 = (long)blockIdx.x * 128;

    f32x4 acc[4][4];
#pragma unroll
    for (int i = 0; i < 4; i++)
#pragma unroll
        for (int j = 0; j < 4; j++) acc[i][j] = (f32x4){0.f, 0.f, 0.f, 0.f};

    int c0 = w * 64 + lane;
    int r0s = c0 >> 2, k0s = (((c0 & 3) ^ ((r0s >> 1) & 3)) << 3);
    int c1 = 256 + w * 64 + lane;
    int r1s = c1 >> 2, k1s = (((c1 & 3) ^ ((r1s >> 1) & 3)) << 3);

    for (int kt = K0; kt < K0 + 768; kt += 32) {
        const u16* AB = A + row0 * lda + kt;
        const u16* BB = B + col0 * (long)lda + kt;
        gld16(AB + (long)r0s * lda + k0s, (char*)As + (w * 64) * 16);
        gld16(AB + (long)r1s * lda + k1s, (char*)As + (256 + w * 64) * 16);
        gld16(BB + (long)r0s * lda + k0s, (char*)Bs + (w * 64) * 16);
        gld16(BB + (long)r1s * lda + k1s, (char*)Bs + (256 + w * 64) * 16);
        __syncthreads();
        f16x8 af[4], bf[4];
#pragma unroll
        for (int mi = 0; mi < 4; mi++) {
            int row = wr * 64 + mi * 16 + lr;
            af[mi] = *(const f16x8*)&As[row * 32 + ((lg ^ ((row >> 1) & 3)) << 3)];
        }
#pragma unroll
        for (int ni = 0; ni < 4; ni++) {
            int row = wc * 64 + ni * 16 + lr;
            bf[ni] = *(const f16x8*)&Bs[row * 32 + ((lg ^ ((row >> 1) & 3)) << 3)];
        }
#pragma unroll
        for (int mi = 0; mi < 4; mi++)
#pragma unroll
            for (int ni = 0; ni < 4; ni++)
                acc[mi][ni] = __builtin_amdgcn_mfma_f32_16x16x32_f16(af[mi], bf[ni], acc[mi][ni], 0, 0, 0);
        __syncthreads();
    }

    long mbase = row0 + wr * 64;
    long nbase = col0 + wc * 64;
#pragma unroll
    for (int mi = 0; mi < 4; mi++) {
#pragma unroll
        for (int r = 0; r < 4; r++) {
            long grow = mbase + mi * 16 + lg * 4 + r;
            if (grow >= NROWS) continue;
#pragma unroll
            for (int ni = 0; ni < 4; ni++) {
                long gcol = nbase + ni * 16 + lr;
                C[grow * D + gcol] = acc[mi][ni][r];
            }
        }
    }
}

// ---------------- fused reduce + layernorm: h (+= 6 slabs) -> LN -> fp16 ----------------
__global__ __launch_bounds__(256) void ln_fuse_kernel(
    float* __restrict__ X, u16* __restrict__ Yh16, const float* __restrict__ part,
    const float* __restrict__ gamma, const float* __restrict__ beta,
    int compact, int doReduce, int writeBack) {
    int r = blockIdx.x;
    long xrow = compact ? ((long)(r / NPATCH) * NTOK + 1 + (r % NPATCH)) : (long)r;
    float* x = X + xrow * D;
    int t = threadIdx.x;
    float v[3];
    float s = 0.f, ss = 0.f;
#pragma unroll
    for (int i = 0; i < 3; i++) {
        int c = t + 256 * i;
        float val = x[c];
        if (doReduce) {
            long off = xrow * D + c;
            float p01 = part[off] + part[SZL + off];
            float p23 = part[2 * SZL + off] + part[3 * SZL + off];
            float p45 = part[4 * SZL + off] + part[5 * SZL + off];
            val += (p01 + p23) + p45;
            if (writeBack) x[c] = val;
        }
        v[i] = val;
        s += val;
        ss += val * val;
    }
    __shared__ float red[8];
    for (int off = 32; off; off >>= 1) {
        s += __shfl_down(s, off, 64);
        ss += __shfl_down(ss, off, 64);
    }
    int wid = t >> 6, lane = t & 63;
    if (lane == 0) { red[wid] = s; red[4 + wid] = ss; }
    __syncthreads();
    s = red[0] + red[1] + red[2] + red[3];
    ss = red[4] + red[5] + red[6] + red[7];
    float mu = s * (1.f / 768.f);
    float var = ss * (1.f / 768.f) - mu * mu;
    float inv = rsqrtf(var + 1e-5f);
#pragma unroll
    for (int i = 0; i < 3; i++) {
        int c = t + 256 * i;
        float yv = gamma[c] * (v[i] - mu) * inv + beta[c];
        Yh16[(long)r * D + c] = f2h(yv);
    }
}

// ---------------- parallel f32 attention softmax (stride-65 LDS, Pt only) ----------------
__global__ __launch_bounds__(256) void attn_p_kernel(const float* __restrict__ Q, const float* __restrict__ K,
                                                     float* __restrict__ Pt) {
    __shared__ float Ks[NTOK][65];
    int bh = blockIdx.x, mt = blockIdx.y;
    int b = bh / NH, h = bh % NH;
    int t = threadIdx.x;
    const float* Kb = K + (long)b * NTOK * D + h * HD;
    for (int i = t; i < NTOK * 16; i += 256) {
        int n = i >> 4, k4 = (i & 15) << 2;
        float4 v = *(const float4*)(Kb + (long)n * D + k4);
        Ks[n][k4] = v.x; Ks[n][k4 + 1] = v.y; Ks[n][k4 + 2] = v.z; Ks[n][k4 + 3] = v.w;
    }
    __syncthreads();
    int ql = t >> 4, l16 = t & 15;
    int m = mt * 16 + ql;
    int mr = m < NTOK ? m : NTOK - 1;
    const float* Qrow = Q + (long)(b * NTOK + mr) * D + h * HD;
    float q[64];
#pragma unroll
    for (int k = 0; k < 64; k += 4) {
        float4 v = *(const float4*)(Qrow + k);
        q[k] = v.x; q[k + 1] = v.y; q[k + 2] = v.z; q[k + 3] = v.w;
    }
    float s[13];
    float mx = -1e30f;
#pragma unroll
    for (int i = 0; i < 13; i++) {
        int n = i * 16 + l16;
        const float* kr = Ks[n < NTOK ? n : 0];
        float a0 = 0.f, a1 = 0.f, a2 = 0.f, a3 = 0.f;
#pragma unroll
        for (int k = 0; k < 64; k += 4) {
            a0 += kr[k] * q[k];
            a1 += kr[k + 1] * q[k + 1];
            a2 += kr[k + 2] * q[k + 2];
            a3 += kr[k + 3] * q[k + 3];
        }
        float sv = ((a0 + a1) + (a2 + a3)) * BETA_F;
        s[i] = (n < NTOK) ? sv : -1e30f;
        mx = fmaxf(mx, s[i]);
    }
    mx = fmaxf(mx, __shfl_xor(mx, 1, 64));
    mx = fmaxf(mx, __shfl_xor(mx, 2, 64));
    mx = fmaxf(mx, __shfl_xor(mx, 4, 64));
    mx = fmaxf(mx, __shfl_xor(mx, 8, 64));
    float ssum = 0.f;
#pragma unroll
    for (int i = 0; i < 13; i++) {
        float e = (s[i] > -1e29f) ? __expf(s[i] - mx) : 0.f;
        s[i] = e;
        ssum += e;
    }
    ssum += __shfl_xor(ssum, 1, 64);
    ssum += __shfl_xor(ssum, 2, 64);
    ssum += __shfl_xor(ssum, 4, 64);
    ssum += __shfl_xor(ssum, 8, 64);
    float inv = 1.f / ssum;
    if (m < NTOK) {
        float* PtB = Pt + (long)bh * PBH;
#pragma unroll
        for (int i = 0; i < 13; i++) {
            int n = i * 16 + l16;
            if (n < NTOK) PtB[(long)m * PLD + n] = s[i] * inv;
        }
    }
}

// ---------------- attention grads: G1 (A normal) + G2 (A transposed) in one launch ----------------
__global__ __launch_bounds__(256) void attn_g_kernel(
    const float* __restrict__ Pt, const float* __restrict__ Qb, const float* __restrict__ Kb,
    u16* __restrict__ G1, u16* __restrict__ G2) {
    __shared__ float As[16][68];
    __shared__ float Bs[16][68];
    int z = blockIdx.z;
    int which = z / 192, bh = z - which * 192;
    int b = bh / NH, h = bh % NH;
    const float* A = Pt + (long)bh * PBH;
    const float* B = (which ? Qb : Kb) + (long)b * NTOK * D + h * HD;
    u16* G = which ? G2 : G1;

    int t = threadIdx.x;
    int tx = t & 15, ty = t >> 4;
    int row0 = blockIdx.y * 64;

    float acc[4][4] = {};

    for (int kt = 0; kt < NTOK; kt += 16) {
        if (which == 0) {
            int r = t >> 2, c4 = (t & 3) << 2;
            int gr = row0 + r, gk = kt + c4;
            float4 v = make_float4(0.f, 0.f, 0.f, 0.f);
            if (gr < NTOK) {
                if (gk + 3 < NTOK) {
                    v = *(const float4*)(A + (long)gr * PLD + gk);
                } else {
                    float x0 = (gk < NTOK) ? A[(long)gr * PLD + gk] : 0.f;
                    float x1 = (gk + 1 < NTOK) ? A[(long)gr * PLD + gk + 1] : 0.f;
                    float x2 = (gk + 2 < NTOK) ? A[(long)gr * PLD + gk + 2] : 0.f;
                    float x3 = (gk + 3 < NTOK) ? A[(long)gr * PLD + gk + 3] : 0.f;
                    v = make_float4(x0, x1, x2, x3);
                }
            }
            As[c4 + 0][r] = v.x; As[c4 + 1][r] = v.y; As[c4 + 2][r] = v.z; As[c4 + 3][r] = v.w;
        } else {
            int rr = t >> 4, c4 = (t & 15) << 2;
            int gk = kt + rr, gc = row0 + c4;
            float4 v = make_float4(0.f, 0.f, 0.f, 0.f);
            if (gk < NTOK && gc + 3 < PLD) v = *(const float4*)(A + (long)gk * PLD + gc);
            As[rr][c4 + 0] = v.x; As[rr][c4 + 1] = v.y; As[rr][c4 + 2] = v.z; As[rr][c4 + 3] = v.w;
        }
        {
            int r = t >> 4, c4 = (t & 15) << 2;
            int gk = kt + r;
            float4 v = make_float4(0.f, 0.f, 0.f, 0.f);
            if (gk < NTOK) v = *(const float4*)(B + (long)gk * D + c4);
            Bs[r][c4 + 0] = v.x; Bs[r][c4 + 1] = v.y; Bs[r][c4 + 2] = v.z; Bs[r][c4 + 3] = v.w;
        }
        __syncthreads();
#pragma unroll
        for (int kk = 0; kk < 16; kk++) {
            float av[4], bv[4];
#pragma unroll
            for (int i = 0; i < 4; i++) av[i] = As[kk][ty * 4 + i];
#pragma unroll
            for (int j = 0; j < 4; j++) bv[j] = Bs[kk][tx * 4 + j];
#pragma unroll
            for (int i = 0; i < 4; i++)
#pragma unroll
                for (int j = 0; j < 4; j++) acc[i][j] += av[i] * bv[j];
        }
        __syncthreads();
    }
#pragma unroll
    for (int i = 0; i < 4; i++) {
        int gr = row0 + ty * 4 + i;
        if (gr >= NTOK) continue;
#pragma unroll
        for (int j = 0; j < 4; j++) {
            int gc = tx * 4 + j;
            long idx = ((long)(b * NTOK + gr)) * D + h * HD + gc;
            G[idx] = f2h(acc[i][j]);
        }
    }
}

// ================= setup pieces =================

__global__ __launch_bounds__(256) void patchify_kernel(const float* __restrict__ x, float* __restrict__ tok) {
    int idx = blockIdx.x * 256 + threadIdx.x;
    const int total = NB * NPATCH * D;
    if (idx >= total) return;
    int d = idx % D;
    int p = (idx / D) % NPATCH;
    int b = idx / (D * NPATCH);
    int c = d >> 8;
    int pi = (d >> 4) & 15;
    int pj = d & 15;
    int hp = p / 14, wp = p % 14;
    int row = hp * 16 + pi, col = wp * 16 + pj;
    tok[idx] = x[(((long)b * 3 + c) * 224 + row) * 224 + col];
}

__global__ __launch_bounds__(256) void cls_pos_kernel(float* __restrict__ h, const float* __restrict__ cls,
                                                      const float* __restrict__ pos) {
    int idx = blockIdx.x * 256 + threadIdx.x;
    const int total = NB * NTOK * D;
    if (idx >= total) return;
    int d = idx % D;
    int n = (idx / D) % NTOK;
    float v = pos[n * D + d];
    if (n == 0) h[idx] = cls[d] + v;
    else        h[idx] = h[idx] + v;
}

__global__ __launch_bounds__(256) void wcat_kernel(const float* __restrict__ w, float* __restrict__ Wm) {
    int idx = blockIdx.x * 256 + threadIdx.x;
    const int total = NH * D * HD;
    if (idx >= total) return;
    int k = idx & 63;
    int d = (idx >> 6) % D;
    int hh = idx / (D * HD);
    Wm[d * D + hh * HD + k] = w[idx];
}

// ---------------- f32 GEMM (patch embed only) ----------------
__global__ __launch_bounds__(256) void gemm_f32(
    const float* __restrict__ A, const float* __restrict__ B, float* __restrict__ C,
    const float* __restrict__ bias,
    int M, int N, int K, int lda, int ldb, int ldc,
    long sA1, long sC1) {
    int z = blockIdx.z;
    A += (long)z * sA1;
    long coff = (long)z * sC1;

    __shared__ float As[16][68];
    __shared__ float Bs[16][68];

    int t = threadIdx.x;
    int tx = t & 15, ty = t >> 4;
    int row0 = blockIdx.y * 64, col0 = blockIdx.x * 64;

    float acc[4][4] = {};

    for (int kt = 0; kt < K; kt += 16) {
        {
            int r = t >> 2;
            int c4 = (t & 3) << 2;
            int gr = row0 + r;
            int gk = kt + c4;
            float4 v = make_float4(0.f, 0.f, 0.f, 0.f);
            if (gr < M && gk + 3 < K) v = *(const float4*)(A + (long)gr * lda + gk);
            As[c4 + 0][r] = v.x; As[c4 + 1][r] = v.y; As[c4 + 2][r] = v.z; As[c4 + 3][r] = v.w;
        }
        {
            int r = t >> 4;
            int c4 = (t & 15) << 2;
            int gk = kt + r;
            int gc = col0 + c4;
            float4 v = make_float4(0.f, 0.f, 0.f, 0.f);
            if (gk < K && gc + 3 < N) v = *(const float4*)(B + (long)gk * ldb + gc);
            Bs[r][c4 + 0] = v.x; Bs[r][c4 + 1] = v.y; Bs[r][c4 + 2] = v.z; Bs[r][c4 + 3] = v.w;
        }
        __syncthreads();
#pragma unroll
        for (int kk = 0; kk < 16; kk++) {
            float av[4], bv[4];
#pragma unroll
            for (int i = 0; i < 4; i++) av[i] = As[kk][ty * 4 + i];
#pragma unroll
            for (int j = 0; j < 4; j++) bv[j] = Bs[kk][tx * 4 + j];
#pragma unroll
            for (int i = 0; i < 4; i++)
#pragma unroll
                for (int j = 0; j < 4; j++) acc[i][j] += av[i] * bv[j];
        }
        __syncthreads();
    }
#pragma unroll
    for (int i = 0; i < 4; i++) {
        int gr = row0 + ty * 4 + i;
        if (gr >= M) continue;
#pragma unroll
        for (int j = 0; j < 4; j++) {
            int gc = col0 + tx * 4 + j;
            if (gc >= N) continue;
            float v = acc[i][j];
            if (bias) v += bias[gc];
            C[coff + (long)gr * ldc + gc] = v;
        }
    }
}

// fp16 preps
__global__ __launch_bounds__(256) void prep_transpose_h(const float* __restrict__ src,
                                                        u16* __restrict__ dst, int R, int C) {
    int idx = blockIdx.x * 256 + threadIdx.x;
    if (idx >= R * C) return;
    int r = idx % R, c = idx / R;
    dst[idx] = f2h(src[(long)r * C + c]);
}
__global__ __launch_bounds__(256) void prep_convert_h(const float* __restrict__ src,
                                                      u16* __restrict__ dst, int n) {
    int idx = blockIdx.x * 256 + threadIdx.x;
    if (idx >= n) return;
    dst[idx] = f2h(src[idx]);
}

extern "C" void kernel_launch(void* const* d_in, const int* in_sizes, int n_in,
                              void* d_out, int out_size, void* d_ws, size_t ws_size,
                              hipStream_t stream) {
    const float* x        = (const float*)d_in[0];
    const float* patch_w  = (const float*)d_in[1];
    const float* patch_b  = (const float*)d_in[2];
    const float* cls_tok  = (const float*)d_in[3];
    const float* pos_emb  = (const float*)d_in[4];
    const float* ln_gamma = (const float*)d_in[5];
    const float* ln_beta  = (const float*)d_in[6];
    const float* wq       = (const float*)d_in[7];
    const float* wk       = (const float*)d_in[8];
    const float* xi       = (const float*)d_in[9];
    const float* out_gamma= (const float*)d_in[10];
    const float* out_beta = (const float*)d_in[11];
    const float* out_w    = (const float*)d_in[12];
    const float* out_b    = (const float*)d_in[13];
    float* out = (float*)d_out;

    float* ws = (float*)d_ws;
    const long SZ = SZL;
    const long AR = (long)AROWS * D;
    float* h  = ws;
    float* Qb = ws + SZ;
    float* Kb = ws + 2 * SZ;
    u16* gh16    = (u16*)(ws + 3 * SZ);
    u16* WmQTh16 = gh16 + AR;
    u16* WmKTh16 = WmQTh16 + DD;
    u16* WmQh16  = WmKTh16 + DD;
    u16* WmKh16  = WmQh16 + DD;
    u16* xiTh16  = WmKh16 + DD;
    u16* xibh16  = xiTh16 + DH;
    u16* G1h16   = xibh16 + DH;
    u16* G2h16   = G1h16 + AR;
    u16* HH16    = G2h16 + AR;
    u16* owTh16  = HH16 + (long)AROWS * HOP;
    // shared region: part (6*SZ f32) | Pt (192*PBH f32) | tok + WmQ/WmK (setup)
    float* R1  = (float*)(owTh16 + DD);
    float* Pt  = R1;
    float* part = R1;
    float* tok = R1;
    float* WmQ = R1 + SZ;
    float* WmK = WmQ + DD;

    // ---- setup ----
    patchify_kernel<<<(NB * NPATCH * D + 255) / 256, 256, 0, stream>>>(x, tok);
    wcat_kernel<<<(NH * D * HD + 255) / 256, 256, 0, stream>>>(wq, WmQ);
    wcat_kernel<<<(NH * D * HD + 255) / 256, 256, 0, stream>>>(wk, WmK);
    prep_transpose_h<<<(DD + 255) / 256, 256, 0, stream>>>(WmQ, WmQTh16, 768, 768);
    prep_transpose_h<<<(DD + 255) / 256, 256, 0, stream>>>(WmK, WmKTh16, 768, 768);
    prep_convert_h<<<(DD + 255) / 256, 256, 0, stream>>>(WmQ, WmQh16, DD);
    prep_convert_h<<<(DD + 255) / 256, 256, 0, stream>>>(WmK, WmKh16, DD);
    prep_transpose_h<<<(DH + 255) / 256, 256, 0, stream>>>(xi, xiTh16, 768, HOP);
    prep_convert_h<<<(DH + 255) / 256, 256, 0, stream>>>(xi, xibh16, DH);
    prep_transpose_h<<<(DD + 255) / 256, 256, 0, stream>>>(out_w, owTh16, 768, 768);
    // patch embed: f32 (h0 seed stays f32 — sensitivity firewall)
    gemm_f32<<<dim3(12, 4, NB), 256, 0, stream>>>(
        tok, patch_w, h + D, patch_b, NPATCH, D, D, D, D, D,
        (long)NPATCH * D, (long)NTOK * D);
    cls_pos_kernel<<<(NB * NTOK * D + 255) / 256, 256, 0, stream>>>(h, cls_tok, pos_emb);

    for (int step = 0; step < TSTEPS; step++) {
        ln_fuse_kernel<<<NROWS, 256, 0, stream>>>(h, gh16, part, ln_gamma, ln_beta,
                                                  0, step > 0 ? 1 : 0, 1);
        fused_proj<<<dim3(36, 25), 256, 0, stream>>>(gh16, WmQTh16, WmKTh16, xiTh16, Qb, Kb, HH16);
        attn_p_kernel<<<dim3(192, 13), 256, 0, stream>>>(Qb, Kb, Pt);
        attn_g_kernel<<<dim3(1, 4, 384), 256, 0, stream>>>(Pt, Qb, Kb, G1h16, G2h16);
        gemm_h16_fused<<<dim3(6, 25, 6), 256, 0, stream>>>(
            G1h16, G2h16, HH16, WmQh16, WmKh16, xibh16, part);
    }

    // ---- final: reduce + LN (compact) -> fp16, then out projection (fp16 MFMA) ----
    ln_fuse_kernel<<<NPROWS, 256, 0, stream>>>(h, gh16, part, out_gamma, out_beta, 1, 1, 0);
    gemm_h16<<<dim3(6, 25, 1), 256, 0, stream>>>(
        gh16, owTh16, out, out_b, NPROWS, D, D, D, D, D, 0, 0, 0, 0);
}

// Round 14
// 1366.189 us; speedup vs baseline: 5.1792x; 1.0200x over previous
//
#include <hip/hip_runtime.h>

#define NB 16
#define NTOK 197
#define NPATCH 196
#define D 768
#define NH 12
#define HD 64
#define HOP 3072
#define TSTEPS 6
#define BETA_F 0.125f
#define PLD 208                 // Pt leading dim (fp16)
#define PBH (NTOK * PLD)        // 40976
#define NROWS (NB * NTOK)       // 3152
#define NPROWS (NB * NPATCH)    // 3136
#define AROWS 3200              // padded rows for MFMA A-side staging
#define DD (768 * 768)
#define DH (768 * 3072)
#define SZL ((long)NROWS * D)   // 2,420,736

typedef unsigned short u16;
typedef __attribute__((ext_vector_type(8))) _Float16 f16x8;
typedef __attribute__((ext_vector_type(4))) float f32x4;

#define FLAG_ACC 1
#define FLAG_RELU 2
#define FLAG_H16 4

__device__ __forceinline__ u16 f2h(float f) {
    union { _Float16 h; u16 u; } cv;
    cv.h = (_Float16)f;
    return cv.u;
}
__device__ __forceinline__ float h2f(u16 v) {
    union { _Float16 h; u16 u; } cv;
    cv.u = v;
    return (float)cv.h;
}

__device__ __forceinline__ void gld16(const void* g, void* l) {
    __builtin_amdgcn_global_load_lds((const __attribute__((address_space(1))) void*)g,
                                     (__attribute__((address_space(3))) void*)l, 16, 0, 0);
}

// Swizzle note (T2 adapted for global_load_lds, rule #21):
// LDS slot (r, js) holds global 16B-chunk (r, js ^ ((r>>1)&3)); read applies the same XOR.

// ---------------- single-fp16 MFMA GEMM (out-projection) ----------------
__global__ __launch_bounds__(256) void gemm_h16(
    const u16* __restrict__ A, const u16* __restrict__ B,
    void* __restrict__ Cv, const float* __restrict__ bias,
    int M, int N, int K, int lda, int ldbt, int ldc, int flags,
    long sAz, long sBz, long sCz) {
    __shared__ __align__(16) u16 As[128 * 32];
    __shared__ __align__(16) u16 Bs[128 * 32];
    int zz = blockIdx.z;
    A += (long)zz * sAz;
    B += (long)zz * sBz;
    long czoff = (long)zz * sCz;
    int t = threadIdx.x;
    int w = t >> 6, lane = t & 63;
    int lr = lane & 15, lg = lane >> 4;
    int wr = w >> 1, wc = w & 1;
    long row0 = (long)blockIdx.y * 128, col0 = (long)blockIdx.x * 128;

    f32x4 acc[4][4];
#pragma unroll
    for (int i = 0; i < 4; i++)
#pragma unroll
        for (int j = 0; j < 4; j++) acc[i][j] = (f32x4){0.f, 0.f, 0.f, 0.f};

    int c0 = w * 64 + lane;
    int r0s = c0 >> 2, k0s = (((c0 & 3) ^ ((r0s >> 1) & 3)) << 3);
    int c1 = 256 + w * 64 + lane;
    int r1s = c1 >> 2, k1s = (((c1 & 3) ^ ((r1s >> 1) & 3)) << 3);

    for (int kt = 0; kt < K; kt += 32) {
        const u16* AB = A + row0 * lda + kt;
        const u16* BB = B + col0 * ldbt + kt;
        gld16(AB + (long)r0s * lda + k0s, (char*)As + (w * 64) * 16);
        gld16(AB + (long)r1s * lda + k1s, (char*)As + (256 + w * 64) * 16);
        gld16(BB + (long)r0s * ldbt + k0s, (char*)Bs + (w * 64) * 16);
        gld16(BB + (long)r1s * ldbt + k1s, (char*)Bs + (256 + w * 64) * 16);
        __syncthreads();
        f16x8 af[4], bf[4];
#pragma unroll
        for (int mi = 0; mi < 4; mi++) {
            int row = wr * 64 + mi * 16 + lr;
            af[mi] = *(const f16x8*)&As[row * 32 + ((lg ^ ((row >> 1) & 3)) << 3)];
        }
#pragma unroll
        for (int ni = 0; ni < 4; ni++) {
            int row = wc * 64 + ni * 16 + lr;
            bf[ni] = *(const f16x8*)&Bs[row * 32 + ((lg ^ ((row >> 1) & 3)) << 3)];
        }
#pragma unroll
        for (int mi = 0; mi < 4; mi++)
#pragma unroll
            for (int ni = 0; ni < 4; ni++)
                acc[mi][ni] = __builtin_amdgcn_mfma_f32_16x16x32_f16(af[mi], bf[ni], acc[mi][ni], 0, 0, 0);
        __syncthreads();
    }

    long mbase = row0 + wr * 64;
    long nbase = col0 + wc * 64;
#pragma unroll
    for (int mi = 0; mi < 4; mi++) {
#pragma unroll
        for (int r = 0; r < 4; r++) {
            long grow = mbase + mi * 16 + lg * 4 + r;
            if (grow >= M) continue;
#pragma unroll
            for (int ni = 0; ni < 4; ni++) {
                long gcol = nbase + ni * 16 + lr;
                float v = acc[mi][ni][r];
                if (bias) v += bias[gcol];
                if (flags & FLAG_RELU) v = fmaxf(v, 0.f);
                long idx = czoff + grow * ldc + gcol;
                if (flags & FLAG_ACC) ((float*)Cv)[idx] += v;
                else if (flags & FLAG_H16) ((u16*)Cv)[idx] = f2h(v);
                else ((float*)Cv)[idx] = v;
            }
        }
    }
}

// ---------------- fused projection: QK (f32 out) + Hopfield-1 (fp16+relu) ----------------
__global__ __launch_bounds__(256) void fused_proj(
    const u16* __restrict__ A,
    const u16* __restrict__ WQT, const u16* __restrict__ WKT, const u16* __restrict__ XIT,
    float* __restrict__ Qb, float* __restrict__ Kb, u16* __restrict__ HH) {
    __shared__ __align__(16) u16 As[128 * 32];
    __shared__ __align__(16) u16 Bs[128 * 32];
    int cx = blockIdx.x;
    const u16* B; int ldc; long col0; int mode;
    if (cx < 6)       { B = WQT; ldc = 768;  col0 = (long)cx * 128;        mode = 0; }
    else if (cx < 12) { B = WKT; ldc = 768;  col0 = (long)(cx - 6) * 128;  mode = 1; }
    else              { B = XIT; ldc = 3072; col0 = (long)(cx - 12) * 128; mode = 2; }
    int t = threadIdx.x;
    int w = t >> 6, lane = t & 63;
    int lr = lane & 15, lg = lane >> 4;
    int wr = w >> 1, wc = w & 1;
    long row0 = (long)blockIdx.y * 128;

    f32x4 acc[4][4];
#pragma unroll
    for (int i = 0; i < 4; i++)
#pragma unroll
        for (int j = 0; j < 4; j++) acc[i][j] = (f32x4){0.f, 0.f, 0.f, 0.f};

    int c0 = w * 64 + lane;
    int r0s = c0 >> 2, k0s = (((c0 & 3) ^ ((r0s >> 1) & 3)) << 3);
    int c1 = 256 + w * 64 + lane;
    int r1s = c1 >> 2, k1s = (((c1 & 3) ^ ((r1s >> 1) & 3)) << 3);

    for (int kt = 0; kt < 768; kt += 32) {
        const u16* AB = A + row0 * 768 + kt;
        const u16* BB = B + col0 * 768 + kt;
        gld16(AB + (long)r0s * 768 + k0s, (char*)As + (w * 64) * 16);
        gld16(AB + (long)r1s * 768 + k1s, (char*)As + (256 + w * 64) * 16);
        gld16(BB + (long)r0s * 768 + k0s, (char*)Bs + (w * 64) * 16);
        gld16(BB + (long)r1s * 768 + k1s, (char*)Bs + (256 + w * 64) * 16);
        __syncthreads();
        f16x8 af[4], bf[4];
#pragma unroll
        for (int mi = 0; mi < 4; mi++) {
            int row = wr * 64 + mi * 16 + lr;
            af[mi] = *(const f16x8*)&As[row * 32 + ((lg ^ ((row >> 1) & 3)) << 3)];
        }
#pragma unroll
        for (int ni = 0; ni < 4; ni++) {
            int row = wc * 64 + ni * 16 + lr;
            bf[ni] = *(const f16x8*)&Bs[row * 32 + ((lg ^ ((row >> 1) & 3)) << 3)];
        }
#pragma unroll
        for (int mi = 0; mi < 4; mi++)
#pragma unroll
            for (int ni = 0; ni < 4; ni++)
                acc[mi][ni] = __builtin_amdgcn_mfma_f32_16x16x32_f16(af[mi], bf[ni], acc[mi][ni], 0, 0, 0);
        __syncthreads();
    }

    long mbase = row0 + wr * 64;
    long nbase = col0 + wc * 64;
#pragma unroll
    for (int mi = 0; mi < 4; mi++) {
#pragma unroll
        for (int r = 0; r < 4; r++) {
            long grow = mbase + mi * 16 + lg * 4 + r;
            if (grow >= NROWS) continue;
#pragma unroll
            for (int ni = 0; ni < 4; ni++) {
                long gcol = nbase + ni * 16 + lr;
                float v = acc[mi][ni][r];
                long idx = grow * ldc + gcol;
                if (mode == 0)      Qb[idx] = v;
                else if (mode == 1) Kb[idx] = v;
                else                HH[idx] = f2h(fmaxf(v, 0.f));
            }
        }
    }
}

// ---------------- fused accumulate GEMM: 6 split-K partials -> fp16 slabs ----------------
__global__ __launch_bounds__(256) void gemm_h16_fused(
    const u16* __restrict__ G1, const u16* __restrict__ G2, const u16* __restrict__ HH,
    const u16* __restrict__ WQ, const u16* __restrict__ WK, const u16* __restrict__ XB,
    u16* __restrict__ part) {
    __shared__ __align__(16) u16 As[128 * 32];
    __shared__ __align__(16) u16 Bs[128 * 32];
    int zz = blockIdx.z;
    const u16* A; const u16* B; int lda; int K0;
    if (zz == 0)      { A = G1; B = WQ; lda = 768;  K0 = 0; }
    else if (zz == 1) { A = G2; B = WK; lda = 768;  K0 = 0; }
    else              { A = HH; B = XB; lda = 3072; K0 = (zz - 2) * 768; }
    u16* C = part + (long)zz * SZL;

    int t = threadIdx.x;
    int w = t >> 6, lane = t & 63;
    int lr = lane & 15, lg = lane >> 4;
    int wr = w >> 1, wc = w & 1;
    long row0 = (long)blockIdx.y * 128, col0 = (long)blockIdx.x * 128;

    f32x4 acc[4][4];
#pragma unroll
    for (int i = 0; i < 4; i++)
#pragma unroll
        for (int j = 0; j < 4; j++) acc[i][j] = (f32x4){0.f, 0.f, 0.f, 0.f};

    int c0 = w * 64 + lane;
    int r0s = c0 >> 2, k0s = (((c0 & 3) ^ ((r0s >> 1) & 3)) << 3);
    int c1 = 256 + w * 64 + lane;
    int r1s = c1 >> 2, k1s = (((c1 & 3) ^ ((r1s >> 1) & 3)) << 3);

    for (int kt = K0; kt < K0 + 768; kt += 32) {
        const u16* AB = A + row0 * lda + kt;
        const u16* BB = B + col0 * (long)lda + kt;
        gld16(AB + (long)r0s * lda + k0s, (char*)As + (w * 64) * 16);
        gld16(AB + (long)r1s * lda + k1s, (char*)As + (256 + w * 64) * 16);
        gld16(BB + (long)r0s * lda + k0s, (char*)Bs + (w * 64) * 16);
        gld16(BB + (long)r1s * lda + k1s, (char*)Bs + (256 + w * 64) * 16);
        __syncthreads();
        f16x8 af[4], bf[4];
#pragma unroll
        for (int mi = 0; mi < 4; mi++) {
            int row = wr * 64 + mi * 16 + lr;
            af[mi] = *(const f16x8*)&As[row * 32 + ((lg ^ ((row >> 1) & 3)) << 3)];
        }
#pragma unroll
        for (int ni = 0; ni < 4; ni++) {
            int row = wc * 64 + ni * 16 + lr;
            bf[ni] = *(const f16x8*)&Bs[row * 32 + ((lg ^ ((row >> 1) & 3)) << 3)];
        }
#pragma unroll
        for (int mi = 0; mi < 4; mi++)
#pragma unroll
            for (int ni = 0; ni < 4; ni++)
                acc[mi][ni] = __builtin_amdgcn_mfma_f32_16x16x32_f16(af[mi], bf[ni], acc[mi][ni], 0, 0, 0);
        __syncthreads();
    }

    long mbase = row0 + wr * 64;
    long nbase = col0 + wc * 64;
#pragma unroll
    for (int mi = 0; mi < 4; mi++) {
#pragma unroll
        for (int r = 0; r < 4; r++) {
            long grow = mbase + mi * 16 + lg * 4 + r;
            if (grow >= NROWS) continue;
#pragma unroll
            for (int ni = 0; ni < 4; ni++) {
                long gcol = nbase + ni * 16 + lr;
                C[grow * D + gcol] = f2h(acc[mi][ni][r]);
            }
        }
    }
}

// ---------------- fused reduce + layernorm: h (+= 6 fp16 slabs) -> LN -> fp16 ----------------
__global__ __launch_bounds__(256) void ln_fuse_kernel(
    float* __restrict__ X, u16* __restrict__ Yh16, const u16* __restrict__ part,
    const float* __restrict__ gamma, const float* __restrict__ beta,
    int compact, int doReduce, int writeBack) {
    int r = blockIdx.x;
    long xrow = compact ? ((long)(r / NPATCH) * NTOK + 1 + (r % NPATCH)) : (long)r;
    float* x = X + xrow * D;
    int t = threadIdx.x;
    float v[3];
    float s = 0.f, ss = 0.f;
#pragma unroll
    for (int i = 0; i < 3; i++) {
        int c = t + 256 * i;
        float val = x[c];
        if (doReduce) {
            long off = xrow * D + c;
            float p01 = h2f(part[off]) + h2f(part[SZL + off]);
            float p23 = h2f(part[2 * SZL + off]) + h2f(part[3 * SZL + off]);
            float p45 = h2f(part[4 * SZL + off]) + h2f(part[5 * SZL + off]);
            val += (p01 + p23) + p45;
            if (writeBack) x[c] = val;
        }
        v[i] = val;
        s += val;
        ss += val * val;
    }
    __shared__ float red[8];
    for (int off = 32; off; off >>= 1) {
        s += __shfl_down(s, off, 64);
        ss += __shfl_down(ss, off, 64);
    }
    int wid = t >> 6, lane = t & 63;
    if (lane == 0) { red[wid] = s; red[4 + wid] = ss; }
    __syncthreads();
    s = red[0] + red[1] + red[2] + red[3];
    ss = red[4] + red[5] + red[6] + red[7];
    float mu = s * (1.f / 768.f);
    float var = ss * (1.f / 768.f) - mu * mu;
    float inv = rsqrtf(var + 1e-5f);
#pragma unroll
    for (int i = 0; i < 3; i++) {
        int c = t + 256 * i;
        float yv = gamma[c] * (v[i] - mu) * inv + beta[c];
        Yh16[(long)r * D + c] = f2h(yv);
    }
}

// ---------------- parallel f32 attention softmax -> fp16 Pt (pads zeroed) ----------------
__global__ __launch_bounds__(256) void attn_p_kernel(const float* __restrict__ Q, const float* __restrict__ K,
                                                     u16* __restrict__ Pt) {
    __shared__ float Ks[NTOK][65];
    int bh = blockIdx.x, mt = blockIdx.y;
    int b = bh / NH, h = bh % NH;
    int t = threadIdx.x;
    const float* Kb = K + (long)b * NTOK * D + h * HD;
    for (int i = t; i < NTOK * 16; i += 256) {
        int n = i >> 4, k4 = (i & 15) << 2;
        float4 v = *(const float4*)(Kb + (long)n * D + k4);
        Ks[n][k4] = v.x; Ks[n][k4 + 1] = v.y; Ks[n][k4 + 2] = v.z; Ks[n][k4 + 3] = v.w;
    }
    __syncthreads();
    int ql = t >> 4, l16 = t & 15;
    int m = mt * 16 + ql;
    int mr = m < NTOK ? m : NTOK - 1;
    const float* Qrow = Q + (long)(b * NTOK + mr) * D + h * HD;
    float q[64];
#pragma unroll
    for (int k = 0; k < 64; k += 4) {
        float4 v = *(const float4*)(Qrow + k);
        q[k] = v.x; q[k + 1] = v.y; q[k + 2] = v.z; q[k + 3] = v.w;
    }
    float s[13];
    float mx = -1e30f;
#pragma unroll
    for (int i = 0; i < 13; i++) {
        int n = i * 16 + l16;
        const float* kr = Ks[n < NTOK ? n : 0];
        float a0 = 0.f, a1 = 0.f, a2 = 0.f, a3 = 0.f;
#pragma unroll
        for (int k = 0; k < 64; k += 4) {
            a0 += kr[k] * q[k];
            a1 += kr[k + 1] * q[k + 1];
            a2 += kr[k + 2] * q[k + 2];
            a3 += kr[k + 3] * q[k + 3];
        }
        float sv = ((a0 + a1) + (a2 + a3)) * BETA_F;
        s[i] = (n < NTOK) ? sv : -1e30f;
        mx = fmaxf(mx, s[i]);
    }
    mx = fmaxf(mx, __shfl_xor(mx, 1, 64));
    mx = fmaxf(mx, __shfl_xor(mx, 2, 64));
    mx = fmaxf(mx, __shfl_xor(mx, 4, 64));
    mx = fmaxf(mx, __shfl_xor(mx, 8, 64));
    float ssum = 0.f;
#pragma unroll
    for (int i = 0; i < 13; i++) {
        float e = (s[i] > -1e29f) ? __expf(s[i] - mx) : 0.f;
        s[i] = e;
        ssum += e;
    }
    ssum += __shfl_xor(ssum, 1, 64);
    ssum += __shfl_xor(ssum, 2, 64);
    ssum += __shfl_xor(ssum, 4, 64);
    ssum += __shfl_xor(ssum, 8, 64);
    float inv = 1.f / ssum;
    if (m < NTOK) {
        u16* PtB = Pt + (long)bh * PBH;
#pragma unroll
        for (int i = 0; i < 13; i++) {
            int n = i * 16 + l16;
            PtB[(long)m * PLD + n] = (n < NTOK) ? f2h(s[i] * inv) : (u16)0;
        }
    }
}

// ---------------- attention grads: G1 (A normal) + G2 (A transposed), fp16 Pt in ----------------
__global__ __launch_bounds__(256) void attn_g_kernel(
    const u16* __restrict__ Pt, const float* __restrict__ Qb, const float* __restrict__ Kb,
    u16* __restrict__ G1, u16* __restrict__ G2) {
    __shared__ float As[16][68];
    __shared__ float Bs[16][68];
    int z = blockIdx.z;
    int which = z / 192, bh = z - which * 192;
    int b = bh / NH, h = bh % NH;
    const u16* A = Pt + (long)bh * PBH;
    const float* B = (which ? Qb : Kb) + (long)b * NTOK * D + h * HD;
    u16* G = which ? G2 : G1;

    int t = threadIdx.x;
    int tx = t & 15, ty = t >> 4;
    int row0 = blockIdx.y * 64;

    float acc[4][4] = {};

    for (int kt = 0; kt < NTOK; kt += 16) {
        if (which == 0) {
            // As[k][r] = Pt[row0+r][kt+k]  (pad cols are zero in Pt)
            int r = t >> 2, c4 = (t & 3) << 2;
            int gr = row0 + r, gk = kt + c4;
            float4 v = make_float4(0.f, 0.f, 0.f, 0.f);
            if (gr < NTOK) {
                ushort4 u = *(const ushort4*)(A + (long)gr * PLD + gk);
                v = make_float4(h2f(u.x), h2f(u.y), h2f(u.z), h2f(u.w));
            }
            As[c4 + 0][r] = v.x; As[c4 + 1][r] = v.y; As[c4 + 2][r] = v.z; As[c4 + 3][r] = v.w;
        } else {
            // As[k][r] = Pt[kt+k][row0+r]
            int rr = t >> 4, c4 = (t & 15) << 2;
            int gk = kt + rr, gc = row0 + c4;
            float4 v = make_float4(0.f, 0.f, 0.f, 0.f);
            if (gk < NTOK && gc + 3 < PLD) {
                ushort4 u = *(const ushort4*)(A + (long)gk * PLD + gc);
                v = make_float4(h2f(u.x), h2f(u.y), h2f(u.z), h2f(u.w));
            }
            As[rr][c4 + 0] = v.x; As[rr][c4 + 1] = v.y; As[rr][c4 + 2] = v.z; As[rr][c4 + 3] = v.w;
        }
        {
            int r = t >> 4, c4 = (t & 15) << 2;
            int gk = kt + r;
            float4 v = make_float4(0.f, 0.f, 0.f, 0.f);
            if (gk < NTOK) v = *(const float4*)(B + (long)gk * D + c4);
            Bs[r][c4 + 0] = v.x; Bs[r][c4 + 1] = v.y; Bs[r][c4 + 2] = v.z; Bs[r][c4 + 3] = v.w;
        }
        __syncthreads();
#pragma unroll
        for (int kk = 0; kk < 16; kk++) {
            float av[4], bv[4];
#pragma unroll
            for (int i = 0; i < 4; i++) av[i] = As[kk][ty * 4 + i];
#pragma unroll
            for (int j = 0; j < 4; j++) bv[j] = Bs[kk][tx * 4 + j];
#pragma unroll
            for (int i = 0; i < 4; i++)
#pragma unroll
                for (int j = 0; j < 4; j++) acc[i][j] += av[i] * bv[j];
        }
        __syncthreads();
    }
#pragma unroll
    for (int i = 0; i < 4; i++) {
        int gr = row0 + ty * 4 + i;
        if (gr >= NTOK) continue;
#pragma unroll
        for (int j = 0; j < 4; j++) {
            int gc = tx * 4 + j;
            long idx = ((long)(b * NTOK + gr)) * D + h * HD + gc;
            G[idx] = f2h(acc[i][j]);
        }
    }
}

// ================= setup pieces =================

__global__ __launch_bounds__(256) void patchify_kernel(const float* __restrict__ x, float* __restrict__ tok) {
    int idx = blockIdx.x * 256 + threadIdx.x;
    const int total = NB * NPATCH * D;
    if (idx >= total) return;
    int d = idx % D;
    int p = (idx / D) % NPATCH;
    int b = idx / (D * NPATCH);
    int c = d >> 8;
    int pi = (d >> 4) & 15;
    int pj = d & 15;
    int hp = p / 14, wp = p % 14;
    int row = hp * 16 + pi, col = wp * 16 + pj;
    tok[idx] = x[(((long)b * 3 + c) * 224 + row) * 224 + col];
}

__global__ __launch_bounds__(256) void cls_pos_kernel(float* __restrict__ h, const float* __restrict__ cls,
                                                      const float* __restrict__ pos) {
    int idx = blockIdx.x * 256 + threadIdx.x;
    const int total = NB * NTOK * D;
    if (idx >= total) return;
    int d = idx % D;
    int n = (idx / D) % NTOK;
    float v = pos[n * D + d];
    if (n == 0) h[idx] = cls[d] + v;
    else        h[idx] = h[idx] + v;
}

__global__ __launch_bounds__(256) void wcat_kernel(const float* __restrict__ w, float* __restrict__ Wm) {
    int idx = blockIdx.x * 256 + threadIdx.x;
    const int total = NH * D * HD;
    if (idx >= total) return;
    int k = idx & 63;
    int d = (idx >> 6) % D;
    int hh = idx / (D * HD);
    Wm[d * D + hh * HD + k] = w[idx];
}

// ---------------- f32 GEMM (patch embed only) ----------------
__global__ __launch_bounds__(256) void gemm_f32(
    const float* __restrict__ A, const float* __restrict__ B, float* __restrict__ C,
    const float* __restrict__ bias,
    int M, int N, int K, int lda, int ldb, int ldc,
    long sA1, long sC1) {
    int z = blockIdx.z;
    A += (long)z * sA1;
    long coff = (long)z * sC1;

    __shared__ float As[16][68];
    __shared__ float Bs[16][68];

    int t = threadIdx.x;
    int tx = t & 15, ty = t >> 4;
    int row0 = blockIdx.y * 64, col0 = blockIdx.x * 64;

    float acc[4][4] = {};

    for (int kt = 0; kt < K; kt += 16) {
        {
            int r = t >> 2;
            int c4 = (t & 3) << 2;
            int gr = row0 + r;
            int gk = kt + c4;
            float4 v = make_float4(0.f, 0.f, 0.f, 0.f);
            if (gr < M && gk + 3 < K) v = *(const float4*)(A + (long)gr * lda + gk);
            As[c4 + 0][r] = v.x; As[c4 + 1][r] = v.y; As[c4 + 2][r] = v.z; As[c4 + 3][r] = v.w;
        }
        {
            int r = t >> 4;
            int c4 = (t & 15) << 2;
            int gk = kt + r;
            int gc = col0 + c4;
            float4 v = make_float4(0.f, 0.f, 0.f, 0.f);
            if (gk < K && gc + 3 < N) v = *(const float4*)(B + (long)gk * ldb + gc);
            Bs[r][c4 + 0] = v.x; Bs[r][c4 + 1] = v.y; Bs[r][c4 + 2] = v.z; Bs[r][c4 + 3] = v.w;
        }
        __syncthreads();
#pragma unroll
        for (int kk = 0; kk < 16; kk++) {
            float av[4], bv[4];
#pragma unroll
            for (int i = 0; i < 4; i++) av[i] = As[kk][ty * 4 + i];
#pragma unroll
            for (int j = 0; j < 4; j++) bv[j] = Bs[kk][tx * 4 + j];
#pragma unroll
            for (int i = 0; i < 4; i++)
#pragma unroll
                for (int j = 0; j < 4; j++) acc[i][j] += av[i] * bv[j];
        }
        __syncthreads();
    }
#pragma unroll
    for (int i = 0; i < 4; i++) {
        int gr = row0 + ty * 4 + i;
        if (gr >= M) continue;
#pragma unroll
        for (int j = 0; j < 4; j++) {
            int gc = col0 + tx * 4 + j;
            if (gc >= N) continue;
            float v = acc[i][j];
            if (bias) v += bias[gc];
            C[coff + (long)gr * ldc + gc] = v;
        }
    }
}

// fp16 preps
__global__ __launch_bounds__(256) void prep_transpose_h(const float* __restrict__ src,
                                                        u16* __restrict__ dst, int R, int C) {
    int idx = blockIdx.x * 256 + threadIdx.x;
    if (idx >= R * C) return;
    int r = idx % R, c = idx / R;
    dst[idx] = f2h(src[(long)r * C + c]);
}
__global__ __launch_bounds__(256) void prep_convert_h(const float* __restrict__ src,
                                                      u16* __restrict__ dst, int n) {
    int idx = blockIdx.x * 256 + threadIdx.x;
    if (idx >= n) return;
    dst[idx] = f2h(src[idx]);
}

extern "C" void kernel_launch(void* const* d_in, const int* in_sizes, int n_in,
                              void* d_out, int out_size, void* d_ws, size_t ws_size,
                              hipStream_t stream) {
    const float* x        = (const float*)d_in[0];
    const float* patch_w  = (const float*)d_in[1];
    const float* patch_b  = (const float*)d_in[2];
    const float* cls_tok  = (const float*)d_in[3];
    const float* pos_emb  = (const float*)d_in[4];
    const float* ln_gamma = (const float*)d_in[5];
    const float* ln_beta  = (const float*)d_in[6];
    const float* wq       = (const float*)d_in[7];
    const float* wk       = (const float*)d_in[8];
    const float* xi       = (const float*)d_in[9];
    const float* out_gamma= (const float*)d_in[10];
    const float* out_beta = (const float*)d_in[11];
    const float* out_w    = (const float*)d_in[12];
    const float* out_b    = (const float*)d_in[13];
    float* out = (float*)d_out;

    float* ws = (float*)d_ws;
    const long SZ = SZL;
    const long AR = (long)AROWS * D;
    float* h  = ws;
    float* Qb = ws + SZ;
    float* Kb = ws + 2 * SZ;
    u16* gh16    = (u16*)(ws + 3 * SZ);
    u16* WmQTh16 = gh16 + AR;
    u16* WmKTh16 = WmQTh16 + DD;
    u16* WmQh16  = WmKTh16 + DD;
    u16* WmKh16  = WmQh16 + DD;
    u16* xiTh16  = WmKh16 + DD;
    u16* xibh16  = xiTh16 + DH;
    u16* G1h16   = xibh16 + DH;
    u16* G2h16   = G1h16 + AR;
    u16* HH16    = G2h16 + AR;
    u16* owTh16  = HH16 + (long)AROWS * HOP;
    // shared region (sequenced aliasing): part (6*SZ u16) | Pt (192*PBH u16) | tok/WmQ/WmK (setup f32)
    char* R1c = (char*)(owTh16 + DD);
    u16* Pt16   = (u16*)R1c;
    u16* part16 = (u16*)R1c;
    float* tok  = (float*)R1c;
    float* WmQ  = (float*)R1c + SZ;
    float* WmK  = WmQ + DD;

    // ---- setup ----
    patchify_kernel<<<(NB * NPATCH * D + 255) / 256, 256, 0, stream>>>(x, tok);
    wcat_kernel<<<(NH * D * HD + 255) / 256, 256, 0, stream>>>(wq, WmQ);
    wcat_kernel<<<(NH * D * HD + 255) / 256, 256, 0, stream>>>(wk, WmK);
    prep_transpose_h<<<(DD + 255) / 256, 256, 0, stream>>>(WmQ, WmQTh16, 768, 768);
    prep_transpose_h<<<(DD + 255) / 256, 256, 0, stream>>>(WmK, WmKTh16, 768, 768);
    prep_convert_h<<<(DD + 255) / 256, 256, 0, stream>>>(WmQ, WmQh16, DD);
    prep_convert_h<<<(DD + 255) / 256, 256, 0, stream>>>(WmK, WmKh16, DD);
    prep_transpose_h<<<(DH + 255) / 256, 256, 0, stream>>>(xi, xiTh16, 768, HOP);
    prep_convert_h<<<(DH + 255) / 256, 256, 0, stream>>>(xi, xibh16, DH);
    prep_transpose_h<<<(DD + 255) / 256, 256, 0, stream>>>(out_w, owTh16, 768, 768);
    // patch embed: f32 (h0 seed stays f32 — sensitivity firewall)
    gemm_f32<<<dim3(12, 4, NB), 256, 0, stream>>>(
        tok, patch_w, h + D, patch_b, NPATCH, D, D, D, D, D,
        (long)NPATCH * D, (long)NTOK * D);
    cls_pos_kernel<<<(NB * NTOK * D + 255) / 256, 256, 0, stream>>>(h, cls_tok, pos_emb);

    for (int step = 0; step < TSTEPS; step++) {
        ln_fuse_kernel<<<NROWS, 256, 0, stream>>>(h, gh16, part16, ln_gamma, ln_beta,
                                                  0, step > 0 ? 1 : 0, 1);
        fused_proj<<<dim3(36, 25), 256, 0, stream>>>(gh16, WmQTh16, WmKTh16, xiTh16, Qb, Kb, HH16);
        attn_p_kernel<<<dim3(192, 13), 256, 0, stream>>>(Qb, Kb, Pt16);
        attn_g_kernel<<<dim3(1, 4, 384), 256, 0, stream>>>(Pt16, Qb, Kb, G1h16, G2h16);
        gemm_h16_fused<<<dim3(6, 25, 6), 256, 0, stream>>>(
            G1h16, G2h16, HH16, WmQh16, WmKh16, xibh16, part16);
    }

    // ---- final: reduce + LN (compact) -> fp16, then out projection (fp16 MFMA) ----
    ln_fuse_kernel<<<NPROWS, 256, 0, stream>>>(h, gh16, part16, out_gamma, out_beta, 1, 1, 0);
    gemm_h16<<<dim3(6, 25, 1), 256, 0, stream>>>(
        gh16, owTh16, out, out_b, NPROWS, D, D, D, D, D, 0, 0, 0, 0);
}